// Round 16
// baseline (541.823 us; speedup 1.0000x reference)
//
#include <hip/hip_runtime.h>
#include <hip/hip_bf16.h>
#include <math.h>

// PsiQRH block, MI355X. B=8 S=4096 QD=4 DM=1024 H=16 HD=64.
// Round 16: kx_filter final IFFT via in-place dr6 permutation + rdit64 so the
// global store order is SEQUENTIAL (r12-style clean write stream; r13-15's
// digit-reversed segment order caused 4x TCC write amplification).

#define DEV static __device__ __forceinline__
typedef unsigned int uint32;
typedef unsigned short u16;

typedef __attribute__((ext_vector_type(8))) _Float16 f16x8;
typedef __attribute__((ext_vector_type(4))) float f32x4;
typedef __attribute__((ext_vector_type(2))) unsigned int u32x2;

DEV float2 cmulf(float2 a, float2 b) {
  return make_float2(a.x * b.x - a.y * b.y, a.x * b.y + a.y * b.x);
}
DEV u16 f2h(float f) {
  union { _Float16 h; u16 u; } v;
  v.h = (_Float16)f;
  return v.u;
}
DEV float h2f(uint32 u) {
  union { u16 s; _Float16 h; } v;
  v.s = (u16)u;
  return (float)v.h;
}
DEV uint32 pack2h(float a, float b) {
  return (uint32)f2h(a) | ((uint32)f2h(b) << 16);
}
DEV void glds16(void* lds, const void* g) {
  __builtin_amdgcn_global_load_lds((const __attribute__((address_space(1))) unsigned int*)g,
                                   (__attribute__((address_space(3))) unsigned int*)lds, 16, 0, 0);
}
DEV void wave_sync() {
  asm volatile("s_waitcnt lgkmcnt(0)" ::: "memory");
  __builtin_amdgcn_sched_barrier(0);
}
DEV int dr10(int v) {   // base-4 digit reversal, 10-bit
  int r = (int)(__brev((unsigned)v) >> 22);
  return ((r & 0x155) << 1) | ((r & 0x2AA) >> 1);
}
constexpr int dr6c(int v) {   // base-4 digit reversal, 6-bit (involution)
  return ((v & 3) << 4) | (v & 12) | ((v >> 4) & 3);
}

// quarter-wave table: CQ[j] = cos(pi*j/32), j=0..16
constexpr float CQ[17] = {
  1.0f, 0.995184726672197f, 0.980785280403230f, 0.956940335732209f,
  0.923879532511287f, 0.881921264348355f, 0.831469612302545f, 0.773010453362737f,
  0.707106781186548f, 0.634393284163645f, 0.555570233019602f, 0.471396736825998f,
  0.382683432365090f, 0.290284677254462f, 0.195090322016128f, 0.098017140329561f, 0.0f };
constexpr float twc64(int j) {   // cos(2*pi*j/64)
  return (j & 63) <= 16 ? CQ[j & 63]
       : (j & 63) <= 32 ? -CQ[32 - (j & 63)]
       : (j & 63) <= 48 ? -CQ[(j & 63) - 32] : CQ[64 - (j & 63)];
}
constexpr float tws64(int j) {   // sin(2*pi*j/64)
  return (j & 63) <= 16 ? CQ[16 - (j & 63)]
       : (j & 63) <= 32 ? CQ[(j & 63) - 16]
       : (j & 63) <= 48 ? -CQ[48 - (j & 63)] : -CQ[(j & 63) - 48];
}

// cos/sin of pi*j/16, j = 0..15 (stage-offset twiddles for LDS FFTs)
constexpr float CR_C[16] = {
  1.0f, 0.980785280403230f, 0.923879532511287f, 0.831469612302545f,
  0.707106781186548f, 0.555570233019602f, 0.382683432365090f, 0.195090322016128f,
  0.0f, -0.195090322016128f, -0.382683432365090f, -0.555570233019602f,
  -0.707106781186548f, -0.831469612302545f, -0.923879532511287f, -0.980785280403230f };
constexpr float CR_S[16] = {
  0.0f, 0.195090322016128f, 0.382683432365090f, 0.555570233019602f,
  0.707106781186548f, 0.831469612302545f, 0.923879532511287f, 0.980785280403230f,
  1.0f, 0.980785280403230f, 0.923879532511287f, 0.831469612302545f,
  0.707106781186548f, 0.555570233019602f, 0.382683432365090f, 0.195090322016128f };

// ---------------- in-register 64-pt radix-4 FFTs (fully unrolled, const twiddles) -------------
template<int SGN>
DEV void rdif64(float2* z) {
  #pragma unroll
  for (int j = 0; j < 16; ++j) {
    float2 x0 = z[j], x1 = z[j + 16], x2 = z[j + 32], x3 = z[j + 48];
    float2 s0 = make_float2(x0.x + x2.x, x0.y + x2.y);
    float2 s1 = make_float2(x0.x - x2.x, x0.y - x2.y);
    float2 s2 = make_float2(x1.x + x3.x, x1.y + x3.y);
    float2 d  = make_float2(x1.x - x3.x, x1.y - x3.y);
    float2 s3 = (SGN < 0) ? make_float2(d.y, -d.x) : make_float2(-d.y, d.x);
    z[j] = make_float2(s0.x + s2.x, s0.y + s2.y);
    const float2 tf1 = make_float2(twc64(j),     (float)SGN * tws64(j));
    const float2 tf2 = make_float2(twc64(2 * j), (float)SGN * tws64(2 * j));
    const float2 tf3 = make_float2(twc64(3 * j), (float)SGN * tws64(3 * j));
    z[j + 16] = cmulf(make_float2(s1.x + s3.x, s1.y + s3.y), tf1);
    z[j + 32] = cmulf(make_float2(s0.x - s2.x, s0.y - s2.y), tf2);
    z[j + 48] = cmulf(make_float2(s1.x - s3.x, s1.y - s3.y), tf3);
  }
  #pragma unroll
  for (int b = 0; b < 64; b += 16)
    #pragma unroll
    for (int j = 0; j < 4; ++j) {
      const int i = b + j;
      float2 x0 = z[i], x1 = z[i + 4], x2 = z[i + 8], x3 = z[i + 12];
      float2 s0 = make_float2(x0.x + x2.x, x0.y + x2.y);
      float2 s1 = make_float2(x0.x - x2.x, x0.y - x2.y);
      float2 s2 = make_float2(x1.x + x3.x, x1.y + x3.y);
      float2 d  = make_float2(x1.x - x3.x, x1.y - x3.y);
      float2 s3 = (SGN < 0) ? make_float2(d.y, -d.x) : make_float2(-d.y, d.x);
      z[i] = make_float2(s0.x + s2.x, s0.y + s2.y);
      const float2 tf1 = make_float2(twc64(4 * j),  (float)SGN * tws64(4 * j));
      const float2 tf2 = make_float2(twc64(8 * j),  (float)SGN * tws64(8 * j));
      const float2 tf3 = make_float2(twc64(12 * j), (float)SGN * tws64(12 * j));
      z[i + 4]  = cmulf(make_float2(s1.x + s3.x, s1.y + s3.y), tf1);
      z[i + 8]  = cmulf(make_float2(s0.x - s2.x, s0.y - s2.y), tf2);
      z[i + 12] = cmulf(make_float2(s1.x - s3.x, s1.y - s3.y), tf3);
    }
  #pragma unroll
  for (int b = 0; b < 64; b += 4) {
    float2 x0 = z[b], x1 = z[b + 1], x2 = z[b + 2], x3 = z[b + 3];
    float2 s0 = make_float2(x0.x + x2.x, x0.y + x2.y);
    float2 s1 = make_float2(x0.x - x2.x, x0.y - x2.y);
    float2 s2 = make_float2(x1.x + x3.x, x1.y + x3.y);
    float2 d  = make_float2(x1.x - x3.x, x1.y - x3.y);
    float2 s3 = (SGN < 0) ? make_float2(d.y, -d.x) : make_float2(-d.y, d.x);
    z[b]     = make_float2(s0.x + s2.x, s0.y + s2.y);
    z[b + 1] = make_float2(s1.x + s3.x, s1.y + s3.y);
    z[b + 2] = make_float2(s0.x - s2.x, s0.y - s2.y);
    z[b + 3] = make_float2(s1.x - s3.x, s1.y - s3.y);
  }
}

template<int SGN>
DEV void rdit64(float2* z) {
  #pragma unroll
  for (int b = 0; b < 64; b += 4) {
    float2 b0 = z[b], b1 = z[b + 1], b2 = z[b + 2], b3 = z[b + 3];
    float2 t0 = make_float2(b0.x + b2.x, b0.y + b2.y);
    float2 t1 = make_float2(b0.x - b2.x, b0.y - b2.y);
    float2 t2 = make_float2(b1.x + b3.x, b1.y + b3.y);
    float2 d  = make_float2(b1.x - b3.x, b1.y - b3.y);
    float2 t3 = (SGN > 0) ? make_float2(-d.y, d.x) : make_float2(d.y, -d.x);
    z[b]     = make_float2(t0.x + t2.x, t0.y + t2.y);
    z[b + 1] = make_float2(t1.x + t3.x, t1.y + t3.y);
    z[b + 2] = make_float2(t0.x - t2.x, t0.y - t2.y);
    z[b + 3] = make_float2(t1.x - t3.x, t1.y - t3.y);
  }
  #pragma unroll
  for (int b = 0; b < 64; b += 16)
    #pragma unroll
    for (int j = 0; j < 4; ++j) {
      const int i = b + j;
      const float2 tf1 = make_float2(twc64(4 * j),  (float)SGN * tws64(4 * j));
      const float2 tf2 = make_float2(twc64(8 * j),  (float)SGN * tws64(8 * j));
      const float2 tf3 = make_float2(twc64(12 * j), (float)SGN * tws64(12 * j));
      float2 b0 = z[i];
      float2 b1 = cmulf(z[i + 4], tf1);
      float2 b2 = cmulf(z[i + 8], tf2);
      float2 b3 = cmulf(z[i + 12], tf3);
      float2 t0 = make_float2(b0.x + b2.x, b0.y + b2.y);
      float2 t1 = make_float2(b0.x - b2.x, b0.y - b2.y);
      float2 t2 = make_float2(b1.x + b3.x, b1.y + b3.y);
      float2 d  = make_float2(b1.x - b3.x, b1.y - b3.y);
      float2 t3 = (SGN > 0) ? make_float2(-d.y, d.x) : make_float2(d.y, -d.x);
      z[i]      = make_float2(t0.x + t2.x, t0.y + t2.y);
      z[i + 4]  = make_float2(t1.x + t3.x, t1.y + t3.y);
      z[i + 8]  = make_float2(t0.x - t2.x, t0.y - t2.y);
      z[i + 12] = make_float2(t1.x - t3.x, t1.y - t3.y);
    }
  #pragma unroll
  for (int j = 0; j < 16; ++j) {
    const float2 tf1 = make_float2(twc64(j),     (float)SGN * tws64(j));
    const float2 tf2 = make_float2(twc64(2 * j), (float)SGN * tws64(2 * j));
    const float2 tf3 = make_float2(twc64(3 * j), (float)SGN * tws64(3 * j));
    float2 b0 = z[j];
    float2 b1 = cmulf(z[j + 16], tf1);
    float2 b2 = cmulf(z[j + 32], tf2);
    float2 b3 = cmulf(z[j + 48], tf3);
    float2 t0 = make_float2(b0.x + b2.x, b0.y + b2.y);
    float2 t1 = make_float2(b0.x - b2.x, b0.y - b2.y);
    float2 t2 = make_float2(b1.x + b3.x, b1.y + b3.y);
    float2 d  = make_float2(b1.x - b3.x, b1.y - b3.y);
    float2 t3 = (SGN > 0) ? make_float2(-d.y, d.x) : make_float2(d.y, -d.x);
    z[j]      = make_float2(t0.x + t2.x, t0.y + t2.y);
    z[j + 16] = make_float2(t1.x + t3.x, t1.y + t3.y);
    z[j + 32] = make_float2(t0.x - t2.x, t0.y - t2.y);
    z[j + 48] = make_float2(t1.x - t3.x, t1.y - t3.y);
  }
}

// Radix-4 DIF over LDS, natural in -> digit-reversed out (negative exponent).
template<int L, int NLOG, int NSUB, bool WL>
DEV void dif4_stages(float2* F, int lg) {
  #pragma unroll
  for (int st = 0; st < NLOG / 2; ++st) {
    const int qlog = NLOG - 2 - 2 * st;
    const int q = 1 << qlog;
    float bs, bc;
    __sincosf((float)(lg & (q - 1)) * (-1.57079632679489661923f / (float)q), &bs, &bc);
    const float2 base = make_float2(bc, bs);
    #pragma unroll
    for (int u = 0; u < NSUB * (1 << (NLOG - 2)) / L; ++u) {
      const int sub = (u * L) >> (NLOG - 2);
      const int bf = ((u * L) & ((1 << (NLOG - 2)) - 1)) + lg;
      const int jj = ((u * L) % q) * 8 / q;
      const int i1 = (sub << NLOG) + ((bf >> qlog) << (qlog + 2)) + (bf & (q - 1));
      float2 x0 = F[i1], x1 = F[i1 + q], x2 = F[i1 + 2 * q], x3 = F[i1 + 3 * q];
      float2 s0 = make_float2(x0.x + x2.x, x0.y + x2.y);
      float2 s1 = make_float2(x0.x - x2.x, x0.y - x2.y);
      float2 s2 = make_float2(x1.x + x3.x, x1.y + x3.y);
      float2 dq = make_float2(x1.x - x3.x, x1.y - x3.y);
      float2 s3 = make_float2(dq.y, -dq.x);               // -i*(x1-x3)
      F[i1] = make_float2(s0.x + s2.x, s0.y + s2.y);
      if (qlog == 0) {
        F[i1 + 1] = make_float2(s1.x + s3.x, s1.y + s3.y);
        F[i1 + 2] = make_float2(s0.x - s2.x, s0.y - s2.y);
        F[i1 + 3] = make_float2(s1.x - s3.x, s1.y - s3.y);
      } else {
        const float2 tf1 = (jj == 0) ? base : cmulf(base, make_float2(CR_C[jj], -CR_S[jj]));
        const float2 tf2 = cmulf(tf1, tf1);
        const float2 tf3 = cmulf(tf2, tf1);
        F[i1 + q]     = cmulf(make_float2(s1.x + s3.x, s1.y + s3.y), tf1);
        F[i1 + 2 * q] = cmulf(make_float2(s0.x - s2.x, s0.y - s2.y), tf2);
        F[i1 + 3 * q] = cmulf(make_float2(s1.x - s3.x, s1.y - s3.y), tf3);
      }
    }
    if (WL) wave_sync(); else __syncthreads();
  }
}

// ---------------- quaternion helpers ----------------------------------------------------------
DEV float4 qmul4(float4 a, float4 b) {
  return make_float4(
    a.x * b.x - a.y * b.y - a.z * b.z - a.w * b.w,
    a.x * b.y + a.y * b.x + a.z * b.w - a.w * b.z,
    a.x * b.z - a.y * b.w + a.z * b.x + a.w * b.y,
    a.x * b.w + a.y * b.z - a.z * b.y + a.w * b.x);
}
DEV float4 qne(float4 q) {
  float n = sqrtf(q.x * q.x + q.y * q.y + q.z * q.z + q.w * q.w) + 1e-8f;
  float r = 1.0f / n;
  return make_float4(q.x * r, q.y * r, q.z * r, q.w * r);
}

// ---------------- fractal pass 1: 1024-pt radix-4 FFTs, wave-private (stride 1028) -----------
__global__ __launch_bounds__(512) void kx_fr_pass1(const float* __restrict__ x,
    const float* __restrict__ W_in, const float* __restrict__ b_in,
    float2* __restrict__ zmid) {
  __shared__ float2 fb[8 * 1028];
  const int t = threadIdx.x, l = t & 63, w = t >> 6;
  const int btile = blockIdx.x, bz = blockIdx.y;
  const int bcol = btile * 8 + w;
  const int d = 2 * (bcol & 511);
  const int soff = bcol >> 9;
  const float w00 = W_in[d],     w10 = W_in[1024 + d], w20 = W_in[2048 + d], w30 = W_in[3072 + d];
  const float w01 = W_in[d + 1], w11 = W_in[1025 + d], w21 = W_in[2049 + d], w31 = W_in[3073 + d];
  const float bi0 = b_in[d], bi1 = b_in[d + 1];
  const float* xb = x + (size_t)bz * 4096 * 4;
  float2* fbw = fb + w * 1028;
  #pragma unroll
  for (int i = 0; i < 16; ++i) {
    int a = i * 64 + l;
    int s = 4 * a + soff;
    float4 xv = *(const float4*)(xb + (size_t)s * 4);
    float z0 = fmaf(xv.x, w00, fmaf(xv.y, w10, fmaf(xv.z, w20, fmaf(xv.w, w30, bi0))));
    float z1 = fmaf(xv.x, w01, fmaf(xv.y, w11, fmaf(xv.z, w21, fmaf(xv.w, w31, bi1))));
    fbw[a] = make_float2(z0, z1);
  }
  wave_sync();
  dif4_stages<64, 10, 1, true>(fbw, l);
  __syncthreads();
  float2* dst = zmid + (size_t)bz * (1024 * 2048);
  #pragma unroll
  for (int i = 0; i < 16; ++i) {
    int idx = i * 512 + t;
    int w8 = idx & 7, cnat = idx >> 3;
    float2 v = fb[w8 * 1028 + dr10(cnat)];
    dst[(size_t)cnat * 2048 + btile * 8 + w8] = v;
  }
}

DEV float block_reduce128(float* red, int t, float v) {
  red[t] = v; __syncthreads();
  for (int s = 64; s; s >>= 1) { if (t < s) red[t] += red[t + s]; __syncthreads(); }
  float r = red[0]; __syncthreads();
  return r;
}

// ---------------- fractal pass 2: reg-fused r2 + 2x(1024 radix-4); __logf moments ------------
__global__ __launch_bounds__(128) void kx_fr_pass2(const float2* __restrict__ zmid,
    float* __restrict__ partials, float* __restrict__ sparts) {
  __shared__ float2 fb[2 * 2052];
  __shared__ float red[128];
  const int t = threadIdx.x, l = t & 63, w = t >> 6;   // w in {0,1}
  const int cg = blockIdx.x, bz = blockIdx.y;
  const int c = (cg == 0) ? (w ? 512 : 0) : (w ? (1024 - cg) : cg);
  const float2* src = zmid + ((size_t)bz * 1024 + c) * 2048;
  float2* fbc = fb + w * 2052;
  float2 rot[4], stp4;
  {
    float sn, cs;
    __sincosf((float)(l * c) * (-6.28318530717958647692f / 2097152.0f), &sn, &cs);
    rot[0] = make_float2(cs, sn);
    float2 stp;
    __sincosf((float)c * (-6.28318530717958647692f / 32768.0f), &sn, &cs);
    stp = make_float2(cs, sn);
    rot[1] = cmulf(rot[0], stp);
    float2 stp2 = cmulf(stp, stp);
    rot[2] = cmulf(rot[0], stp2);
    rot[3] = cmulf(rot[1], stp2);
    stp4 = cmulf(stp2, stp2);
  }
  float2 zr[32];
  #pragma unroll
  for (int i = 0; i < 32; ++i) {
    int bb = i * 64 + l;
    zr[i] = cmulf(src[bb], rot[i & 3]);
    rot[i & 3] = cmulf(rot[i & 3], stp4);
  }
  {
    float bs, bc;
    __sincosf((float)l * (-3.14159265358979323846f / 1024.0f), &bs, &bc);
    const float2 b2 = make_float2(bc, bs);
    #pragma unroll
    for (int u = 0; u < 16; ++u) {
      const float2 tf = (u == 0) ? b2 : cmulf(b2, make_float2(CR_C[u], -CR_S[u]));
      int i1 = u * 64 + l;
      float2 a0 = zr[u], a1 = zr[u + 16];
      fbc[i1] = make_float2(a0.x + a1.x, a0.y + a1.y);
      fbc[i1 + 1024] = cmulf(make_float2(a0.x - a1.x, a0.y - a1.y), tf);
    }
    wave_sync();
  }
  dif4_stages<64, 10, 2, true>(fbc, l);
  __syncthreads();
  float t0 = 0.f, t1 = 0.f, s0 = 0.f, s1 = 0.f, s2 = 0.f;
  if (cg != 0) {
    const float2* fbm = fb + (1 - w) * 2052;
    float2 pw[32];
    pw[0] = make_float2(1.f, 0.f);
    {
      float sn, cs;
      __sincosf(-3.14159265358979323846f / 2048.0f, &sn, &cs);
      float2 w1 = make_float2(cs, sn);
      #pragma unroll
      for (int j = 1; j < 32; ++j) pw[j] = cmulf(pw[j - 1], w1);
    }
    const int drl = (l & 3) * 256 + ((l >> 2) & 3) * 64 + ((l >> 4) & 3) * 16;
    float2 base2;
    {
      float sn, cs;
      __sincosf((float)drl * (-3.14159265358979323846f / 1024.0f), &sn, &cs);
      float2 lf = make_float2(cs, sn);
      __sincosf((float)c * (-6.28318530717958647692f / 4194304.0f), &sn, &cs);
      base2 = cmulf(make_float2(cs, sn), lf);
    }
    #pragma unroll
    for (int i = 0; i < 32; ++i) {
      const int p = i * 64 + l;
      const int dri = (i & 3) * 4 + ((i >> 2) & 3);
      const int top = i >> 4;
      const int dd = 2 * (drl + dri) + top;
      float2 Zk = fbc[p];
      float2 Zm = fbm[2047 - p];
      float2 E = make_float2(0.5f * (Zk.x + Zm.x), 0.5f * (Zk.y - Zm.y));
      float2 A = make_float2(Zk.x - Zm.x, Zk.y + Zm.y);
      float2 O = make_float2(0.5f * A.y, -0.5f * A.x);
      float2 urot = cmulf(base2, pw[2 * dri + top]);
      float2 U = cmulf(urot, O);
      float Xr = E.x + U.x, Xi = E.y + U.y;
      float P = Xr * Xr + Xi * Xi;
      int k = c + (dd << 10);
      float fr = (float)k * (1.0f / 4194304.0f);
      if (fr > 0.01f && fr < 0.5f) {
        float lp = __logf(P + 1e-10f);
        float lk = __logf(fr + 1e-10f);
        t0 += lp; t1 += lk * lp;
        s0 += 1.0f; s1 += lk; s2 += lk * lk;
      }
    }
  } else {
    const float2* fbm = fbc;   // self-mirrored columns (c = 0, 512)
    float2 urot;
    {
      float sn, cs;
      __sincosf((float)(c + l * 1024) * (-6.28318530717958647692f / 4194304.0f), &sn, &cs);
      urot = make_float2(cs, sn);
    }
    const float2 ustp = make_float2(0.995184726672197f, -0.0980171403295606f); // e^{-i pi/32}
    #pragma unroll
    for (int i = 0; i < 32; ++i) {
      int dd = i * 64 + l;
      int md = (c == 0) ? ((2048 - dd) & 2047) : (2047 - dd);
      int pk = ((dd & 1) << 10) | dr10(dd >> 1);
      int pm = ((md & 1) << 10) | dr10(md >> 1);
      float2 Zk = fbc[pk];
      float2 Zm = fbm[pm];
      float2 E = make_float2(0.5f * (Zk.x + Zm.x), 0.5f * (Zk.y - Zm.y));
      float2 A = make_float2(Zk.x - Zm.x, Zk.y + Zm.y);
      float2 O = make_float2(0.5f * A.y, -0.5f * A.x);
      float2 U = cmulf(urot, O);
      float Xr = E.x + U.x, Xi = E.y + U.y;
      float P = Xr * Xr + Xi * Xi;
      int k = c + (dd << 10);
      float fr = (float)k * (1.0f / 4194304.0f);
      if (fr > 0.01f && fr < 0.5f) {
        float lp = __logf(P + 1e-10f);
        float lk = __logf(fr + 1e-10f);
        t0 += lp; t1 += lk * lp;
        s0 += 1.0f; s1 += lk; s2 += lk * lk;
      }
      urot = cmulf(urot, ustp);
    }
  }
  float T0 = block_reduce128(red, t, t0);
  float T1 = block_reduce128(red, t, t1);
  if (t == 0) {
    partials[((size_t)bz * 512 + cg) * 2 + 0] = T0;
    partials[((size_t)bz * 512 + cg) * 2 + 1] = T1;
  }
  if (bz == 0) {
    float S0 = block_reduce128(red, t, s0);
    float S1 = block_reduce128(red, t, s1);
    float S2 = block_reduce128(red, t, s2);
    if (t == 0) { sparts[cg * 3] = S0; sparts[cg * 3 + 1] = S1; sparts[cg * 3 + 2] = S2; }
  }
}

DEV float block_reduce512(float* sh, int t, float v) {
  sh[t] = v; __syncthreads();
  for (int s = 256; s; s >>= 1) { if (t < s) sh[t] += sh[t + s]; __syncthreads(); }
  float r = sh[0]; __syncthreads();
  return r;
}

// ---------------- finalize: alpha[b]; gelu_k table ---------------------------------------------
__global__ __launch_bounds__(512) void kx_finalize(const float* __restrict__ partials,
    const float* __restrict__ sparts, float* __restrict__ alpha, float* __restrict__ gelu) {
  __shared__ float sh[512];
  __shared__ float lk[4096];
  const int t = threadIdx.x;
  float S0 = block_reduce512(sh, t, sparts[t * 3 + 0]);
  float S1 = block_reduce512(sh, t, sparts[t * 3 + 1]);
  float S2 = block_reduce512(sh, t, sparts[t * 3 + 2]);
  float mk = S1 / S0;
  float var = S2 - mk * S1;
  for (int b = 0; b < 8; ++b) {
    float T0 = block_reduce512(sh, t, partials[((size_t)b * 512 + t) * 2 + 0]);
    float T1 = block_reduce512(sh, t, partials[((size_t)b * 512 + t) * 2 + 1]);
    if (t == 0) {
      float cov = T1 - mk * T0;
      float beta = -cov / (var + 1e-10f);
      float D = fminf(fmaxf((3.0f - beta) * 0.5f, 0.5f), 1.5f);
      alpha[b] = fminf(fmaxf(1.0f + 0.8f * (D - 1.0f), 0.1f), 3.0f);
    }
  }
  for (int s = t; s < 4096; s += 512) {
    int m = (s < 2048) ? s : (4096 - s);
    lk[s] = logf((float)m * (1.0f / 4096.0f) + 1e-8f);
  }
  __syncthreads();
  float ls = 0.f;
  for (int s = t; s < 4096; s += 512) ls += lk[s];
  float mean = block_reduce512(sh, t, ls) * (1.0f / 4096.0f);
  float vs = 0.f;
  for (int s = t; s < 4096; s += 512) { float dv = lk[s] - mean; vs += dv * dv; }
  float sd = sqrtf(block_reduce512(sh, t, vs) * (1.0f / 4095.0f));
  for (int k = t; k < 2049; k += 512) {
    float xn = (lk[k] - mean) / (sd + 1e-8f);
    gelu[k] = 0.5f * xn * (1.0f + erff(xn * 0.70710678118654752440f));
  }
}

// ---------------- gain table + composed quaternions -------------------------------------------
__global__ __launch_bounds__(256) void kx_gains(const float* __restrict__ alpha,
    const float* __restrict__ gelu, const float* __restrict__ abase,
    const float* __restrict__ pshift, const float* __restrict__ thL,
    const float* __restrict__ thR, float* __restrict__ gains, float* __restrict__ qlr) {
  const int bh = blockIdx.x;    // 0..127
  const float aa = abase[bh & 15] * alpha[bh >> 4];
  const float ps = pshift[bh & 15];
  for (int k = threadIdx.x; k < 2049; k += 256)
    gains[(size_t)bh * 2064 + k] = cosf(fmaf(aa, gelu[k], ps));
  if (bh == 0 && threadIdx.x == 0) {
    float4 QL = make_float4(1.f, 0.f, 0.f, 0.f);
    float4 QRC = make_float4(1.f, 0.f, 0.f, 0.f);
    for (int it = 0; it < 4; ++it) {
      float s0, c0, s1, c1, s2, c2;
      sincosf(0.5f * thL[it * 3 + 0], &s0, &c0);
      sincosf(0.5f * thL[it * 3 + 1], &s1, &c1);
      sincosf(0.5f * thL[it * 3 + 2], &s2, &c2);
      float4 qL = qne(make_float4(c0 * c1 * c2, s0 * c1 * c2, c0 * s1 * c2, c0 * c1 * s2));
      QL = qmul4(qL, QL);
      sincosf(0.5f * thR[it * 3 + 0], &s0, &c0);
      sincosf(0.5f * thR[it * 3 + 1], &s1, &c1);
      sincosf(0.5f * thR[it * 3 + 2], &s2, &c2);
      float4 qR = qne(make_float4(c0 * c1 * c2, s0 * c1 * c2, c0 * s1 * c2, c0 * c1 * s2));
      QRC = qmul4(QRC, make_float4(qR.x, -qR.y, -qR.z, -qR.w));
    }
    *(float4*)qlr = QL;
    *(float4*)(qlr + 4) = QRC;
  }
}

// ---------------- W_attn_out transpose -> fp16 [n][d] pre-swizzled ----------------------------
__global__ __launch_bounds__(256) void kx_wt(const float* __restrict__ W, u16* __restrict__ Wt) {
  __shared__ float tile[64][65];
  const int t = threadIdx.x;
  const int nt = blockIdx.x, dt = blockIdx.y;
  #pragma unroll
  for (int i = 0; i < 16; ++i) {
    int idx = i * 256 + t;
    int r = idx >> 6, cc = idx & 63;
    tile[r][cc] = W[(size_t)(dt * 64 + r) * 1024 + nt * 64 + cc];
  }
  __syncthreads();
  #pragma unroll
  for (int i = 0; i < 2; ++i) {
    int task = i * 256 + t;
    int nl = task >> 3, g = task & 7;
    union { u16 h[8]; uint4 v; } pk;
    #pragma unroll
    for (int k = 0; k < 8; ++k) pk.h[k] = f2h(tile[g * 8 + k][nl]);
    size_t idx = (size_t)(nt * 64 + nl) * 1024 + dt * 64 + ((g ^ (nl & 7)) << 3);
    *(uint4*)(Wt + idx) = pk.v;
  }
}

// ---------------- spectral filter: four-step register FFT (64x64), sequential store ----------
__global__ __launch_bounds__(128, 2) void kx_filter(const float* __restrict__ x,
    const float* __restrict__ W_in, const float* __restrict__ b_in,
    const float* __restrict__ gains, uint32* __restrict__ XFp) {
  __shared__ uint32 tr[2][4096];   // fp16x2 transpose buffer, 16KB per wave
  const int t = threadIdx.x, l = t & 63, wv = t >> 6;
  const int g = blockIdx.x, h = blockIdx.y, bz = blockIdx.z;
  const int d0 = h * 64 + g * 4 + wv * 2;
  const float* gn = gains + ((size_t)bz * 16 + h) * 2064;
  const float wa0 = W_in[d0],     wa1 = W_in[1024 + d0], wa2 = W_in[2048 + d0], wa3 = W_in[3072 + d0];
  const float wb0 = W_in[d0 + 1], wb1 = W_in[1025 + d0], wb2 = W_in[2049 + d0], wb3 = W_in[3073 + d0];
  const float bia = b_in[d0], bib = b_in[d0 + 1];
  const float* xb = x + (size_t)bz * 4096 * 4;
  uint32* trw = tr[wv];
  float2 z[64];
  #pragma unroll
  for (int r = 0; r < 64; ++r) {
    int s = r * 64 + l;
    float4 xv = *(const float4*)(xb + (size_t)s * 4);
    float za = fmaf(xv.x, wa0, fmaf(xv.y, wa1, fmaf(xv.z, wa2, fmaf(xv.w, wa3, bia))));
    float zb = fmaf(xv.x, wb0, fmaf(xv.y, wb1, fmaf(xv.z, wb2, fmaf(xv.w, wb3, bib))));
    z[r] = make_float2(za, zb);
  }
  rdif64<-1>(z);
  {
    float sn, cs;
    __sincosf((float)l * (-6.28318530717958647692f / 4096.0f), &sn, &cs);
    float2 w1 = make_float2(cs, sn);
    float2 w2 = cmulf(w1, w1);
    float2 w4 = cmulf(w2, w2);
    float2 tch[4] = { make_float2(1.f, 0.f), w1, w2, cmulf(w2, w1) };
    #pragma unroll
    for (int i = 0; i < 16; ++i) {
      #pragma unroll
      for (int j = 0; j < 4; ++j) {
        const int rr = dr6c(4 * i + j);
        z[rr] = cmulf(z[rr], tch[j]);
      }
      #pragma unroll
      for (int j = 0; j < 4; ++j) tch[j] = cmulf(tch[j], w4);
    }
  }
  #pragma unroll
  for (int r = 0; r < 64; ++r) {
    const int k1 = dr6c(r);
    trw[k1 * 64 + ((l + k1) & 63)] = pack2h(z[r].x, z[r].y);
  }
  wave_sync();
  #pragma unroll
  for (int c = 0; c < 64; ++c) {
    uint32 u = trw[l * 64 + ((c + l) & 63)];
    z[c] = make_float2(h2f(u & 0xFFFFu), h2f(u >> 16));
  }
  wave_sync();
  rdif64<-1>(z);
  #pragma unroll
  for (int r = 0; r < 64; ++r) {
    const int k = l + (dr6c(r) << 6);
    const int km = (k < 2048) ? k : (4096 - k);
    const float gk = gn[km];
    z[r] = make_float2(z[r].x * gk, z[r].y * gk);
  }
  rdit64<1>(z);
  {
    float sn, cs;
    __sincosf((float)l * (6.28318530717958647692f / 4096.0f), &sn, &cs);
    float2 v1 = make_float2(cs, sn);
    float2 v2 = cmulf(v1, v1);
    float2 v4 = cmulf(v2, v2);
    float2 tch[4] = { make_float2(1.f, 0.f), v1, v2, cmulf(v2, v1) };
    #pragma unroll
    for (int i = 0; i < 16; ++i) {
      #pragma unroll
      for (int j = 0; j < 4; ++j)
        z[4 * i + j] = cmulf(z[4 * i + j], tch[j]);
      #pragma unroll
      for (int j = 0; j < 4; ++j) tch[j] = cmulf(tch[j], v4);
    }
  }
  #pragma unroll
  for (int r = 0; r < 64; ++r)
    trw[r * 64 + ((l + r) & 63)] = pack2h(z[r].x, z[r].y);
  wave_sync();
  #pragma unroll
  for (int c = 0; c < 64; ++c) {
    uint32 u = trw[l * 64 + ((c + l) & 63)];
    z[c] = make_float2(h2f(u & 0xFFFFu), h2f(u >> 16));
  }
  wave_sync();
  // permute registers to digit-reversed order (dr6c is an involution: 24 swaps),
  // then DIT inverse -> NATURAL n2 order -> sequential store stream.
  #pragma unroll
  for (int j = 0; j < 64; ++j) {
    const int dj = dr6c(j);
    if (dj > j) { float2 tmp = z[j]; z[j] = z[dj]; z[dj] = tmp; }
  }
  rdit64<1>(z);
  uint32* rowp = XFp + ((size_t)bz * 512 + (d0 >> 1)) * 4096;
  const float sc = 1.0f / 4096.0f;
  #pragma unroll
  for (int r = 0; r < 64; ++r)
    rowp[r * 64 + l] = pack2h(z[r].x * sc, z[r].y * sc);
}

// ---------------- A transpose: u32 [b][512 p][4096 s] -> [b][4096 s][512 p] + slot swizzle ----
__global__ __launch_bounds__(256) void kx_a16(const uint32* __restrict__ XFp, uint32* __restrict__ Aswz) {
  __shared__ uint32 tl[64][65];
  const int t = threadIdx.x;
  const int st = blockIdx.x, pt = blockIdx.y, bz = blockIdx.z;
  const uint32* src = XFp + ((size_t)bz * 512 + pt * 64) * 4096 + st * 64;
  #pragma unroll
  for (int i = 0; i < 16; ++i) {
    int p = i * 4 + (t >> 6);
    int s = t & 63;
    tl[p][s] = src[(size_t)p * 4096 + s];
  }
  __syncthreads();
  uint32* dst = Aswz + ((size_t)bz * 4096 + st * 64) * 512 + pt * 64;
  #pragma unroll
  for (int i = 0; i < 16; ++i) {
    int s = i * 4 + (t >> 6);
    int c = t & 63;
    int gsl = ((c & 31) >> 2) ^ (s & 7);
    int u32idx = (c >> 5) * 32 + gsl * 4 + (c & 3);
    dst[(size_t)s * 512 + u32idx] = tl[c][s];
  }
}

// ---------------- fp16 MFMA GEMM: C16[32768x1024] = A*W (fp16 out) ----------------------------
__global__ __launch_bounds__(256) void kx_gemm(const u16* __restrict__ A,
    const u16* __restrict__ Bw, u16* __restrict__ C) {
  __shared__ u16 sm[32768];
  const int t = threadIdx.x, l = t & 63, w = t >> 6;
  const int wm = w >> 1, wn = w & 1;
  const int id = blockIdx.x;
  const int wg = (id & 7) * 256 + (id >> 3);        // XCD-contiguous chunks (2048 blocks)
  const int bm = wg >> 3, bn = wg & 7;
  const int bh = bm >> 5;
  const u16* Ab = A + ((size_t)(bh * 4096 + (bm & 31) * 128)) * 1024;
  const u16* Bb = Bw + (size_t)(bn * 128) * 1024;
  const int fr = l & 15;
  const int lr = l >> 3, lg = l & 7;
  f32x4 acc[4][4];
  #pragma unroll
  for (int m = 0; m < 4; ++m)
    #pragma unroll
    for (int n = 0; n < 4; ++n) acc[m][n] = (f32x4){0.f, 0.f, 0.f, 0.f};

  #define STAGE(KT, BUF) { \
    u16* Ad = sm + (BUF) * 8192; \
    u16* Bd = sm + 16384 + (BUF) * 8192; \
    _Pragma("unroll") \
    for (int j = 0; j < 4; ++j) { \
      int qq = j * 4 + w; \
      glds16((void*)(Ad + qq * 512), Ab + (size_t)(qq * 8 + lr) * 1024 + (KT) * 64 + lg * 8); \
      glds16((void*)(Bd + qq * 512), Bb + (size_t)(qq * 8 + lr) * 1024 + (KT) * 64 + lg * 8); \
    } }

  STAGE(0, 0);
  __syncthreads();
  for (int kt = 0; kt < 16; ++kt) {
    const int cur = kt & 1;
    if (kt < 15) STAGE(kt + 1, cur ^ 1);
    const u16* Ac = sm + cur * 8192;
    const u16* Bc = sm + 16384 + cur * 8192;
    #pragma unroll
    for (int kk = 0; kk < 2; ++kk) {
      const int g8r = kk * 4 + (l >> 4);
      f16x8 af[4], bf[4];
      #pragma unroll
      for (int m = 0; m < 4; ++m) {
        int s = wm * 64 + m * 16 + fr;
        af[m] = *(const f16x8*)&Ac[s * 64 + ((g8r ^ (s & 7)) << 3)];
      }
      #pragma unroll
      for (int n = 0; n < 4; ++n) {
        int nn = wn * 64 + n * 16 + fr;
        bf[n] = *(const f16x8*)&Bc[nn * 64 + ((g8r ^ (nn & 7)) << 3)];
      }
      #pragma unroll
      for (int m = 0; m < 4; ++m)
        #pragma unroll
        for (int n = 0; n < 4; ++n)
          acc[m][n] = __builtin_amdgcn_mfma_f32_16x16x32_f16(af[m], bf[n], acc[m][n], 0, 0, 0);
    }
    __syncthreads();
  }
  float* Cs = (float*)sm;
  const int rl4 = (l >> 4) * 4;
  #pragma unroll
  for (int m = 0; m < 4; ++m) {
    int rbase = wm * 64 + m * 16 + rl4;
    #pragma unroll
    for (int n = 0; n < 4; ++n) {
      int cc = wn * 64 + n * 16 + fr;
      #pragma unroll
      for (int e = 0; e < 4; ++e) {
        int r = rbase + e;
        Cs[r * 128 + (cc ^ (((r >> 2) & 3) << 3))] = acc[m][n][e];
      }
    }
  }
  __syncthreads();
  u16* cgp = C + (size_t)(bm * 128) * 1024 + bn * 128;
  #pragma unroll
  for (int it = 0; it < 16; ++it) {
    int idx = it * 256 + t;
    int r = idx >> 5, c4 = (idx & 31) * 4;
    f32x4 v = *(const f32x4*)&Cs[r * 128 + (c4 ^ (((r >> 2) & 3) << 3))];
    u32x2 pv;
    pv.x = (uint32)f2h(v.x) | ((uint32)f2h(v.y) << 16);
    pv.y = (uint32)f2h(v.z) | ((uint32)f2h(v.w) << 16);
    __builtin_nontemporal_store(pv, (u32x2*)(cgp + (size_t)r * 1024 + c4));
  }
}

// ---------------- tail: LN(xp+out) -> @W_out -> composed quat -> FF ----------------------------
DEV float wred64(float v) {
  #pragma unroll
  for (int m = 32; m; m >>= 1) v += __shfl_xor(v, m);
  return v;
}
DEV float4 ln4q(float4 v, const float* g, const float* b) {
  float m = 0.25f * (v.x + v.y + v.z + v.w);
  float a0 = v.x - m, a1 = v.y - m, a2 = v.z - m, a3 = v.w - m;
  float var = 0.25f * (a0 * a0 + a1 * a1 + a2 * a2 + a3 * a3);
  float rs = 1.0f / sqrtf(var + 1e-5f);
  return make_float4(a0 * rs * g[0] + b[0], a1 * rs * g[1] + b[1],
                     a2 * rs * g[2] + b[2], a3 * rs * g[3] + b[3]);
}
DEV float gelu1(float v) { return 0.5f * v * (1.0f + erff(v * 0.70710678118654752440f)); }

__global__ __launch_bounds__(256) void kx_tail(const u16* __restrict__ G,
    const float* __restrict__ x, const float* __restrict__ W_in, const float* __restrict__ b_in,
    const float* __restrict__ b_attn, const float* __restrict__ lng, const float* __restrict__ lnb,
    const float* __restrict__ W_out, const float* __restrict__ b_out,
    const float* __restrict__ qlr,
    const float* __restrict__ Wf1, const float* __restrict__ bff1,
    const float* __restrict__ Wf2, const float* __restrict__ bff2,
    const float* __restrict__ n1g, const float* __restrict__ n1b,
    const float* __restrict__ n2g, const float* __restrict__ n2b,
    const float* __restrict__ n3g, const float* __restrict__ n3b,
    float* __restrict__ out) {
  const int l = threadIdx.x & 63, w = threadIdx.x >> 6;
  const size_t rg = (size_t)blockIdx.x * 4 + w;
  const float4 x4 = *(const float4*)(x + rg * 4);
  float4 tv[4];
  float lsum = 0.f;
  #pragma unroll
  for (int j = 0; j < 4; ++j) {
    int dd = j * 256 + l * 4;
    uint2 gv = *(const uint2*)(G + rg * 1024 + dd);
    float4 g4 = make_float4(h2f(gv.x & 0xFFFFu), h2f(gv.x >> 16),
                            h2f(gv.y & 0xFFFFu), h2f(gv.y >> 16));
    float4 w0 = *(const float4*)(W_in + dd);
    float4 w1 = *(const float4*)(W_in + 1024 + dd);
    float4 w2 = *(const float4*)(W_in + 2048 + dd);
    float4 w3 = *(const float4*)(W_in + 3072 + dd);
    float4 bi = *(const float4*)(b_in + dd);
    float4 ba = *(const float4*)(b_attn + dd);
    float4 o;
    o.x = g4.x + bi.x + ba.x + x4.x * w0.x + x4.y * w1.x + x4.z * w2.x + x4.w * w3.x;
    o.y = g4.y + bi.y + ba.y + x4.x * w0.y + x4.y * w1.y + x4.z * w2.y + x4.w * w3.y;
    o.z = g4.z + bi.z + ba.z + x4.x * w0.z + x4.y * w1.z + x4.z * w2.z + x4.w * w3.z;
    o.w = g4.w + bi.w + ba.w + x4.x * w0.w + x4.y * w1.w + x4.z * w2.w + x4.w * w3.w;
    tv[j] = o;
    lsum += o.x + o.y + o.z + o.w;
  }
  const float mean = wred64(lsum) * (1.0f / 1024.0f);
  float vsum = 0.f;
  #pragma unroll
  for (int j = 0; j < 4; ++j) {
    float a0 = tv[j].x - mean, a1 = tv[j].y - mean, a2 = tv[j].z - mean, a3 = tv[j].w - mean;
    vsum += a0 * a0 + a1 * a1 + a2 * a2 + a3 * a3;
  }
  const float rstd = 1.0f / sqrtf(wred64(vsum) * (1.0f / 1024.0f) + 1e-5f);
  float4 aq = make_float4(0.f, 0.f, 0.f, 0.f);
  #pragma unroll
  for (int j = 0; j < 4; ++j) {
    int dd = j * 256 + l * 4;
    float4 gg = *(const float4*)(lng + dd);
    float4 bb = *(const float4*)(lnb + dd);
    float av[4];
    av[0] = (tv[j].x - mean) * rstd * gg.x + bb.x;
    av[1] = (tv[j].y - mean) * rstd * gg.y + bb.y;
    av[2] = (tv[j].z - mean) * rstd * gg.z + bb.z;
    av[3] = (tv[j].w - mean) * rstd * gg.w + bb.w;
    #pragma unroll
    for (int e = 0; e < 4; ++e) {
      float4 wr = *(const float4*)(W_out + (size_t)(dd + e) * 4);
      aq.x = fmaf(av[e], wr.x, aq.x);
      aq.y = fmaf(av[e], wr.y, aq.y);
      aq.z = fmaf(av[e], wr.z, aq.z);
      aq.w = fmaf(av[e], wr.w, aq.w);
    }
  }
  aq.x = wred64(aq.x) + b_out[0];
  aq.y = wred64(aq.y) + b_out[1];
  aq.z = wred64(aq.z) + b_out[2];
  aq.w = wred64(aq.w) + b_out[3];
  float4 q1 = make_float4(x4.x + aq.x, x4.y + aq.y, x4.z + aq.z, x4.w + aq.w);
  float4 hq = qne(ln4q(q1, n1g, n1b));
  const float4 QL = *(const float4*)qlr;
  const float4 QRC = *(const float4*)(qlr + 4);
  float4 o = qne(qmul4(qmul4(QL, hq), QRC));
  float4 h2 = qne(ln4q(make_float4(hq.x + o.x, hq.y + o.y, hq.z + o.z, hq.w + o.w), n2g, n2b));
  float ffx = 0.f, ffy = 0.f, ffz = 0.f, ffw = 0.f;
  if (l < 16) {
    float uv = bff1[l] + h2.x * Wf1[l] + h2.y * Wf1[16 + l] + h2.z * Wf1[32 + l] + h2.w * Wf1[48 + l];
    uv = gelu1(uv);
    float4 w2r = *(const float4*)(Wf2 + l * 4);
    ffx = uv * w2r.x; ffy = uv * w2r.y; ffz = uv * w2r.z; ffw = uv * w2r.w;
  }
  ffx = wred64(ffx) + bff2[0];
  ffy = wred64(ffy) + bff2[1];
  ffz = wred64(ffz) + bff2[2];
  ffw = wred64(ffw) + bff2[3];
  float4 h3 = qne(ln4q(make_float4(h2.x + ffx, h2.y + ffy, h2.z + ffz, h2.w + ffw), n3g, n3b));
  if (l == 0) *(float4*)(out + rg * 4) = h3;
}

extern "C" void kernel_launch(void* const* d_in, const int* in_sizes, int n_in,
                              void* d_out, int out_size, void* d_ws, size_t ws_size,
                              hipStream_t stream) {
  (void)in_sizes; (void)n_in; (void)out_size;
  const float* x      = (const float*)d_in[0];
  const float* W_in   = (const float*)d_in[1];
  const float* b_in   = (const float*)d_in[2];
  const float* abase  = (const float*)d_in[3];
  const float* pshift = (const float*)d_in[4];
  const float* Wattn  = (const float*)d_in[5];
  const float* battn  = (const float*)d_in[6];
  const float* lng    = (const float*)d_in[7];
  const float* lnb    = (const float*)d_in[8];
  const float* Wout   = (const float*)d_in[9];
  const float* bout   = (const float*)d_in[10];
  const float* thL    = (const float*)d_in[11];
  const float* thR    = (const float*)d_in[12];
  const float* Wf1    = (const float*)d_in[13];
  const float* bff1   = (const float*)d_in[14];
  const float* Wf2    = (const float*)d_in[15];
  const float* bff2   = (const float*)d_in[16];
  const float* n1g    = (const float*)d_in[17];
  const float* n1b    = (const float*)d_in[18];
  const float* n2g    = (const float*)d_in[19];
  const float* n2b    = (const float*)d_in[20];
  const float* n3g    = (const float*)d_in[21];
  const float* n3b    = (const float*)d_in[22];

  if (ws_size < (size_t)138459204) return;  // ~132 MiB
  char* ws = (char*)d_ws;
  float2* Zmid  = (float2*)ws;                       // 128MiB (fractal only)
  uint32* XFp   = (uint32*)ws;                       // 64MiB (filter out, u32 pair [b][p][s])
  u16*   Aswz   = (u16*)(ws + 67108864);             // 64MiB (A fp16 [b][s][d] pre-swizzled)
  u16*   C16    = (u16*)ws;                          // 64MiB fp16 gemm out (overlays dead XFp)
  u16*   W2h    = (u16*)(ws + 134217728);            // 2MiB fp16 W^T pre-swizzled
  float* gainsw = (float*)(ws + 136314880);          // ~1MiB gain table [128][2064]
  float* qlrw   = (float*)(ws + 137400320);          // 32B composed quats
  float* partials = (float*)(ws + 138412032);        // 32KB
  float* sparts   = (float*)(ws + 138444800);        // 6KB
  float* alphaw   = (float*)(ws + 138450944);        // 32B
  float* geluw    = (float*)(ws + 138451008);        // 8.2KB

  kx_fr_pass1<<<dim3(256, 8), 512, 0, stream>>>(x, W_in, b_in, Zmid);
  kx_fr_pass2<<<dim3(512, 8), 128, 0, stream>>>(Zmid, partials, sparts);
  kx_finalize<<<1, 512, 0, stream>>>(partials, sparts, alphaw, geluw);
  kx_gains<<<128, 256, 0, stream>>>(alphaw, geluw, abase, pshift, thL, thR, gainsw, qlrw);
  kx_wt<<<dim3(16, 16), 256, 0, stream>>>(Wattn, W2h);
  kx_filter<<<dim3(16, 16, 8), 128, 0, stream>>>(x, W_in, b_in, gainsw, XFp);
  kx_a16<<<dim3(64, 8, 8), 256, 0, stream>>>(XFp, (uint32*)Aswz);
  kx_gemm<<<2048, 256, 0, stream>>>(Aswz, W2h, C16);
  kx_tail<<<8192, 256, 0, stream>>>(C16, x, W_in, b_in, battn, lng, lnb, Wout, bout,
                                    qlrw, Wf1, bff1, Wf2, bff2,
                                    n1g, n1b, n2g, n2b, n3g, n3b, (float*)d_out);
}

// Round 17
// 537.382 us; speedup vs baseline: 1.0083x; 1.0083x over previous
//
#include <hip/hip_runtime.h>
#include <hip/hip_bf16.h>
#include <math.h>

// PsiQRH block, MI355X. B=8 S=4096 QD=4 DM=1024 H=16 HD=64.
// Round 16: kx_filter final IFFT via in-place dr6 permutation + rdit64 so the
// global store order is SEQUENTIAL (r12-style clean write stream; r13-15's
// digit-reversed segment order caused 4x TCC write amplification).

#define DEV static __device__ __forceinline__
typedef unsigned int uint32;
typedef unsigned short u16;

typedef __attribute__((ext_vector_type(8))) _Float16 f16x8;
typedef __attribute__((ext_vector_type(4))) float f32x4;
typedef __attribute__((ext_vector_type(2))) unsigned int u32x2;

DEV float2 cmulf(float2 a, float2 b) {
  return make_float2(a.x * b.x - a.y * b.y, a.x * b.y + a.y * b.x);
}
DEV u16 f2h(float f) {
  union { _Float16 h; u16 u; } v;
  v.h = (_Float16)f;
  return v.u;
}
DEV float h2f(uint32 u) {
  union { u16 s; _Float16 h; } v;
  v.s = (u16)u;
  return (float)v.h;
}
DEV uint32 pack2h(float a, float b) {
  return (uint32)f2h(a) | ((uint32)f2h(b) << 16);
}
DEV void glds16(void* lds, const void* g) {
  __builtin_amdgcn_global_load_lds((const __attribute__((address_space(1))) unsigned int*)g,
                                   (__attribute__((address_space(3))) unsigned int*)lds, 16, 0, 0);
}
DEV void wave_sync() {
  asm volatile("s_waitcnt lgkmcnt(0)" ::: "memory");
  __builtin_amdgcn_sched_barrier(0);
}
DEV int dr10(int v) {   // base-4 digit reversal, 10-bit
  int r = (int)(__brev((unsigned)v) >> 22);
  return ((r & 0x155) << 1) | ((r & 0x2AA) >> 1);
}
constexpr int dr6c(int v) {   // base-4 digit reversal, 6-bit (involution)
  return ((v & 3) << 4) | (v & 12) | ((v >> 4) & 3);
}

// quarter-wave table: CQ[j] = cos(pi*j/32), j=0..16
constexpr float CQ[17] = {
  1.0f, 0.995184726672197f, 0.980785280403230f, 0.956940335732209f,
  0.923879532511287f, 0.881921264348355f, 0.831469612302545f, 0.773010453362737f,
  0.707106781186548f, 0.634393284163645f, 0.555570233019602f, 0.471396736825998f,
  0.382683432365090f, 0.290284677254462f, 0.195090322016128f, 0.098017140329561f, 0.0f };
constexpr float twc64(int j) {   // cos(2*pi*j/64)
  return (j & 63) <= 16 ? CQ[j & 63]
       : (j & 63) <= 32 ? -CQ[32 - (j & 63)]
       : (j & 63) <= 48 ? -CQ[(j & 63) - 32] : CQ[64 - (j & 63)];
}
constexpr float tws64(int j) {   // sin(2*pi*j/64)
  return (j & 63) <= 16 ? CQ[16 - (j & 63)]
       : (j & 63) <= 32 ? CQ[(j & 63) - 16]
       : (j & 63) <= 48 ? -CQ[48 - (j & 63)] : -CQ[(j & 63) - 48];
}

// cos/sin of pi*j/16, j = 0..15 (stage-offset twiddles for LDS FFTs)
constexpr float CR_C[16] = {
  1.0f, 0.980785280403230f, 0.923879532511287f, 0.831469612302545f,
  0.707106781186548f, 0.555570233019602f, 0.382683432365090f, 0.195090322016128f,
  0.0f, -0.195090322016128f, -0.382683432365090f, -0.555570233019602f,
  -0.707106781186548f, -0.831469612302545f, -0.923879532511287f, -0.980785280403230f };
constexpr float CR_S[16] = {
  0.0f, 0.195090322016128f, 0.382683432365090f, 0.555570233019602f,
  0.707106781186548f, 0.831469612302545f, 0.923879532511287f, 0.980785280403230f,
  1.0f, 0.980785280403230f, 0.923879532511287f, 0.831469612302545f,
  0.707106781186548f, 0.555570233019602f, 0.382683432365090f, 0.195090322016128f };

// ---------------- in-register 64-pt radix-4 FFTs (fully unrolled, const twiddles) -------------
template<int SGN>
DEV void rdif64(float2* z) {
  #pragma unroll
  for (int j = 0; j < 16; ++j) {
    float2 x0 = z[j], x1 = z[j + 16], x2 = z[j + 32], x3 = z[j + 48];
    float2 s0 = make_float2(x0.x + x2.x, x0.y + x2.y);
    float2 s1 = make_float2(x0.x - x2.x, x0.y - x2.y);
    float2 s2 = make_float2(x1.x + x3.x, x1.y + x3.y);
    float2 d  = make_float2(x1.x - x3.x, x1.y - x3.y);
    float2 s3 = (SGN < 0) ? make_float2(d.y, -d.x) : make_float2(-d.y, d.x);
    z[j] = make_float2(s0.x + s2.x, s0.y + s2.y);
    const float2 tf1 = make_float2(twc64(j),     (float)SGN * tws64(j));
    const float2 tf2 = make_float2(twc64(2 * j), (float)SGN * tws64(2 * j));
    const float2 tf3 = make_float2(twc64(3 * j), (float)SGN * tws64(3 * j));
    z[j + 16] = cmulf(make_float2(s1.x + s3.x, s1.y + s3.y), tf1);
    z[j + 32] = cmulf(make_float2(s0.x - s2.x, s0.y - s2.y), tf2);
    z[j + 48] = cmulf(make_float2(s1.x - s3.x, s1.y - s3.y), tf3);
  }
  #pragma unroll
  for (int b = 0; b < 64; b += 16)
    #pragma unroll
    for (int j = 0; j < 4; ++j) {
      const int i = b + j;
      float2 x0 = z[i], x1 = z[i + 4], x2 = z[i + 8], x3 = z[i + 12];
      float2 s0 = make_float2(x0.x + x2.x, x0.y + x2.y);
      float2 s1 = make_float2(x0.x - x2.x, x0.y - x2.y);
      float2 s2 = make_float2(x1.x + x3.x, x1.y + x3.y);
      float2 d  = make_float2(x1.x - x3.x, x1.y - x3.y);
      float2 s3 = (SGN < 0) ? make_float2(d.y, -d.x) : make_float2(-d.y, d.x);
      z[i] = make_float2(s0.x + s2.x, s0.y + s2.y);
      const float2 tf1 = make_float2(twc64(4 * j),  (float)SGN * tws64(4 * j));
      const float2 tf2 = make_float2(twc64(8 * j),  (float)SGN * tws64(8 * j));
      const float2 tf3 = make_float2(twc64(12 * j), (float)SGN * tws64(12 * j));
      z[i + 4]  = cmulf(make_float2(s1.x + s3.x, s1.y + s3.y), tf1);
      z[i + 8]  = cmulf(make_float2(s0.x - s2.x, s0.y - s2.y), tf2);
      z[i + 12] = cmulf(make_float2(s1.x - s3.x, s1.y - s3.y), tf3);
    }
  #pragma unroll
  for (int b = 0; b < 64; b += 4) {
    float2 x0 = z[b], x1 = z[b + 1], x2 = z[b + 2], x3 = z[b + 3];
    float2 s0 = make_float2(x0.x + x2.x, x0.y + x2.y);
    float2 s1 = make_float2(x0.x - x2.x, x0.y - x2.y);
    float2 s2 = make_float2(x1.x + x3.x, x1.y + x3.y);
    float2 d  = make_float2(x1.x - x3.x, x1.y - x3.y);
    float2 s3 = (SGN < 0) ? make_float2(d.y, -d.x) : make_float2(-d.y, d.x);
    z[b]     = make_float2(s0.x + s2.x, s0.y + s2.y);
    z[b + 1] = make_float2(s1.x + s3.x, s1.y + s3.y);
    z[b + 2] = make_float2(s0.x - s2.x, s0.y - s2.y);
    z[b + 3] = make_float2(s1.x - s3.x, s1.y - s3.y);
  }
}

template<int SGN>
DEV void rdit64(float2* z) {
  #pragma unroll
  for (int b = 0; b < 64; b += 4) {
    float2 b0 = z[b], b1 = z[b + 1], b2 = z[b + 2], b3 = z[b + 3];
    float2 t0 = make_float2(b0.x + b2.x, b0.y + b2.y);
    float2 t1 = make_float2(b0.x - b2.x, b0.y - b2.y);
    float2 t2 = make_float2(b1.x + b3.x, b1.y + b3.y);
    float2 d  = make_float2(b1.x - b3.x, b1.y - b3.y);
    float2 t3 = (SGN > 0) ? make_float2(-d.y, d.x) : make_float2(d.y, -d.x);
    z[b]     = make_float2(t0.x + t2.x, t0.y + t2.y);
    z[b + 1] = make_float2(t1.x + t3.x, t1.y + t3.y);
    z[b + 2] = make_float2(t0.x - t2.x, t0.y - t2.y);
    z[b + 3] = make_float2(t1.x - t3.x, t1.y - t3.y);
  }
  #pragma unroll
  for (int b = 0; b < 64; b += 16)
    #pragma unroll
    for (int j = 0; j < 4; ++j) {
      const int i = b + j;
      const float2 tf1 = make_float2(twc64(4 * j),  (float)SGN * tws64(4 * j));
      const float2 tf2 = make_float2(twc64(8 * j),  (float)SGN * tws64(8 * j));
      const float2 tf3 = make_float2(twc64(12 * j), (float)SGN * tws64(12 * j));
      float2 b0 = z[i];
      float2 b1 = cmulf(z[i + 4], tf1);
      float2 b2 = cmulf(z[i + 8], tf2);
      float2 b3 = cmulf(z[i + 12], tf3);
      float2 t0 = make_float2(b0.x + b2.x, b0.y + b2.y);
      float2 t1 = make_float2(b0.x - b2.x, b0.y - b2.y);
      float2 t2 = make_float2(b1.x + b3.x, b1.y + b3.y);
      float2 d  = make_float2(b1.x - b3.x, b1.y - b3.y);
      float2 t3 = (SGN > 0) ? make_float2(-d.y, d.x) : make_float2(d.y, -d.x);
      z[i]      = make_float2(t0.x + t2.x, t0.y + t2.y);
      z[i + 4]  = make_float2(t1.x + t3.x, t1.y + t3.y);
      z[i + 8]  = make_float2(t0.x - t2.x, t0.y - t2.y);
      z[i + 12] = make_float2(t1.x - t3.x, t1.y - t3.y);
    }
  #pragma unroll
  for (int j = 0; j < 16; ++j) {
    const float2 tf1 = make_float2(twc64(j),     (float)SGN * tws64(j));
    const float2 tf2 = make_float2(twc64(2 * j), (float)SGN * tws64(2 * j));
    const float2 tf3 = make_float2(twc64(3 * j), (float)SGN * tws64(3 * j));
    float2 b0 = z[j];
    float2 b1 = cmulf(z[j + 16], tf1);
    float2 b2 = cmulf(z[j + 32], tf2);
    float2 b3 = cmulf(z[j + 48], tf3);
    float2 t0 = make_float2(b0.x + b2.x, b0.y + b2.y);
    float2 t1 = make_float2(b0.x - b2.x, b0.y - b2.y);
    float2 t2 = make_float2(b1.x + b3.x, b1.y + b3.y);
    float2 d  = make_float2(b1.x - b3.x, b1.y - b3.y);
    float2 t3 = (SGN > 0) ? make_float2(-d.y, d.x) : make_float2(d.y, -d.x);
    z[j]      = make_float2(t0.x + t2.x, t0.y + t2.y);
    z[j + 16] = make_float2(t1.x + t3.x, t1.y + t3.y);
    z[j + 32] = make_float2(t0.x - t2.x, t0.y - t2.y);
    z[j + 48] = make_float2(t1.x - t3.x, t1.y - t3.y);
  }
}

// Radix-4 DIF over LDS, natural in -> digit-reversed out (negative exponent).
template<int L, int NLOG, int NSUB, bool WL>
DEV void dif4_stages(float2* F, int lg) {
  #pragma unroll
  for (int st = 0; st < NLOG / 2; ++st) {
    const int qlog = NLOG - 2 - 2 * st;
    const int q = 1 << qlog;
    float bs, bc;
    __sincosf((float)(lg & (q - 1)) * (-1.57079632679489661923f / (float)q), &bs, &bc);
    const float2 base = make_float2(bc, bs);
    #pragma unroll
    for (int u = 0; u < NSUB * (1 << (NLOG - 2)) / L; ++u) {
      const int sub = (u * L) >> (NLOG - 2);
      const int bf = ((u * L) & ((1 << (NLOG - 2)) - 1)) + lg;
      const int jj = ((u * L) % q) * 8 / q;
      const int i1 = (sub << NLOG) + ((bf >> qlog) << (qlog + 2)) + (bf & (q - 1));
      float2 x0 = F[i1], x1 = F[i1 + q], x2 = F[i1 + 2 * q], x3 = F[i1 + 3 * q];
      float2 s0 = make_float2(x0.x + x2.x, x0.y + x2.y);
      float2 s1 = make_float2(x0.x - x2.x, x0.y - x2.y);
      float2 s2 = make_float2(x1.x + x3.x, x1.y + x3.y);
      float2 dq = make_float2(x1.x - x3.x, x1.y - x3.y);
      float2 s3 = make_float2(dq.y, -dq.x);               // -i*(x1-x3)
      F[i1] = make_float2(s0.x + s2.x, s0.y + s2.y);
      if (qlog == 0) {
        F[i1 + 1] = make_float2(s1.x + s3.x, s1.y + s3.y);
        F[i1 + 2] = make_float2(s0.x - s2.x, s0.y - s2.y);
        F[i1 + 3] = make_float2(s1.x - s3.x, s1.y - s3.y);
      } else {
        const float2 tf1 = (jj == 0) ? base : cmulf(base, make_float2(CR_C[jj], -CR_S[jj]));
        const float2 tf2 = cmulf(tf1, tf1);
        const float2 tf3 = cmulf(tf2, tf1);
        F[i1 + q]     = cmulf(make_float2(s1.x + s3.x, s1.y + s3.y), tf1);
        F[i1 + 2 * q] = cmulf(make_float2(s0.x - s2.x, s0.y - s2.y), tf2);
        F[i1 + 3 * q] = cmulf(make_float2(s1.x - s3.x, s1.y - s3.y), tf3);
      }
    }
    if (WL) wave_sync(); else __syncthreads();
  }
}

// ---------------- quaternion helpers ----------------------------------------------------------
DEV float4 qmul4(float4 a, float4 b) {
  return make_float4(
    a.x * b.x - a.y * b.y - a.z * b.z - a.w * b.w,
    a.x * b.y + a.y * b.x + a.z * b.w - a.w * b.z,
    a.x * b.z - a.y * b.w + a.z * b.x + a.w * b.y,
    a.x * b.w + a.y * b.z - a.z * b.y + a.w * b.x);
}
DEV float4 qne(float4 q) {
  float n = sqrtf(q.x * q.x + q.y * q.y + q.z * q.z + q.w * q.w) + 1e-8f;
  float r = 1.0f / n;
  return make_float4(q.x * r, q.y * r, q.z * r, q.w * r);
}

// ---------------- fractal pass 1: 1024-pt radix-4 FFTs, wave-private (stride 1028) -----------
__global__ __launch_bounds__(512) void kx_fr_pass1(const float* __restrict__ x,
    const float* __restrict__ W_in, const float* __restrict__ b_in,
    float2* __restrict__ zmid) {
  __shared__ float2 fb[8 * 1028];
  const int t = threadIdx.x, l = t & 63, w = t >> 6;
  const int btile = blockIdx.x, bz = blockIdx.y;
  const int bcol = btile * 8 + w;
  const int d = 2 * (bcol & 511);
  const int soff = bcol >> 9;
  const float w00 = W_in[d],     w10 = W_in[1024 + d], w20 = W_in[2048 + d], w30 = W_in[3072 + d];
  const float w01 = W_in[d + 1], w11 = W_in[1025 + d], w21 = W_in[2049 + d], w31 = W_in[3073 + d];
  const float bi0 = b_in[d], bi1 = b_in[d + 1];
  const float* xb = x + (size_t)bz * 4096 * 4;
  float2* fbw = fb + w * 1028;
  #pragma unroll
  for (int i = 0; i < 16; ++i) {
    int a = i * 64 + l;
    int s = 4 * a + soff;
    float4 xv = *(const float4*)(xb + (size_t)s * 4);
    float z0 = fmaf(xv.x, w00, fmaf(xv.y, w10, fmaf(xv.z, w20, fmaf(xv.w, w30, bi0))));
    float z1 = fmaf(xv.x, w01, fmaf(xv.y, w11, fmaf(xv.z, w21, fmaf(xv.w, w31, bi1))));
    fbw[a] = make_float2(z0, z1);
  }
  wave_sync();
  dif4_stages<64, 10, 1, true>(fbw, l);
  __syncthreads();
  float2* dst = zmid + (size_t)bz * (1024 * 2048);
  #pragma unroll
  for (int i = 0; i < 16; ++i) {
    int idx = i * 512 + t;
    int w8 = idx & 7, cnat = idx >> 3;
    float2 v = fb[w8 * 1028 + dr10(cnat)];
    dst[(size_t)cnat * 2048 + btile * 8 + w8] = v;
  }
}

DEV float block_reduce128(float* red, int t, float v) {
  red[t] = v; __syncthreads();
  for (int s = 64; s; s >>= 1) { if (t < s) red[t] += red[t + s]; __syncthreads(); }
  float r = red[0]; __syncthreads();
  return r;
}

// ---------------- fractal pass 2: reg-fused r2 + 2x(1024 radix-4); __logf moments ------------
__global__ __launch_bounds__(128) void kx_fr_pass2(const float2* __restrict__ zmid,
    float* __restrict__ partials, float* __restrict__ sparts) {
  __shared__ float2 fb[2 * 2052];
  __shared__ float red[128];
  const int t = threadIdx.x, l = t & 63, w = t >> 6;   // w in {0,1}
  const int cg = blockIdx.x, bz = blockIdx.y;
  const int c = (cg == 0) ? (w ? 512 : 0) : (w ? (1024 - cg) : cg);
  const float2* src = zmid + ((size_t)bz * 1024 + c) * 2048;
  float2* fbc = fb + w * 2052;
  float2 rot[4], stp4;
  {
    float sn, cs;
    __sincosf((float)(l * c) * (-6.28318530717958647692f / 2097152.0f), &sn, &cs);
    rot[0] = make_float2(cs, sn);
    float2 stp;
    __sincosf((float)c * (-6.28318530717958647692f / 32768.0f), &sn, &cs);
    stp = make_float2(cs, sn);
    rot[1] = cmulf(rot[0], stp);
    float2 stp2 = cmulf(stp, stp);
    rot[2] = cmulf(rot[0], stp2);
    rot[3] = cmulf(rot[1], stp2);
    stp4 = cmulf(stp2, stp2);
  }
  float2 zr[32];
  #pragma unroll
  for (int i = 0; i < 32; ++i) {
    int bb = i * 64 + l;
    zr[i] = cmulf(src[bb], rot[i & 3]);
    rot[i & 3] = cmulf(rot[i & 3], stp4);
  }
  {
    float bs, bc;
    __sincosf((float)l * (-3.14159265358979323846f / 1024.0f), &bs, &bc);
    const float2 b2 = make_float2(bc, bs);
    #pragma unroll
    for (int u = 0; u < 16; ++u) {
      const float2 tf = (u == 0) ? b2 : cmulf(b2, make_float2(CR_C[u], -CR_S[u]));
      int i1 = u * 64 + l;
      float2 a0 = zr[u], a1 = zr[u + 16];
      fbc[i1] = make_float2(a0.x + a1.x, a0.y + a1.y);
      fbc[i1 + 1024] = cmulf(make_float2(a0.x - a1.x, a0.y - a1.y), tf);
    }
    wave_sync();
  }
  dif4_stages<64, 10, 2, true>(fbc, l);
  __syncthreads();
  float t0 = 0.f, t1 = 0.f, s0 = 0.f, s1 = 0.f, s2 = 0.f;
  if (cg != 0) {
    const float2* fbm = fb + (1 - w) * 2052;
    float2 pw[32];
    pw[0] = make_float2(1.f, 0.f);
    {
      float sn, cs;
      __sincosf(-3.14159265358979323846f / 2048.0f, &sn, &cs);
      float2 w1 = make_float2(cs, sn);
      #pragma unroll
      for (int j = 1; j < 32; ++j) pw[j] = cmulf(pw[j - 1], w1);
    }
    const int drl = (l & 3) * 256 + ((l >> 2) & 3) * 64 + ((l >> 4) & 3) * 16;
    float2 base2;
    {
      float sn, cs;
      __sincosf((float)drl * (-3.14159265358979323846f / 1024.0f), &sn, &cs);
      float2 lf = make_float2(cs, sn);
      __sincosf((float)c * (-6.28318530717958647692f / 4194304.0f), &sn, &cs);
      base2 = cmulf(make_float2(cs, sn), lf);
    }
    #pragma unroll
    for (int i = 0; i < 32; ++i) {
      const int p = i * 64 + l;
      const int dri = (i & 3) * 4 + ((i >> 2) & 3);
      const int top = i >> 4;
      const int dd = 2 * (drl + dri) + top;
      float2 Zk = fbc[p];
      float2 Zm = fbm[2047 - p];
      float2 E = make_float2(0.5f * (Zk.x + Zm.x), 0.5f * (Zk.y - Zm.y));
      float2 A = make_float2(Zk.x - Zm.x, Zk.y + Zm.y);
      float2 O = make_float2(0.5f * A.y, -0.5f * A.x);
      float2 urot = cmulf(base2, pw[2 * dri + top]);
      float2 U = cmulf(urot, O);
      float Xr = E.x + U.x, Xi = E.y + U.y;
      float P = Xr * Xr + Xi * Xi;
      int k = c + (dd << 10);
      float fr = (float)k * (1.0f / 4194304.0f);
      if (fr > 0.01f && fr < 0.5f) {
        float lp = __logf(P + 1e-10f);
        float lk = __logf(fr + 1e-10f);
        t0 += lp; t1 += lk * lp;
        s0 += 1.0f; s1 += lk; s2 += lk * lk;
      }
    }
  } else {
    const float2* fbm = fbc;   // self-mirrored columns (c = 0, 512)
    float2 urot;
    {
      float sn, cs;
      __sincosf((float)(c + l * 1024) * (-6.28318530717958647692f / 4194304.0f), &sn, &cs);
      urot = make_float2(cs, sn);
    }
    const float2 ustp = make_float2(0.995184726672197f, -0.0980171403295606f); // e^{-i pi/32}
    #pragma unroll
    for (int i = 0; i < 32; ++i) {
      int dd = i * 64 + l;
      int md = (c == 0) ? ((2048 - dd) & 2047) : (2047 - dd);
      int pk = ((dd & 1) << 10) | dr10(dd >> 1);
      int pm = ((md & 1) << 10) | dr10(md >> 1);
      float2 Zk = fbc[pk];
      float2 Zm = fbm[pm];
      float2 E = make_float2(0.5f * (Zk.x + Zm.x), 0.5f * (Zk.y - Zm.y));
      float2 A = make_float2(Zk.x - Zm.x, Zk.y + Zm.y);
      float2 O = make_float2(0.5f * A.y, -0.5f * A.x);
      float2 U = cmulf(urot, O);
      float Xr = E.x + U.x, Xi = E.y + U.y;
      float P = Xr * Xr + Xi * Xi;
      int k = c + (dd << 10);
      float fr = (float)k * (1.0f / 4194304.0f);
      if (fr > 0.01f && fr < 0.5f) {
        float lp = __logf(P + 1e-10f);
        float lk = __logf(fr + 1e-10f);
        t0 += lp; t1 += lk * lp;
        s0 += 1.0f; s1 += lk; s2 += lk * lk;
      }
      urot = cmulf(urot, ustp);
    }
  }
  float T0 = block_reduce128(red, t, t0);
  float T1 = block_reduce128(red, t, t1);
  if (t == 0) {
    partials[((size_t)bz * 512 + cg) * 2 + 0] = T0;
    partials[((size_t)bz * 512 + cg) * 2 + 1] = T1;
  }
  if (bz == 0) {
    float S0 = block_reduce128(red, t, s0);
    float S1 = block_reduce128(red, t, s1);
    float S2 = block_reduce128(red, t, s2);
    if (t == 0) { sparts[cg * 3] = S0; sparts[cg * 3 + 1] = S1; sparts[cg * 3 + 2] = S2; }
  }
}

DEV float block_reduce512(float* sh, int t, float v) {
  sh[t] = v; __syncthreads();
  for (int s = 256; s; s >>= 1) { if (t < s) sh[t] += sh[t + s]; __syncthreads(); }
  float r = sh[0]; __syncthreads();
  return r;
}

// ---------------- finalize: alpha[b]; gelu_k table ---------------------------------------------
__global__ __launch_bounds__(512) void kx_finalize(const float* __restrict__ partials,
    const float* __restrict__ sparts, float* __restrict__ alpha, float* __restrict__ gelu) {
  __shared__ float sh[512];
  __shared__ float lk[4096];
  const int t = threadIdx.x;
  float S0 = block_reduce512(sh, t, sparts[t * 3 + 0]);
  float S1 = block_reduce512(sh, t, sparts[t * 3 + 1]);
  float S2 = block_reduce512(sh, t, sparts[t * 3 + 2]);
  float mk = S1 / S0;
  float var = S2 - mk * S1;
  for (int b = 0; b < 8; ++b) {
    float T0 = block_reduce512(sh, t, partials[((size_t)b * 512 + t) * 2 + 0]);
    float T1 = block_reduce512(sh, t, partials[((size_t)b * 512 + t) * 2 + 1]);
    if (t == 0) {
      float cov = T1 - mk * T0;
      float beta = -cov / (var + 1e-10f);
      float D = fminf(fmaxf((3.0f - beta) * 0.5f, 0.5f), 1.5f);
      alpha[b] = fminf(fmaxf(1.0f + 0.8f * (D - 1.0f), 0.1f), 3.0f);
    }
  }
  for (int s = t; s < 4096; s += 512) {
    int m = (s < 2048) ? s : (4096 - s);
    lk[s] = logf((float)m * (1.0f / 4096.0f) + 1e-8f);
  }
  __syncthreads();
  float ls = 0.f;
  for (int s = t; s < 4096; s += 512) ls += lk[s];
  float mean = block_reduce512(sh, t, ls) * (1.0f / 4096.0f);
  float vs = 0.f;
  for (int s = t; s < 4096; s += 512) { float dv = lk[s] - mean; vs += dv * dv; }
  float sd = sqrtf(block_reduce512(sh, t, vs) * (1.0f / 4095.0f));
  for (int k = t; k < 2049; k += 512) {
    float xn = (lk[k] - mean) / (sd + 1e-8f);
    gelu[k] = 0.5f * xn * (1.0f + erff(xn * 0.70710678118654752440f));
  }
}

// ---------------- gain table + composed quaternions -------------------------------------------
__global__ __launch_bounds__(256) void kx_gains(const float* __restrict__ alpha,
    const float* __restrict__ gelu, const float* __restrict__ abase,
    const float* __restrict__ pshift, const float* __restrict__ thL,
    const float* __restrict__ thR, float* __restrict__ gains, float* __restrict__ qlr) {
  const int bh = blockIdx.x;    // 0..127
  const float aa = abase[bh & 15] * alpha[bh >> 4];
  const float ps = pshift[bh & 15];
  for (int k = threadIdx.x; k < 2049; k += 256)
    gains[(size_t)bh * 2064 + k] = cosf(fmaf(aa, gelu[k], ps));
  if (bh == 0 && threadIdx.x == 0) {
    float4 QL = make_float4(1.f, 0.f, 0.f, 0.f);
    float4 QRC = make_float4(1.f, 0.f, 0.f, 0.f);
    for (int it = 0; it < 4; ++it) {
      float s0, c0, s1, c1, s2, c2;
      sincosf(0.5f * thL[it * 3 + 0], &s0, &c0);
      sincosf(0.5f * thL[it * 3 + 1], &s1, &c1);
      sincosf(0.5f * thL[it * 3 + 2], &s2, &c2);
      float4 qL = qne(make_float4(c0 * c1 * c2, s0 * c1 * c2, c0 * s1 * c2, c0 * c1 * s2));
      QL = qmul4(qL, QL);
      sincosf(0.5f * thR[it * 3 + 0], &s0, &c0);
      sincosf(0.5f * thR[it * 3 + 1], &s1, &c1);
      sincosf(0.5f * thR[it * 3 + 2], &s2, &c2);
      float4 qR = qne(make_float4(c0 * c1 * c2, s0 * c1 * c2, c0 * s1 * c2, c0 * c1 * s2));
      QRC = qmul4(QRC, make_float4(qR.x, -qR.y, -qR.z, -qR.w));
    }
    *(float4*)qlr = QL;
    *(float4*)(qlr + 4) = QRC;
  }
}

// ---------------- W_attn_out transpose -> fp16 [n][d] pre-swizzled ----------------------------
__global__ __launch_bounds__(256) void kx_wt(const float* __restrict__ W, u16* __restrict__ Wt) {
  __shared__ float tile[64][65];
  const int t = threadIdx.x;
  const int nt = blockIdx.x, dt = blockIdx.y;
  #pragma unroll
  for (int i = 0; i < 16; ++i) {
    int idx = i * 256 + t;
    int r = idx >> 6, cc = idx & 63;
    tile[r][cc] = W[(size_t)(dt * 64 + r) * 1024 + nt * 64 + cc];
  }
  __syncthreads();
  #pragma unroll
  for (int i = 0; i < 2; ++i) {
    int task = i * 256 + t;
    int nl = task >> 3, g = task & 7;
    union { u16 h[8]; uint4 v; } pk;
    #pragma unroll
    for (int k = 0; k < 8; ++k) pk.h[k] = f2h(tile[g * 8 + k][nl]);
    size_t idx = (size_t)(nt * 64 + nl) * 1024 + dt * 64 + ((g ^ (nl & 7)) << 3);
    *(uint4*)(Wt + idx) = pk.v;
  }
}

// ---------------- spectral filter: four-step register FFT (64x64), sequential store ----------
__global__ __launch_bounds__(128, 2) void kx_filter(const float* __restrict__ x,
    const float* __restrict__ W_in, const float* __restrict__ b_in,
    const float* __restrict__ gains, uint32* __restrict__ XFp) {
  __shared__ uint32 tr[2][4096];   // fp16x2 transpose buffer, 16KB per wave
  const int t = threadIdx.x, l = t & 63, wv = t >> 6;
  const int g = blockIdx.x, h = blockIdx.y, bz = blockIdx.z;
  const int d0 = h * 64 + g * 4 + wv * 2;
  const float* gn = gains + ((size_t)bz * 16 + h) * 2064;
  const float wa0 = W_in[d0],     wa1 = W_in[1024 + d0], wa2 = W_in[2048 + d0], wa3 = W_in[3072 + d0];
  const float wb0 = W_in[d0 + 1], wb1 = W_in[1025 + d0], wb2 = W_in[2049 + d0], wb3 = W_in[3073 + d0];
  const float bia = b_in[d0], bib = b_in[d0 + 1];
  const float* xb = x + (size_t)bz * 4096 * 4;
  uint32* trw = tr[wv];
  float2 z[64];
  #pragma unroll
  for (int r = 0; r < 64; ++r) {
    int s = r * 64 + l;
    float4 xv = *(const float4*)(xb + (size_t)s * 4);
    float za = fmaf(xv.x, wa0, fmaf(xv.y, wa1, fmaf(xv.z, wa2, fmaf(xv.w, wa3, bia))));
    float zb = fmaf(xv.x, wb0, fmaf(xv.y, wb1, fmaf(xv.z, wb2, fmaf(xv.w, wb3, bib))));
    z[r] = make_float2(za, zb);
  }
  rdif64<-1>(z);
  {
    float sn, cs;
    __sincosf((float)l * (-6.28318530717958647692f / 4096.0f), &sn, &cs);
    float2 w1 = make_float2(cs, sn);
    float2 w2 = cmulf(w1, w1);
    float2 w4 = cmulf(w2, w2);
    float2 tch[4] = { make_float2(1.f, 0.f), w1, w2, cmulf(w2, w1) };
    #pragma unroll
    for (int i = 0; i < 16; ++i) {
      #pragma unroll
      for (int j = 0; j < 4; ++j) {
        const int rr = dr6c(4 * i + j);
        z[rr] = cmulf(z[rr], tch[j]);
      }
      #pragma unroll
      for (int j = 0; j < 4; ++j) tch[j] = cmulf(tch[j], w4);
    }
  }
  #pragma unroll
  for (int r = 0; r < 64; ++r) {
    const int k1 = dr6c(r);
    trw[k1 * 64 + ((l + k1) & 63)] = pack2h(z[r].x, z[r].y);
  }
  wave_sync();
  #pragma unroll
  for (int c = 0; c < 64; ++c) {
    uint32 u = trw[l * 64 + ((c + l) & 63)];
    z[c] = make_float2(h2f(u & 0xFFFFu), h2f(u >> 16));
  }
  wave_sync();
  rdif64<-1>(z);
  #pragma unroll
  for (int r = 0; r < 64; ++r) {
    const int k = l + (dr6c(r) << 6);
    const int km = (k < 2048) ? k : (4096 - k);
    const float gk = gn[km];
    z[r] = make_float2(z[r].x * gk, z[r].y * gk);
  }
  rdit64<1>(z);
  {
    float sn, cs;
    __sincosf((float)l * (6.28318530717958647692f / 4096.0f), &sn, &cs);
    float2 v1 = make_float2(cs, sn);
    float2 v2 = cmulf(v1, v1);
    float2 v4 = cmulf(v2, v2);
    float2 tch[4] = { make_float2(1.f, 0.f), v1, v2, cmulf(v2, v1) };
    #pragma unroll
    for (int i = 0; i < 16; ++i) {
      #pragma unroll
      for (int j = 0; j < 4; ++j)
        z[4 * i + j] = cmulf(z[4 * i + j], tch[j]);
      #pragma unroll
      for (int j = 0; j < 4; ++j) tch[j] = cmulf(tch[j], v4);
    }
  }
  #pragma unroll
  for (int r = 0; r < 64; ++r)
    trw[r * 64 + ((l + r) & 63)] = pack2h(z[r].x, z[r].y);
  wave_sync();
  #pragma unroll
  for (int c = 0; c < 64; ++c) {
    uint32 u = trw[l * 64 + ((c + l) & 63)];
    z[c] = make_float2(h2f(u & 0xFFFFu), h2f(u >> 16));
  }
  wave_sync();
  // permute registers to digit-reversed order (dr6c is an involution: 24 swaps),
  // then DIT inverse -> NATURAL n2 order -> sequential store stream.
  #pragma unroll
  for (int j = 0; j < 64; ++j) {
    const int dj = dr6c(j);
    if (dj > j) { float2 tmp = z[j]; z[j] = z[dj]; z[dj] = tmp; }
  }
  rdit64<1>(z);
  uint32* rowp = XFp + ((size_t)bz * 512 + (d0 >> 1)) * 4096;
  const float sc = 1.0f / 4096.0f;
  #pragma unroll
  for (int r = 0; r < 64; ++r)
    rowp[r * 64 + l] = pack2h(z[r].x * sc, z[r].y * sc);
}

// ---------------- A transpose: u32 [b][512 p][4096 s] -> [b][4096 s][512 p] + slot swizzle ----
__global__ __launch_bounds__(256) void kx_a16(const uint32* __restrict__ XFp, uint32* __restrict__ Aswz) {
  __shared__ uint32 tl[64][65];
  const int t = threadIdx.x;
  const int st = blockIdx.x, pt = blockIdx.y, bz = blockIdx.z;
  const uint32* src = XFp + ((size_t)bz * 512 + pt * 64) * 4096 + st * 64;
  #pragma unroll
  for (int i = 0; i < 16; ++i) {
    int p = i * 4 + (t >> 6);
    int s = t & 63;
    tl[p][s] = src[(size_t)p * 4096 + s];
  }
  __syncthreads();
  uint32* dst = Aswz + ((size_t)bz * 4096 + st * 64) * 512 + pt * 64;
  #pragma unroll
  for (int i = 0; i < 16; ++i) {
    int s = i * 4 + (t >> 6);
    int c = t & 63;
    int gsl = ((c & 31) >> 2) ^ (s & 7);
    int u32idx = (c >> 5) * 32 + gsl * 4 + (c & 3);
    dst[(size_t)s * 512 + u32idx] = tl[c][s];
  }
}

// ---------------- fp16 MFMA GEMM: C16[32768x1024] = A*W (fp16 out) ----------------------------
__global__ __launch_bounds__(256) void kx_gemm(const u16* __restrict__ A,
    const u16* __restrict__ Bw, u16* __restrict__ C) {
  __shared__ u16 sm[32768];
  const int t = threadIdx.x, l = t & 63, w = t >> 6;
  const int wm = w >> 1, wn = w & 1;
  const int id = blockIdx.x;
  const int wg = (id & 7) * 256 + (id >> 3);        // XCD-contiguous chunks (2048 blocks)
  const int bm = wg >> 3, bn = wg & 7;
  const int bh = bm >> 5;
  const u16* Ab = A + ((size_t)(bh * 4096 + (bm & 31) * 128)) * 1024;
  const u16* Bb = Bw + (size_t)(bn * 128) * 1024;
  const int fr = l & 15;
  const int lr = l >> 3, lg = l & 7;
  f32x4 acc[4][4];
  #pragma unroll
  for (int m = 0; m < 4; ++m)
    #pragma unroll
    for (int n = 0; n < 4; ++n) acc[m][n] = (f32x4){0.f, 0.f, 0.f, 0.f};

  #define STAGE(KT, BUF) { \
    u16* Ad = sm + (BUF) * 8192; \
    u16* Bd = sm + 16384 + (BUF) * 8192; \
    _Pragma("unroll") \
    for (int j = 0; j < 4; ++j) { \
      int qq = j * 4 + w; \
      glds16((void*)(Ad + qq * 512), Ab + (size_t)(qq * 8 + lr) * 1024 + (KT) * 64 + lg * 8); \
      glds16((void*)(Bd + qq * 512), Bb + (size_t)(qq * 8 + lr) * 1024 + (KT) * 64 + lg * 8); \
    } }

  STAGE(0, 0);
  __syncthreads();
  for (int kt = 0; kt < 16; ++kt) {
    const int cur = kt & 1;
    if (kt < 15) STAGE(kt + 1, cur ^ 1);
    const u16* Ac = sm + cur * 8192;
    const u16* Bc = sm + 16384 + cur * 8192;
    #pragma unroll
    for (int kk = 0; kk < 2; ++kk) {
      const int g8r = kk * 4 + (l >> 4);
      f16x8 af[4], bf[4];
      #pragma unroll
      for (int m = 0; m < 4; ++m) {
        int s = wm * 64 + m * 16 + fr;
        af[m] = *(const f16x8*)&Ac[s * 64 + ((g8r ^ (s & 7)) << 3)];
      }
      #pragma unroll
      for (int n = 0; n < 4; ++n) {
        int nn = wn * 64 + n * 16 + fr;
        bf[n] = *(const f16x8*)&Bc[nn * 64 + ((g8r ^ (nn & 7)) << 3)];
      }
      #pragma unroll
      for (int m = 0; m < 4; ++m)
        #pragma unroll
        for (int n = 0; n < 4; ++n)
          acc[m][n] = __builtin_amdgcn_mfma_f32_16x16x32_f16(af[m], bf[n], acc[m][n], 0, 0, 0);
    }
    __syncthreads();
  }
  float* Cs = (float*)sm;
  const int rl4 = (l >> 4) * 4;
  #pragma unroll
  for (int m = 0; m < 4; ++m) {
    int rbase = wm * 64 + m * 16 + rl4;
    #pragma unroll
    for (int n = 0; n < 4; ++n) {
      int cc = wn * 64 + n * 16 + fr;
      #pragma unroll
      for (int e = 0; e < 4; ++e) {
        int r = rbase + e;
        Cs[r * 128 + (cc ^ (((r >> 2) & 3) << 3))] = acc[m][n][e];
      }
    }
  }
  __syncthreads();
  u16* cgp = C + (size_t)(bm * 128) * 1024 + bn * 128;
  #pragma unroll
  for (int it = 0; it < 16; ++it) {
    int idx = it * 256 + t;
    int r = idx >> 5, c4 = (idx & 31) * 4;
    f32x4 v = *(const f32x4*)&Cs[r * 128 + (c4 ^ (((r >> 2) & 3) << 3))];
    u32x2 pv;
    pv.x = (uint32)f2h(v.x) | ((uint32)f2h(v.y) << 16);
    pv.y = (uint32)f2h(v.z) | ((uint32)f2h(v.w) << 16);
    __builtin_nontemporal_store(pv, (u32x2*)(cgp + (size_t)r * 1024 + c4));
  }
}

// ---------------- tail: LN(xp+out) -> @W_out -> composed quat -> FF ----------------------------
DEV float wred64(float v) {
  #pragma unroll
  for (int m = 32; m; m >>= 1) v += __shfl_xor(v, m);
  return v;
}
DEV float4 ln4q(float4 v, const float* g, const float* b) {
  float m = 0.25f * (v.x + v.y + v.z + v.w);
  float a0 = v.x - m, a1 = v.y - m, a2 = v.z - m, a3 = v.w - m;
  float var = 0.25f * (a0 * a0 + a1 * a1 + a2 * a2 + a3 * a3);
  float rs = 1.0f / sqrtf(var + 1e-5f);
  return make_float4(a0 * rs * g[0] + b[0], a1 * rs * g[1] + b[1],
                     a2 * rs * g[2] + b[2], a3 * rs * g[3] + b[3]);
}
DEV float gelu1(float v) { return 0.5f * v * (1.0f + erff(v * 0.70710678118654752440f)); }

__global__ __launch_bounds__(256) void kx_tail(const u16* __restrict__ G,
    const float* __restrict__ x, const float* __restrict__ W_in, const float* __restrict__ b_in,
    const float* __restrict__ b_attn, const float* __restrict__ lng, const float* __restrict__ lnb,
    const float* __restrict__ W_out, const float* __restrict__ b_out,
    const float* __restrict__ qlr,
    const float* __restrict__ Wf1, const float* __restrict__ bff1,
    const float* __restrict__ Wf2, const float* __restrict__ bff2,
    const float* __restrict__ n1g, const float* __restrict__ n1b,
    const float* __restrict__ n2g, const float* __restrict__ n2b,
    const float* __restrict__ n3g, const float* __restrict__ n3b,
    float* __restrict__ out) {
  const int l = threadIdx.x & 63, w = threadIdx.x >> 6;
  const size_t rg = (size_t)blockIdx.x * 4 + w;
  const float4 x4 = *(const float4*)(x + rg * 4);
  float4 tv[4];
  float lsum = 0.f;
  #pragma unroll
  for (int j = 0; j < 4; ++j) {
    int dd = j * 256 + l * 4;
    uint2 gv = *(const uint2*)(G + rg * 1024 + dd);
    float4 g4 = make_float4(h2f(gv.x & 0xFFFFu), h2f(gv.x >> 16),
                            h2f(gv.y & 0xFFFFu), h2f(gv.y >> 16));
    float4 w0 = *(const float4*)(W_in + dd);
    float4 w1 = *(const float4*)(W_in + 1024 + dd);
    float4 w2 = *(const float4*)(W_in + 2048 + dd);
    float4 w3 = *(const float4*)(W_in + 3072 + dd);
    float4 bi = *(const float4*)(b_in + dd);
    float4 ba = *(const float4*)(b_attn + dd);
    float4 o;
    o.x = g4.x + bi.x + ba.x + x4.x * w0.x + x4.y * w1.x + x4.z * w2.x + x4.w * w3.x;
    o.y = g4.y + bi.y + ba.y + x4.x * w0.y + x4.y * w1.y + x4.z * w2.y + x4.w * w3.y;
    o.z = g4.z + bi.z + ba.z + x4.x * w0.z + x4.y * w1.z + x4.z * w2.z + x4.w * w3.z;
    o.w = g4.w + bi.w + ba.w + x4.x * w0.w + x4.y * w1.w + x4.z * w2.w + x4.w * w3.w;
    tv[j] = o;
    lsum += o.x + o.y + o.z + o.w;
  }
  const float mean = wred64(lsum) * (1.0f / 1024.0f);
  float vsum = 0.f;
  #pragma unroll
  for (int j = 0; j < 4; ++j) {
    float a0 = tv[j].x - mean, a1 = tv[j].y - mean, a2 = tv[j].z - mean, a3 = tv[j].w - mean;
    vsum += a0 * a0 + a1 * a1 + a2 * a2 + a3 * a3;
  }
  const float rstd = 1.0f / sqrtf(wred64(vsum) * (1.0f / 1024.0f) + 1e-5f);
  float4 aq = make_float4(0.f, 0.f, 0.f, 0.f);
  #pragma unroll
  for (int j = 0; j < 4; ++j) {
    int dd = j * 256 + l * 4;
    float4 gg = *(const float4*)(lng + dd);
    float4 bb = *(const float4*)(lnb + dd);
    float av[4];
    av[0] = (tv[j].x - mean) * rstd * gg.x + bb.x;
    av[1] = (tv[j].y - mean) * rstd * gg.y + bb.y;
    av[2] = (tv[j].z - mean) * rstd * gg.z + bb.z;
    av[3] = (tv[j].w - mean) * rstd * gg.w + bb.w;
    #pragma unroll
    for (int e = 0; e < 4; ++e) {
      float4 wr = *(const float4*)(W_out + (size_t)(dd + e) * 4);
      aq.x = fmaf(av[e], wr.x, aq.x);
      aq.y = fmaf(av[e], wr.y, aq.y);
      aq.z = fmaf(av[e], wr.z, aq.z);
      aq.w = fmaf(av[e], wr.w, aq.w);
    }
  }
  aq.x = wred64(aq.x) + b_out[0];
  aq.y = wred64(aq.y) + b_out[1];
  aq.z = wred64(aq.z) + b_out[2];
  aq.w = wred64(aq.w) + b_out[3];
  float4 q1 = make_float4(x4.x + aq.x, x4.y + aq.y, x4.z + aq.z, x4.w + aq.w);
  float4 hq = qne(ln4q(q1, n1g, n1b));
  const float4 QL = *(const float4*)qlr;
  const float4 QRC = *(const float4*)(qlr + 4);
  float4 o = qne(qmul4(qmul4(QL, hq), QRC));
  float4 h2 = qne(ln4q(make_float4(hq.x + o.x, hq.y + o.y, hq.z + o.z, hq.w + o.w), n2g, n2b));
  float ffx = 0.f, ffy = 0.f, ffz = 0.f, ffw = 0.f;
  if (l < 16) {
    float uv = bff1[l] + h2.x * Wf1[l] + h2.y * Wf1[16 + l] + h2.z * Wf1[32 + l] + h2.w * Wf1[48 + l];
    uv = gelu1(uv);
    float4 w2r = *(const float4*)(Wf2 + l * 4);
    ffx = uv * w2r.x; ffy = uv * w2r.y; ffz = uv * w2r.z; ffw = uv * w2r.w;
  }
  ffx = wred64(ffx) + bff2[0];
  ffy = wred64(ffy) + bff2[1];
  ffz = wred64(ffz) + bff2[2];
  ffw = wred64(ffw) + bff2[3];
  float4 h3 = qne(ln4q(make_float4(h2.x + ffx, h2.y + ffy, h2.z + ffz, h2.w + ffw), n3g, n3b));
  if (l == 0) *(float4*)(out + rg * 4) = h3;
}

extern "C" void kernel_launch(void* const* d_in, const int* in_sizes, int n_in,
                              void* d_out, int out_size, void* d_ws, size_t ws_size,
                              hipStream_t stream) {
  (void)in_sizes; (void)n_in; (void)out_size;
  const float* x      = (const float*)d_in[0];
  const float* W_in   = (const float*)d_in[1];
  const float* b_in   = (const float*)d_in[2];
  const float* abase  = (const float*)d_in[3];
  const float* pshift = (const float*)d_in[4];
  const float* Wattn  = (const float*)d_in[5];
  const float* battn  = (const float*)d_in[6];
  const float* lng    = (const float*)d_in[7];
  const float* lnb    = (const float*)d_in[8];
  const float* Wout   = (const float*)d_in[9];
  const float* bout   = (const float*)d_in[10];
  const float* thL    = (const float*)d_in[11];
  const float* thR    = (const float*)d_in[12];
  const float* Wf1    = (const float*)d_in[13];
  const float* bff1   = (const float*)d_in[14];
  const float* Wf2    = (const float*)d_in[15];
  const float* bff2   = (const float*)d_in[16];
  const float* n1g    = (const float*)d_in[17];
  const float* n1b    = (const float*)d_in[18];
  const float* n2g    = (const float*)d_in[19];
  const float* n2b    = (const float*)d_in[20];
  const float* n3g    = (const float*)d_in[21];
  const float* n3b    = (const float*)d_in[22];

  if (ws_size < (size_t)138459204) return;  // ~132 MiB
  char* ws = (char*)d_ws;
  float2* Zmid  = (float2*)ws;                       // 128MiB (fractal only)
  uint32* XFp   = (uint32*)ws;                       // 64MiB (filter out, u32 pair [b][p][s])
  u16*   Aswz   = (u16*)(ws + 67108864);             // 64MiB (A fp16 [b][s][d] pre-swizzled)
  u16*   C16    = (u16*)ws;                          // 64MiB fp16 gemm out (overlays dead XFp)
  u16*   W2h    = (u16*)(ws + 134217728);            // 2MiB fp16 W^T pre-swizzled
  float* gainsw = (float*)(ws + 136314880);          // ~1MiB gain table [128][2064]
  float* qlrw   = (float*)(ws + 137400320);          // 32B composed quats
  float* partials = (float*)(ws + 138412032);        // 32KB
  float* sparts   = (float*)(ws + 138444800);        // 6KB
  float* alphaw   = (float*)(ws + 138450944);        // 32B
  float* geluw    = (float*)(ws + 138451008);        // 8.2KB

  kx_fr_pass1<<<dim3(256, 8), 512, 0, stream>>>(x, W_in, b_in, Zmid);
  kx_fr_pass2<<<dim3(512, 8), 128, 0, stream>>>(Zmid, partials, sparts);
  kx_finalize<<<1, 512, 0, stream>>>(partials, sparts, alphaw, geluw);
  kx_gains<<<128, 256, 0, stream>>>(alphaw, geluw, abase, pshift, thL, thR, gainsw, qlrw);
  kx_wt<<<dim3(16, 16), 256, 0, stream>>>(Wattn, W2h);
  kx_filter<<<dim3(16, 16, 8), 128, 0, stream>>>(x, W_in, b_in, gainsw, XFp);
  kx_a16<<<dim3(64, 8, 8), 256, 0, stream>>>(XFp, (uint32*)Aswz);
  kx_gemm<<<2048, 256, 0, stream>>>(Aswz, W2h, C16);
  kx_tail<<<8192, 256, 0, stream>>>(C16, x, W_in, b_in, battn, lng, lnb, Wout, bout,
                                    qlrw, Wf1, bff1, Wf2, bff2,
                                    n1g, n1b, n2g, n2b, n3g, n3b, (float*)d_out);
}

// Round 18
// 440.225 us; speedup vs baseline: 1.2308x; 1.2207x over previous
//
#include <hip/hip_runtime.h>
#include <hip/hip_bf16.h>
#include <math.h>

// PsiQRH block, MI355X. B=8 S=4096 QD=4 DM=1024 H=16 HD=64.
// Round 17: kx_filter __launch_bounds__(128,2) -> (128,1). The 2-waves/EU hint
// capped VGPRs at 128 == sizeof(z[64]) alone -> the register FFT spilled to
// scratch (global), which WAS the 250MB WRITE / 100MB FETCH all along.

#define DEV static __device__ __forceinline__
typedef unsigned int uint32;
typedef unsigned short u16;

typedef __attribute__((ext_vector_type(8))) _Float16 f16x8;
typedef __attribute__((ext_vector_type(4))) float f32x4;
typedef __attribute__((ext_vector_type(2))) unsigned int u32x2;

DEV float2 cmulf(float2 a, float2 b) {
  return make_float2(a.x * b.x - a.y * b.y, a.x * b.y + a.y * b.x);
}
DEV u16 f2h(float f) {
  union { _Float16 h; u16 u; } v;
  v.h = (_Float16)f;
  return v.u;
}
DEV float h2f(uint32 u) {
  union { u16 s; _Float16 h; } v;
  v.s = (u16)u;
  return (float)v.h;
}
DEV uint32 pack2h(float a, float b) {
  return (uint32)f2h(a) | ((uint32)f2h(b) << 16);
}
DEV void glds16(void* lds, const void* g) {
  __builtin_amdgcn_global_load_lds((const __attribute__((address_space(1))) unsigned int*)g,
                                   (__attribute__((address_space(3))) unsigned int*)lds, 16, 0, 0);
}
DEV void wave_sync() {
  asm volatile("s_waitcnt lgkmcnt(0)" ::: "memory");
  __builtin_amdgcn_sched_barrier(0);
}
DEV int dr10(int v) {   // base-4 digit reversal, 10-bit
  int r = (int)(__brev((unsigned)v) >> 22);
  return ((r & 0x155) << 1) | ((r & 0x2AA) >> 1);
}
constexpr int dr6c(int v) {   // base-4 digit reversal, 6-bit (involution)
  return ((v & 3) << 4) | (v & 12) | ((v >> 4) & 3);
}

// quarter-wave table: CQ[j] = cos(pi*j/32), j=0..16
constexpr float CQ[17] = {
  1.0f, 0.995184726672197f, 0.980785280403230f, 0.956940335732209f,
  0.923879532511287f, 0.881921264348355f, 0.831469612302545f, 0.773010453362737f,
  0.707106781186548f, 0.634393284163645f, 0.555570233019602f, 0.471396736825998f,
  0.382683432365090f, 0.290284677254462f, 0.195090322016128f, 0.098017140329561f, 0.0f };
constexpr float twc64(int j) {   // cos(2*pi*j/64)
  return (j & 63) <= 16 ? CQ[j & 63]
       : (j & 63) <= 32 ? -CQ[32 - (j & 63)]
       : (j & 63) <= 48 ? -CQ[(j & 63) - 32] : CQ[64 - (j & 63)];
}
constexpr float tws64(int j) {   // sin(2*pi*j/64)
  return (j & 63) <= 16 ? CQ[16 - (j & 63)]
       : (j & 63) <= 32 ? CQ[(j & 63) - 16]
       : (j & 63) <= 48 ? -CQ[48 - (j & 63)] : -CQ[(j & 63) - 48];
}

// cos/sin of pi*j/16, j = 0..15 (stage-offset twiddles for LDS FFTs)
constexpr float CR_C[16] = {
  1.0f, 0.980785280403230f, 0.923879532511287f, 0.831469612302545f,
  0.707106781186548f, 0.555570233019602f, 0.382683432365090f, 0.195090322016128f,
  0.0f, -0.195090322016128f, -0.382683432365090f, -0.555570233019602f,
  -0.707106781186548f, -0.831469612302545f, -0.923879532511287f, -0.980785280403230f };
constexpr float CR_S[16] = {
  0.0f, 0.195090322016128f, 0.382683432365090f, 0.555570233019602f,
  0.707106781186548f, 0.831469612302545f, 0.923879532511287f, 0.980785280403230f,
  1.0f, 0.980785280403230f, 0.923879532511287f, 0.831469612302545f,
  0.707106781186548f, 0.555570233019602f, 0.382683432365090f, 0.195090322016128f };

// ---------------- in-register 64-pt radix-4 FFTs (fully unrolled, const twiddles) -------------
template<int SGN>
DEV void rdif64(float2* z) {
  #pragma unroll
  for (int j = 0; j < 16; ++j) {
    float2 x0 = z[j], x1 = z[j + 16], x2 = z[j + 32], x3 = z[j + 48];
    float2 s0 = make_float2(x0.x + x2.x, x0.y + x2.y);
    float2 s1 = make_float2(x0.x - x2.x, x0.y - x2.y);
    float2 s2 = make_float2(x1.x + x3.x, x1.y + x3.y);
    float2 d  = make_float2(x1.x - x3.x, x1.y - x3.y);
    float2 s3 = (SGN < 0) ? make_float2(d.y, -d.x) : make_float2(-d.y, d.x);
    z[j] = make_float2(s0.x + s2.x, s0.y + s2.y);
    const float2 tf1 = make_float2(twc64(j),     (float)SGN * tws64(j));
    const float2 tf2 = make_float2(twc64(2 * j), (float)SGN * tws64(2 * j));
    const float2 tf3 = make_float2(twc64(3 * j), (float)SGN * tws64(3 * j));
    z[j + 16] = cmulf(make_float2(s1.x + s3.x, s1.y + s3.y), tf1);
    z[j + 32] = cmulf(make_float2(s0.x - s2.x, s0.y - s2.y), tf2);
    z[j + 48] = cmulf(make_float2(s1.x - s3.x, s1.y - s3.y), tf3);
  }
  #pragma unroll
  for (int b = 0; b < 64; b += 16)
    #pragma unroll
    for (int j = 0; j < 4; ++j) {
      const int i = b + j;
      float2 x0 = z[i], x1 = z[i + 4], x2 = z[i + 8], x3 = z[i + 12];
      float2 s0 = make_float2(x0.x + x2.x, x0.y + x2.y);
      float2 s1 = make_float2(x0.x - x2.x, x0.y - x2.y);
      float2 s2 = make_float2(x1.x + x3.x, x1.y + x3.y);
      float2 d  = make_float2(x1.x - x3.x, x1.y - x3.y);
      float2 s3 = (SGN < 0) ? make_float2(d.y, -d.x) : make_float2(-d.y, d.x);
      z[i] = make_float2(s0.x + s2.x, s0.y + s2.y);
      const float2 tf1 = make_float2(twc64(4 * j),  (float)SGN * tws64(4 * j));
      const float2 tf2 = make_float2(twc64(8 * j),  (float)SGN * tws64(8 * j));
      const float2 tf3 = make_float2(twc64(12 * j), (float)SGN * tws64(12 * j));
      z[i + 4]  = cmulf(make_float2(s1.x + s3.x, s1.y + s3.y), tf1);
      z[i + 8]  = cmulf(make_float2(s0.x - s2.x, s0.y - s2.y), tf2);
      z[i + 12] = cmulf(make_float2(s1.x - s3.x, s1.y - s3.y), tf3);
    }
  #pragma unroll
  for (int b = 0; b < 64; b += 4) {
    float2 x0 = z[b], x1 = z[b + 1], x2 = z[b + 2], x3 = z[b + 3];
    float2 s0 = make_float2(x0.x + x2.x, x0.y + x2.y);
    float2 s1 = make_float2(x0.x - x2.x, x0.y - x2.y);
    float2 s2 = make_float2(x1.x + x3.x, x1.y + x3.y);
    float2 d  = make_float2(x1.x - x3.x, x1.y - x3.y);
    float2 s3 = (SGN < 0) ? make_float2(d.y, -d.x) : make_float2(-d.y, d.x);
    z[b]     = make_float2(s0.x + s2.x, s0.y + s2.y);
    z[b + 1] = make_float2(s1.x + s3.x, s1.y + s3.y);
    z[b + 2] = make_float2(s0.x - s2.x, s0.y - s2.y);
    z[b + 3] = make_float2(s1.x - s3.x, s1.y - s3.y);
  }
}

template<int SGN>
DEV void rdit64(float2* z) {
  #pragma unroll
  for (int b = 0; b < 64; b += 4) {
    float2 b0 = z[b], b1 = z[b + 1], b2 = z[b + 2], b3 = z[b + 3];
    float2 t0 = make_float2(b0.x + b2.x, b0.y + b2.y);
    float2 t1 = make_float2(b0.x - b2.x, b0.y - b2.y);
    float2 t2 = make_float2(b1.x + b3.x, b1.y + b3.y);
    float2 d  = make_float2(b1.x - b3.x, b1.y - b3.y);
    float2 t3 = (SGN > 0) ? make_float2(-d.y, d.x) : make_float2(d.y, -d.x);
    z[b]     = make_float2(t0.x + t2.x, t0.y + t2.y);
    z[b + 1] = make_float2(t1.x + t3.x, t1.y + t3.y);
    z[b + 2] = make_float2(t0.x - t2.x, t0.y - t2.y);
    z[b + 3] = make_float2(t1.x - t3.x, t1.y - t3.y);
  }
  #pragma unroll
  for (int b = 0; b < 64; b += 16)
    #pragma unroll
    for (int j = 0; j < 4; ++j) {
      const int i = b + j;
      const float2 tf1 = make_float2(twc64(4 * j),  (float)SGN * tws64(4 * j));
      const float2 tf2 = make_float2(twc64(8 * j),  (float)SGN * tws64(8 * j));
      const float2 tf3 = make_float2(twc64(12 * j), (float)SGN * tws64(12 * j));
      float2 b0 = z[i];
      float2 b1 = cmulf(z[i + 4], tf1);
      float2 b2 = cmulf(z[i + 8], tf2);
      float2 b3 = cmulf(z[i + 12], tf3);
      float2 t0 = make_float2(b0.x + b2.x, b0.y + b2.y);
      float2 t1 = make_float2(b0.x - b2.x, b0.y - b2.y);
      float2 t2 = make_float2(b1.x + b3.x, b1.y + b3.y);
      float2 d  = make_float2(b1.x - b3.x, b1.y - b3.y);
      float2 t3 = (SGN > 0) ? make_float2(-d.y, d.x) : make_float2(d.y, -d.x);
      z[i]      = make_float2(t0.x + t2.x, t0.y + t2.y);
      z[i + 4]  = make_float2(t1.x + t3.x, t1.y + t3.y);
      z[i + 8]  = make_float2(t0.x - t2.x, t0.y - t2.y);
      z[i + 12] = make_float2(t1.x - t3.x, t1.y - t3.y);
    }
  #pragma unroll
  for (int j = 0; j < 16; ++j) {
    const float2 tf1 = make_float2(twc64(j),     (float)SGN * tws64(j));
    const float2 tf2 = make_float2(twc64(2 * j), (float)SGN * tws64(2 * j));
    const float2 tf3 = make_float2(twc64(3 * j), (float)SGN * tws64(3 * j));
    float2 b0 = z[j];
    float2 b1 = cmulf(z[j + 16], tf1);
    float2 b2 = cmulf(z[j + 32], tf2);
    float2 b3 = cmulf(z[j + 48], tf3);
    float2 t0 = make_float2(b0.x + b2.x, b0.y + b2.y);
    float2 t1 = make_float2(b0.x - b2.x, b0.y - b2.y);
    float2 t2 = make_float2(b1.x + b3.x, b1.y + b3.y);
    float2 d  = make_float2(b1.x - b3.x, b1.y - b3.y);
    float2 t3 = (SGN > 0) ? make_float2(-d.y, d.x) : make_float2(d.y, -d.x);
    z[j]      = make_float2(t0.x + t2.x, t0.y + t2.y);
    z[j + 16] = make_float2(t1.x + t3.x, t1.y + t3.y);
    z[j + 32] = make_float2(t0.x - t2.x, t0.y - t2.y);
    z[j + 48] = make_float2(t1.x - t3.x, t1.y - t3.y);
  }
}

// Radix-4 DIF over LDS, natural in -> digit-reversed out (negative exponent).
template<int L, int NLOG, int NSUB, bool WL>
DEV void dif4_stages(float2* F, int lg) {
  #pragma unroll
  for (int st = 0; st < NLOG / 2; ++st) {
    const int qlog = NLOG - 2 - 2 * st;
    const int q = 1 << qlog;
    float bs, bc;
    __sincosf((float)(lg & (q - 1)) * (-1.57079632679489661923f / (float)q), &bs, &bc);
    const float2 base = make_float2(bc, bs);
    #pragma unroll
    for (int u = 0; u < NSUB * (1 << (NLOG - 2)) / L; ++u) {
      const int sub = (u * L) >> (NLOG - 2);
      const int bf = ((u * L) & ((1 << (NLOG - 2)) - 1)) + lg;
      const int jj = ((u * L) % q) * 8 / q;
      const int i1 = (sub << NLOG) + ((bf >> qlog) << (qlog + 2)) + (bf & (q - 1));
      float2 x0 = F[i1], x1 = F[i1 + q], x2 = F[i1 + 2 * q], x3 = F[i1 + 3 * q];
      float2 s0 = make_float2(x0.x + x2.x, x0.y + x2.y);
      float2 s1 = make_float2(x0.x - x2.x, x0.y - x2.y);
      float2 s2 = make_float2(x1.x + x3.x, x1.y + x3.y);
      float2 dq = make_float2(x1.x - x3.x, x1.y - x3.y);
      float2 s3 = make_float2(dq.y, -dq.x);               // -i*(x1-x3)
      F[i1] = make_float2(s0.x + s2.x, s0.y + s2.y);
      if (qlog == 0) {
        F[i1 + 1] = make_float2(s1.x + s3.x, s1.y + s3.y);
        F[i1 + 2] = make_float2(s0.x - s2.x, s0.y - s2.y);
        F[i1 + 3] = make_float2(s1.x - s3.x, s1.y - s3.y);
      } else {
        const float2 tf1 = (jj == 0) ? base : cmulf(base, make_float2(CR_C[jj], -CR_S[jj]));
        const float2 tf2 = cmulf(tf1, tf1);
        const float2 tf3 = cmulf(tf2, tf1);
        F[i1 + q]     = cmulf(make_float2(s1.x + s3.x, s1.y + s3.y), tf1);
        F[i1 + 2 * q] = cmulf(make_float2(s0.x - s2.x, s0.y - s2.y), tf2);
        F[i1 + 3 * q] = cmulf(make_float2(s1.x - s3.x, s1.y - s3.y), tf3);
      }
    }
    if (WL) wave_sync(); else __syncthreads();
  }
}

// ---------------- quaternion helpers ----------------------------------------------------------
DEV float4 qmul4(float4 a, float4 b) {
  return make_float4(
    a.x * b.x - a.y * b.y - a.z * b.z - a.w * b.w,
    a.x * b.y + a.y * b.x + a.z * b.w - a.w * b.z,
    a.x * b.z - a.y * b.w + a.z * b.x + a.w * b.y,
    a.x * b.w + a.y * b.z - a.z * b.y + a.w * b.x);
}
DEV float4 qne(float4 q) {
  float n = sqrtf(q.x * q.x + q.y * q.y + q.z * q.z + q.w * q.w) + 1e-8f;
  float r = 1.0f / n;
  return make_float4(q.x * r, q.y * r, q.z * r, q.w * r);
}

// ---------------- fractal pass 1: 1024-pt radix-4 FFTs, wave-private (stride 1028) -----------
__global__ __launch_bounds__(512) void kx_fr_pass1(const float* __restrict__ x,
    const float* __restrict__ W_in, const float* __restrict__ b_in,
    float2* __restrict__ zmid) {
  __shared__ float2 fb[8 * 1028];
  const int t = threadIdx.x, l = t & 63, w = t >> 6;
  const int btile = blockIdx.x, bz = blockIdx.y;
  const int bcol = btile * 8 + w;
  const int d = 2 * (bcol & 511);
  const int soff = bcol >> 9;
  const float w00 = W_in[d],     w10 = W_in[1024 + d], w20 = W_in[2048 + d], w30 = W_in[3072 + d];
  const float w01 = W_in[d + 1], w11 = W_in[1025 + d], w21 = W_in[2049 + d], w31 = W_in[3073 + d];
  const float bi0 = b_in[d], bi1 = b_in[d + 1];
  const float* xb = x + (size_t)bz * 4096 * 4;
  float2* fbw = fb + w * 1028;
  #pragma unroll
  for (int i = 0; i < 16; ++i) {
    int a = i * 64 + l;
    int s = 4 * a + soff;
    float4 xv = *(const float4*)(xb + (size_t)s * 4);
    float z0 = fmaf(xv.x, w00, fmaf(xv.y, w10, fmaf(xv.z, w20, fmaf(xv.w, w30, bi0))));
    float z1 = fmaf(xv.x, w01, fmaf(xv.y, w11, fmaf(xv.z, w21, fmaf(xv.w, w31, bi1))));
    fbw[a] = make_float2(z0, z1);
  }
  wave_sync();
  dif4_stages<64, 10, 1, true>(fbw, l);
  __syncthreads();
  float2* dst = zmid + (size_t)bz * (1024 * 2048);
  #pragma unroll
  for (int i = 0; i < 16; ++i) {
    int idx = i * 512 + t;
    int w8 = idx & 7, cnat = idx >> 3;
    float2 v = fb[w8 * 1028 + dr10(cnat)];
    dst[(size_t)cnat * 2048 + btile * 8 + w8] = v;
  }
}

DEV float block_reduce128(float* red, int t, float v) {
  red[t] = v; __syncthreads();
  for (int s = 64; s; s >>= 1) { if (t < s) red[t] += red[t + s]; __syncthreads(); }
  float r = red[0]; __syncthreads();
  return r;
}

// ---------------- fractal pass 2: reg-fused r2 + 2x(1024 radix-4); __logf moments ------------
__global__ __launch_bounds__(128) void kx_fr_pass2(const float2* __restrict__ zmid,
    float* __restrict__ partials, float* __restrict__ sparts) {
  __shared__ float2 fb[2 * 2052];
  __shared__ float red[128];
  const int t = threadIdx.x, l = t & 63, w = t >> 6;   // w in {0,1}
  const int cg = blockIdx.x, bz = blockIdx.y;
  const int c = (cg == 0) ? (w ? 512 : 0) : (w ? (1024 - cg) : cg);
  const float2* src = zmid + ((size_t)bz * 1024 + c) * 2048;
  float2* fbc = fb + w * 2052;
  float2 rot[4], stp4;
  {
    float sn, cs;
    __sincosf((float)(l * c) * (-6.28318530717958647692f / 2097152.0f), &sn, &cs);
    rot[0] = make_float2(cs, sn);
    float2 stp;
    __sincosf((float)c * (-6.28318530717958647692f / 32768.0f), &sn, &cs);
    stp = make_float2(cs, sn);
    rot[1] = cmulf(rot[0], stp);
    float2 stp2 = cmulf(stp, stp);
    rot[2] = cmulf(rot[0], stp2);
    rot[3] = cmulf(rot[1], stp2);
    stp4 = cmulf(stp2, stp2);
  }
  float2 zr[32];
  #pragma unroll
  for (int i = 0; i < 32; ++i) {
    int bb = i * 64 + l;
    zr[i] = cmulf(src[bb], rot[i & 3]);
    rot[i & 3] = cmulf(rot[i & 3], stp4);
  }
  {
    float bs, bc;
    __sincosf((float)l * (-3.14159265358979323846f / 1024.0f), &bs, &bc);
    const float2 b2 = make_float2(bc, bs);
    #pragma unroll
    for (int u = 0; u < 16; ++u) {
      const float2 tf = (u == 0) ? b2 : cmulf(b2, make_float2(CR_C[u], -CR_S[u]));
      int i1 = u * 64 + l;
      float2 a0 = zr[u], a1 = zr[u + 16];
      fbc[i1] = make_float2(a0.x + a1.x, a0.y + a1.y);
      fbc[i1 + 1024] = cmulf(make_float2(a0.x - a1.x, a0.y - a1.y), tf);
    }
    wave_sync();
  }
  dif4_stages<64, 10, 2, true>(fbc, l);
  __syncthreads();
  float t0 = 0.f, t1 = 0.f, s0 = 0.f, s1 = 0.f, s2 = 0.f;
  if (cg != 0) {
    const float2* fbm = fb + (1 - w) * 2052;
    float2 pw[32];
    pw[0] = make_float2(1.f, 0.f);
    {
      float sn, cs;
      __sincosf(-3.14159265358979323846f / 2048.0f, &sn, &cs);
      float2 w1 = make_float2(cs, sn);
      #pragma unroll
      for (int j = 1; j < 32; ++j) pw[j] = cmulf(pw[j - 1], w1);
    }
    const int drl = (l & 3) * 256 + ((l >> 2) & 3) * 64 + ((l >> 4) & 3) * 16;
    float2 base2;
    {
      float sn, cs;
      __sincosf((float)drl * (-3.14159265358979323846f / 1024.0f), &sn, &cs);
      float2 lf = make_float2(cs, sn);
      __sincosf((float)c * (-6.28318530717958647692f / 4194304.0f), &sn, &cs);
      base2 = cmulf(make_float2(cs, sn), lf);
    }
    #pragma unroll
    for (int i = 0; i < 32; ++i) {
      const int p = i * 64 + l;
      const int dri = (i & 3) * 4 + ((i >> 2) & 3);
      const int top = i >> 4;
      const int dd = 2 * (drl + dri) + top;
      float2 Zk = fbc[p];
      float2 Zm = fbm[2047 - p];
      float2 E = make_float2(0.5f * (Zk.x + Zm.x), 0.5f * (Zk.y - Zm.y));
      float2 A = make_float2(Zk.x - Zm.x, Zk.y + Zm.y);
      float2 O = make_float2(0.5f * A.y, -0.5f * A.x);
      float2 urot = cmulf(base2, pw[2 * dri + top]);
      float2 U = cmulf(urot, O);
      float Xr = E.x + U.x, Xi = E.y + U.y;
      float P = Xr * Xr + Xi * Xi;
      int k = c + (dd << 10);
      float fr = (float)k * (1.0f / 4194304.0f);
      if (fr > 0.01f && fr < 0.5f) {
        float lp = __logf(P + 1e-10f);
        float lk = __logf(fr + 1e-10f);
        t0 += lp; t1 += lk * lp;
        s0 += 1.0f; s1 += lk; s2 += lk * lk;
      }
    }
  } else {
    const float2* fbm = fbc;   // self-mirrored columns (c = 0, 512)
    float2 urot;
    {
      float sn, cs;
      __sincosf((float)(c + l * 1024) * (-6.28318530717958647692f / 4194304.0f), &sn, &cs);
      urot = make_float2(cs, sn);
    }
    const float2 ustp = make_float2(0.995184726672197f, -0.0980171403295606f); // e^{-i pi/32}
    #pragma unroll
    for (int i = 0; i < 32; ++i) {
      int dd = i * 64 + l;
      int md = (c == 0) ? ((2048 - dd) & 2047) : (2047 - dd);
      int pk = ((dd & 1) << 10) | dr10(dd >> 1);
      int pm = ((md & 1) << 10) | dr10(md >> 1);
      float2 Zk = fbc[pk];
      float2 Zm = fbm[pm];
      float2 E = make_float2(0.5f * (Zk.x + Zm.x), 0.5f * (Zk.y - Zm.y));
      float2 A = make_float2(Zk.x - Zm.x, Zk.y + Zm.y);
      float2 O = make_float2(0.5f * A.y, -0.5f * A.x);
      float2 U = cmulf(urot, O);
      float Xr = E.x + U.x, Xi = E.y + U.y;
      float P = Xr * Xr + Xi * Xi;
      int k = c + (dd << 10);
      float fr = (float)k * (1.0f / 4194304.0f);
      if (fr > 0.01f && fr < 0.5f) {
        float lp = __logf(P + 1e-10f);
        float lk = __logf(fr + 1e-10f);
        t0 += lp; t1 += lk * lp;
        s0 += 1.0f; s1 += lk; s2 += lk * lk;
      }
      urot = cmulf(urot, ustp);
    }
  }
  float T0 = block_reduce128(red, t, t0);
  float T1 = block_reduce128(red, t, t1);
  if (t == 0) {
    partials[((size_t)bz * 512 + cg) * 2 + 0] = T0;
    partials[((size_t)bz * 512 + cg) * 2 + 1] = T1;
  }
  if (bz == 0) {
    float S0 = block_reduce128(red, t, s0);
    float S1 = block_reduce128(red, t, s1);
    float S2 = block_reduce128(red, t, s2);
    if (t == 0) { sparts[cg * 3] = S0; sparts[cg * 3 + 1] = S1; sparts[cg * 3 + 2] = S2; }
  }
}

DEV float block_reduce512(float* sh, int t, float v) {
  sh[t] = v; __syncthreads();
  for (int s = 256; s; s >>= 1) { if (t < s) sh[t] += sh[t + s]; __syncthreads(); }
  float r = sh[0]; __syncthreads();
  return r;
}

// ---------------- finalize: alpha[b]; gelu_k table ---------------------------------------------
__global__ __launch_bounds__(512) void kx_finalize(const float* __restrict__ partials,
    const float* __restrict__ sparts, float* __restrict__ alpha, float* __restrict__ gelu) {
  __shared__ float sh[512];
  __shared__ float lk[4096];
  const int t = threadIdx.x;
  float S0 = block_reduce512(sh, t, sparts[t * 3 + 0]);
  float S1 = block_reduce512(sh, t, sparts[t * 3 + 1]);
  float S2 = block_reduce512(sh, t, sparts[t * 3 + 2]);
  float mk = S1 / S0;
  float var = S2 - mk * S1;
  for (int b = 0; b < 8; ++b) {
    float T0 = block_reduce512(sh, t, partials[((size_t)b * 512 + t) * 2 + 0]);
    float T1 = block_reduce512(sh, t, partials[((size_t)b * 512 + t) * 2 + 1]);
    if (t == 0) {
      float cov = T1 - mk * T0;
      float beta = -cov / (var + 1e-10f);
      float D = fminf(fmaxf((3.0f - beta) * 0.5f, 0.5f), 1.5f);
      alpha[b] = fminf(fmaxf(1.0f + 0.8f * (D - 1.0f), 0.1f), 3.0f);
    }
  }
  for (int s = t; s < 4096; s += 512) {
    int m = (s < 2048) ? s : (4096 - s);
    lk[s] = logf((float)m * (1.0f / 4096.0f) + 1e-8f);
  }
  __syncthreads();
  float ls = 0.f;
  for (int s = t; s < 4096; s += 512) ls += lk[s];
  float mean = block_reduce512(sh, t, ls) * (1.0f / 4096.0f);
  float vs = 0.f;
  for (int s = t; s < 4096; s += 512) { float dv = lk[s] - mean; vs += dv * dv; }
  float sd = sqrtf(block_reduce512(sh, t, vs) * (1.0f / 4095.0f));
  for (int k = t; k < 2049; k += 512) {
    float xn = (lk[k] - mean) / (sd + 1e-8f);
    gelu[k] = 0.5f * xn * (1.0f + erff(xn * 0.70710678118654752440f));
  }
}

// ---------------- gain table + composed quaternions -------------------------------------------
__global__ __launch_bounds__(256) void kx_gains(const float* __restrict__ alpha,
    const float* __restrict__ gelu, const float* __restrict__ abase,
    const float* __restrict__ pshift, const float* __restrict__ thL,
    const float* __restrict__ thR, float* __restrict__ gains, float* __restrict__ qlr) {
  const int bh = blockIdx.x;    // 0..127
  const float aa = abase[bh & 15] * alpha[bh >> 4];
  const float ps = pshift[bh & 15];
  for (int k = threadIdx.x; k < 2049; k += 256)
    gains[(size_t)bh * 2064 + k] = cosf(fmaf(aa, gelu[k], ps));
  if (bh == 0 && threadIdx.x == 0) {
    float4 QL = make_float4(1.f, 0.f, 0.f, 0.f);
    float4 QRC = make_float4(1.f, 0.f, 0.f, 0.f);
    for (int it = 0; it < 4; ++it) {
      float s0, c0, s1, c1, s2, c2;
      sincosf(0.5f * thL[it * 3 + 0], &s0, &c0);
      sincosf(0.5f * thL[it * 3 + 1], &s1, &c1);
      sincosf(0.5f * thL[it * 3 + 2], &s2, &c2);
      float4 qL = qne(make_float4(c0 * c1 * c2, s0 * c1 * c2, c0 * s1 * c2, c0 * c1 * s2));
      QL = qmul4(qL, QL);
      sincosf(0.5f * thR[it * 3 + 0], &s0, &c0);
      sincosf(0.5f * thR[it * 3 + 1], &s1, &c1);
      sincosf(0.5f * thR[it * 3 + 2], &s2, &c2);
      float4 qR = qne(make_float4(c0 * c1 * c2, s0 * c1 * c2, c0 * s1 * c2, c0 * c1 * s2));
      QRC = qmul4(QRC, make_float4(qR.x, -qR.y, -qR.z, -qR.w));
    }
    *(float4*)qlr = QL;
    *(float4*)(qlr + 4) = QRC;
  }
}

// ---------------- W_attn_out transpose -> fp16 [n][d] pre-swizzled ----------------------------
__global__ __launch_bounds__(256) void kx_wt(const float* __restrict__ W, u16* __restrict__ Wt) {
  __shared__ float tile[64][65];
  const int t = threadIdx.x;
  const int nt = blockIdx.x, dt = blockIdx.y;
  #pragma unroll
  for (int i = 0; i < 16; ++i) {
    int idx = i * 256 + t;
    int r = idx >> 6, cc = idx & 63;
    tile[r][cc] = W[(size_t)(dt * 64 + r) * 1024 + nt * 64 + cc];
  }
  __syncthreads();
  #pragma unroll
  for (int i = 0; i < 2; ++i) {
    int task = i * 256 + t;
    int nl = task >> 3, g = task & 7;
    union { u16 h[8]; uint4 v; } pk;
    #pragma unroll
    for (int k = 0; k < 8; ++k) pk.h[k] = f2h(tile[g * 8 + k][nl]);
    size_t idx = (size_t)(nt * 64 + nl) * 1024 + dt * 64 + ((g ^ (nl & 7)) << 3);
    *(uint4*)(Wt + idx) = pk.v;
  }
}

// ---------------- spectral filter: four-step register FFT (64x64), sequential store ----------
__global__ __launch_bounds__(128, 1) void kx_filter(const float* __restrict__ x,
    const float* __restrict__ W_in, const float* __restrict__ b_in,
    const float* __restrict__ gains, uint32* __restrict__ XFp) {
  __shared__ uint32 tr[2][4096];   // fp16x2 transpose buffer, 16KB per wave
  const int t = threadIdx.x, l = t & 63, wv = t >> 6;
  const int g = blockIdx.x, h = blockIdx.y, bz = blockIdx.z;
  const int d0 = h * 64 + g * 4 + wv * 2;
  const float* gn = gains + ((size_t)bz * 16 + h) * 2064;
  const float wa0 = W_in[d0],     wa1 = W_in[1024 + d0], wa2 = W_in[2048 + d0], wa3 = W_in[3072 + d0];
  const float wb0 = W_in[d0 + 1], wb1 = W_in[1025 + d0], wb2 = W_in[2049 + d0], wb3 = W_in[3073 + d0];
  const float bia = b_in[d0], bib = b_in[d0 + 1];
  const float* xb = x + (size_t)bz * 4096 * 4;
  uint32* trw = tr[wv];
  float2 z[64];
  #pragma unroll
  for (int r = 0; r < 64; ++r) {
    int s = r * 64 + l;
    float4 xv = *(const float4*)(xb + (size_t)s * 4);
    float za = fmaf(xv.x, wa0, fmaf(xv.y, wa1, fmaf(xv.z, wa2, fmaf(xv.w, wa3, bia))));
    float zb = fmaf(xv.x, wb0, fmaf(xv.y, wb1, fmaf(xv.z, wb2, fmaf(xv.w, wb3, bib))));
    z[r] = make_float2(za, zb);
  }
  rdif64<-1>(z);
  {
    float sn, cs;
    __sincosf((float)l * (-6.28318530717958647692f / 4096.0f), &sn, &cs);
    float2 w1 = make_float2(cs, sn);
    float2 w2 = cmulf(w1, w1);
    float2 w4 = cmulf(w2, w2);
    float2 tch[4] = { make_float2(1.f, 0.f), w1, w2, cmulf(w2, w1) };
    #pragma unroll
    for (int i = 0; i < 16; ++i) {
      #pragma unroll
      for (int j = 0; j < 4; ++j) {
        const int rr = dr6c(4 * i + j);
        z[rr] = cmulf(z[rr], tch[j]);
      }
      #pragma unroll
      for (int j = 0; j < 4; ++j) tch[j] = cmulf(tch[j], w4);
    }
  }
  #pragma unroll
  for (int r = 0; r < 64; ++r) {
    const int k1 = dr6c(r);
    trw[k1 * 64 + ((l + k1) & 63)] = pack2h(z[r].x, z[r].y);
  }
  wave_sync();
  #pragma unroll
  for (int c = 0; c < 64; ++c) {
    uint32 u = trw[l * 64 + ((c + l) & 63)];
    z[c] = make_float2(h2f(u & 0xFFFFu), h2f(u >> 16));
  }
  wave_sync();
  rdif64<-1>(z);
  #pragma unroll
  for (int r = 0; r < 64; ++r) {
    const int k = l + (dr6c(r) << 6);
    const int km = (k < 2048) ? k : (4096 - k);
    const float gk = gn[km];
    z[r] = make_float2(z[r].x * gk, z[r].y * gk);
  }
  rdit64<1>(z);
  {
    float sn, cs;
    __sincosf((float)l * (6.28318530717958647692f / 4096.0f), &sn, &cs);
    float2 v1 = make_float2(cs, sn);
    float2 v2 = cmulf(v1, v1);
    float2 v4 = cmulf(v2, v2);
    float2 tch[4] = { make_float2(1.f, 0.f), v1, v2, cmulf(v2, v1) };
    #pragma unroll
    for (int i = 0; i < 16; ++i) {
      #pragma unroll
      for (int j = 0; j < 4; ++j)
        z[4 * i + j] = cmulf(z[4 * i + j], tch[j]);
      #pragma unroll
      for (int j = 0; j < 4; ++j) tch[j] = cmulf(tch[j], v4);
    }
  }
  #pragma unroll
  for (int r = 0; r < 64; ++r)
    trw[r * 64 + ((l + r) & 63)] = pack2h(z[r].x, z[r].y);
  wave_sync();
  #pragma unroll
  for (int c = 0; c < 64; ++c) {
    uint32 u = trw[l * 64 + ((c + l) & 63)];
    z[c] = make_float2(h2f(u & 0xFFFFu), h2f(u >> 16));
  }
  wave_sync();
  // permute registers to digit-reversed order (dr6c is an involution: 24 swaps),
  // then DIT inverse -> NATURAL n2 order -> sequential store stream.
  #pragma unroll
  for (int j = 0; j < 64; ++j) {
    const int dj = dr6c(j);
    if (dj > j) { float2 tmp = z[j]; z[j] = z[dj]; z[dj] = tmp; }
  }
  rdit64<1>(z);
  uint32* rowp = XFp + ((size_t)bz * 512 + (d0 >> 1)) * 4096;
  const float sc = 1.0f / 4096.0f;
  #pragma unroll
  for (int r = 0; r < 64; ++r)
    rowp[r * 64 + l] = pack2h(z[r].x * sc, z[r].y * sc);
}

// ---------------- A transpose: u32 [b][512 p][4096 s] -> [b][4096 s][512 p] + slot swizzle ----
__global__ __launch_bounds__(256) void kx_a16(const uint32* __restrict__ XFp, uint32* __restrict__ Aswz) {
  __shared__ uint32 tl[64][65];
  const int t = threadIdx.x;
  const int st = blockIdx.x, pt = blockIdx.y, bz = blockIdx.z;
  const uint32* src = XFp + ((size_t)bz * 512 + pt * 64) * 4096 + st * 64;
  #pragma unroll
  for (int i = 0; i < 16; ++i) {
    int p = i * 4 + (t >> 6);
    int s = t & 63;
    tl[p][s] = src[(size_t)p * 4096 + s];
  }
  __syncthreads();
  uint32* dst = Aswz + ((size_t)bz * 4096 + st * 64) * 512 + pt * 64;
  #pragma unroll
  for (int i = 0; i < 16; ++i) {
    int s = i * 4 + (t >> 6);
    int c = t & 63;
    int gsl = ((c & 31) >> 2) ^ (s & 7);
    int u32idx = (c >> 5) * 32 + gsl * 4 + (c & 3);
    dst[(size_t)s * 512 + u32idx] = tl[c][s];
  }
}

// ---------------- fp16 MFMA GEMM: C16[32768x1024] = A*W (fp16 out) ----------------------------
__global__ __launch_bounds__(256) void kx_gemm(const u16* __restrict__ A,
    const u16* __restrict__ Bw, u16* __restrict__ C) {
  __shared__ u16 sm[32768];
  const int t = threadIdx.x, l = t & 63, w = t >> 6;
  const int wm = w >> 1, wn = w & 1;
  const int id = blockIdx.x;
  const int wg = (id & 7) * 256 + (id >> 3);        // XCD-contiguous chunks (2048 blocks)
  const int bm = wg >> 3, bn = wg & 7;
  const int bh = bm >> 5;
  const u16* Ab = A + ((size_t)(bh * 4096 + (bm & 31) * 128)) * 1024;
  const u16* Bb = Bw + (size_t)(bn * 128) * 1024;
  const int fr = l & 15;
  const int lr = l >> 3, lg = l & 7;
  f32x4 acc[4][4];
  #pragma unroll
  for (int m = 0; m < 4; ++m)
    #pragma unroll
    for (int n = 0; n < 4; ++n) acc[m][n] = (f32x4){0.f, 0.f, 0.f, 0.f};

  #define STAGE(KT, BUF) { \
    u16* Ad = sm + (BUF) * 8192; \
    u16* Bd = sm + 16384 + (BUF) * 8192; \
    _Pragma("unroll") \
    for (int j = 0; j < 4; ++j) { \
      int qq = j * 4 + w; \
      glds16((void*)(Ad + qq * 512), Ab + (size_t)(qq * 8 + lr) * 1024 + (KT) * 64 + lg * 8); \
      glds16((void*)(Bd + qq * 512), Bb + (size_t)(qq * 8 + lr) * 1024 + (KT) * 64 + lg * 8); \
    } }

  STAGE(0, 0);
  __syncthreads();
  for (int kt = 0; kt < 16; ++kt) {
    const int cur = kt & 1;
    if (kt < 15) STAGE(kt + 1, cur ^ 1);
    const u16* Ac = sm + cur * 8192;
    const u16* Bc = sm + 16384 + cur * 8192;
    #pragma unroll
    for (int kk = 0; kk < 2; ++kk) {
      const int g8r = kk * 4 + (l >> 4);
      f16x8 af[4], bf[4];
      #pragma unroll
      for (int m = 0; m < 4; ++m) {
        int s = wm * 64 + m * 16 + fr;
        af[m] = *(const f16x8*)&Ac[s * 64 + ((g8r ^ (s & 7)) << 3)];
      }
      #pragma unroll
      for (int n = 0; n < 4; ++n) {
        int nn = wn * 64 + n * 16 + fr;
        bf[n] = *(const f16x8*)&Bc[nn * 64 + ((g8r ^ (nn & 7)) << 3)];
      }
      #pragma unroll
      for (int m = 0; m < 4; ++m)
        #pragma unroll
        for (int n = 0; n < 4; ++n)
          acc[m][n] = __builtin_amdgcn_mfma_f32_16x16x32_f16(af[m], bf[n], acc[m][n], 0, 0, 0);
    }
    __syncthreads();
  }
  float* Cs = (float*)sm;
  const int rl4 = (l >> 4) * 4;
  #pragma unroll
  for (int m = 0; m < 4; ++m) {
    int rbase = wm * 64 + m * 16 + rl4;
    #pragma unroll
    for (int n = 0; n < 4; ++n) {
      int cc = wn * 64 + n * 16 + fr;
      #pragma unroll
      for (int e = 0; e < 4; ++e) {
        int r = rbase + e;
        Cs[r * 128 + (cc ^ (((r >> 2) & 3) << 3))] = acc[m][n][e];
      }
    }
  }
  __syncthreads();
  u16* cgp = C + (size_t)(bm * 128) * 1024 + bn * 128;
  #pragma unroll
  for (int it = 0; it < 16; ++it) {
    int idx = it * 256 + t;
    int r = idx >> 5, c4 = (idx & 31) * 4;
    f32x4 v = *(const f32x4*)&Cs[r * 128 + (c4 ^ (((r >> 2) & 3) << 3))];
    u32x2 pv;
    pv.x = (uint32)f2h(v.x) | ((uint32)f2h(v.y) << 16);
    pv.y = (uint32)f2h(v.z) | ((uint32)f2h(v.w) << 16);
    __builtin_nontemporal_store(pv, (u32x2*)(cgp + (size_t)r * 1024 + c4));
  }
}

// ---------------- tail: LN(xp+out) -> @W_out -> composed quat -> FF ----------------------------
DEV float wred64(float v) {
  #pragma unroll
  for (int m = 32; m; m >>= 1) v += __shfl_xor(v, m);
  return v;
}
DEV float4 ln4q(float4 v, const float* g, const float* b) {
  float m = 0.25f * (v.x + v.y + v.z + v.w);
  float a0 = v.x - m, a1 = v.y - m, a2 = v.z - m, a3 = v.w - m;
  float var = 0.25f * (a0 * a0 + a1 * a1 + a2 * a2 + a3 * a3);
  float rs = 1.0f / sqrtf(var + 1e-5f);
  return make_float4(a0 * rs * g[0] + b[0], a1 * rs * g[1] + b[1],
                     a2 * rs * g[2] + b[2], a3 * rs * g[3] + b[3]);
}
DEV float gelu1(float v) { return 0.5f * v * (1.0f + erff(v * 0.70710678118654752440f)); }

__global__ __launch_bounds__(256) void kx_tail(const u16* __restrict__ G,
    const float* __restrict__ x, const float* __restrict__ W_in, const float* __restrict__ b_in,
    const float* __restrict__ b_attn, const float* __restrict__ lng, const float* __restrict__ lnb,
    const float* __restrict__ W_out, const float* __restrict__ b_out,
    const float* __restrict__ qlr,
    const float* __restrict__ Wf1, const float* __restrict__ bff1,
    const float* __restrict__ Wf2, const float* __restrict__ bff2,
    const float* __restrict__ n1g, const float* __restrict__ n1b,
    const float* __restrict__ n2g, const float* __restrict__ n2b,
    const float* __restrict__ n3g, const float* __restrict__ n3b,
    float* __restrict__ out) {
  const int l = threadIdx.x & 63, w = threadIdx.x >> 6;
  const size_t rg = (size_t)blockIdx.x * 4 + w;
  const float4 x4 = *(const float4*)(x + rg * 4);
  float4 tv[4];
  float lsum = 0.f;
  #pragma unroll
  for (int j = 0; j < 4; ++j) {
    int dd = j * 256 + l * 4;
    uint2 gv = *(const uint2*)(G + rg * 1024 + dd);
    float4 g4 = make_float4(h2f(gv.x & 0xFFFFu), h2f(gv.x >> 16),
                            h2f(gv.y & 0xFFFFu), h2f(gv.y >> 16));
    float4 w0 = *(const float4*)(W_in + dd);
    float4 w1 = *(const float4*)(W_in + 1024 + dd);
    float4 w2 = *(const float4*)(W_in + 2048 + dd);
    float4 w3 = *(const float4*)(W_in + 3072 + dd);
    float4 bi = *(const float4*)(b_in + dd);
    float4 ba = *(const float4*)(b_attn + dd);
    float4 o;
    o.x = g4.x + bi.x + ba.x + x4.x * w0.x + x4.y * w1.x + x4.z * w2.x + x4.w * w3.x;
    o.y = g4.y + bi.y + ba.y + x4.x * w0.y + x4.y * w1.y + x4.z * w2.y + x4.w * w3.y;
    o.z = g4.z + bi.z + ba.z + x4.x * w0.z + x4.y * w1.z + x4.z * w2.z + x4.w * w3.z;
    o.w = g4.w + bi.w + ba.w + x4.x * w0.w + x4.y * w1.w + x4.z * w2.w + x4.w * w3.w;
    tv[j] = o;
    lsum += o.x + o.y + o.z + o.w;
  }
  const float mean = wred64(lsum) * (1.0f / 1024.0f);
  float vsum = 0.f;
  #pragma unroll
  for (int j = 0; j < 4; ++j) {
    float a0 = tv[j].x - mean, a1 = tv[j].y - mean, a2 = tv[j].z - mean, a3 = tv[j].w - mean;
    vsum += a0 * a0 + a1 * a1 + a2 * a2 + a3 * a3;
  }
  const float rstd = 1.0f / sqrtf(wred64(vsum) * (1.0f / 1024.0f) + 1e-5f);
  float4 aq = make_float4(0.f, 0.f, 0.f, 0.f);
  #pragma unroll
  for (int j = 0; j < 4; ++j) {
    int dd = j * 256 + l * 4;
    float4 gg = *(const float4*)(lng + dd);
    float4 bb = *(const float4*)(lnb + dd);
    float av[4];
    av[0] = (tv[j].x - mean) * rstd * gg.x + bb.x;
    av[1] = (tv[j].y - mean) * rstd * gg.y + bb.y;
    av[2] = (tv[j].z - mean) * rstd * gg.z + bb.z;
    av[3] = (tv[j].w - mean) * rstd * gg.w + bb.w;
    #pragma unroll
    for (int e = 0; e < 4; ++e) {
      float4 wr = *(const float4*)(W_out + (size_t)(dd + e) * 4);
      aq.x = fmaf(av[e], wr.x, aq.x);
      aq.y = fmaf(av[e], wr.y, aq.y);
      aq.z = fmaf(av[e], wr.z, aq.z);
      aq.w = fmaf(av[e], wr.w, aq.w);
    }
  }
  aq.x = wred64(aq.x) + b_out[0];
  aq.y = wred64(aq.y) + b_out[1];
  aq.z = wred64(aq.z) + b_out[2];
  aq.w = wred64(aq.w) + b_out[3];
  float4 q1 = make_float4(x4.x + aq.x, x4.y + aq.y, x4.z + aq.z, x4.w + aq.w);
  float4 hq = qne(ln4q(q1, n1g, n1b));
  const float4 QL = *(const float4*)qlr;
  const float4 QRC = *(const float4*)(qlr + 4);
  float4 o = qne(qmul4(qmul4(QL, hq), QRC));
  float4 h2 = qne(ln4q(make_float4(hq.x + o.x, hq.y + o.y, hq.z + o.z, hq.w + o.w), n2g, n2b));
  float ffx = 0.f, ffy = 0.f, ffz = 0.f, ffw = 0.f;
  if (l < 16) {
    float uv = bff1[l] + h2.x * Wf1[l] + h2.y * Wf1[16 + l] + h2.z * Wf1[32 + l] + h2.w * Wf1[48 + l];
    uv = gelu1(uv);
    float4 w2r = *(const float4*)(Wf2 + l * 4);
    ffx = uv * w2r.x; ffy = uv * w2r.y; ffz = uv * w2r.z; ffw = uv * w2r.w;
  }
  ffx = wred64(ffx) + bff2[0];
  ffy = wred64(ffy) + bff2[1];
  ffz = wred64(ffz) + bff2[2];
  ffw = wred64(ffw) + bff2[3];
  float4 h3 = qne(ln4q(make_float4(h2.x + ffx, h2.y + ffy, h2.z + ffz, h2.w + ffw), n3g, n3b));
  if (l == 0) *(float4*)(out + rg * 4) = h3;
}

extern "C" void kernel_launch(void* const* d_in, const int* in_sizes, int n_in,
                              void* d_out, int out_size, void* d_ws, size_t ws_size,
                              hipStream_t stream) {
  (void)in_sizes; (void)n_in; (void)out_size;
  const float* x      = (const float*)d_in[0];
  const float* W_in   = (const float*)d_in[1];
  const float* b_in   = (const float*)d_in[2];
  const float* abase  = (const float*)d_in[3];
  const float* pshift = (const float*)d_in[4];
  const float* Wattn  = (const float*)d_in[5];
  const float* battn  = (const float*)d_in[6];
  const float* lng    = (const float*)d_in[7];
  const float* lnb    = (const float*)d_in[8];
  const float* Wout   = (const float*)d_in[9];
  const float* bout   = (const float*)d_in[10];
  const float* thL    = (const float*)d_in[11];
  const float* thR    = (const float*)d_in[12];
  const float* Wf1    = (const float*)d_in[13];
  const float* bff1   = (const float*)d_in[14];
  const float* Wf2    = (const float*)d_in[15];
  const float* bff2   = (const float*)d_in[16];
  const float* n1g    = (const float*)d_in[17];
  const float* n1b    = (const float*)d_in[18];
  const float* n2g    = (const float*)d_in[19];
  const float* n2b    = (const float*)d_in[20];
  const float* n3g    = (const float*)d_in[21];
  const float* n3b    = (const float*)d_in[22];

  if (ws_size < (size_t)138459204) return;  // ~132 MiB
  char* ws = (char*)d_ws;
  float2* Zmid  = (float2*)ws;                       // 128MiB (fractal only)
  uint32* XFp   = (uint32*)ws;                       // 64MiB (filter out, u32 pair [b][p][s])
  u16*   Aswz   = (u16*)(ws + 67108864);             // 64MiB (A fp16 [b][s][d] pre-swizzled)
  u16*   C16    = (u16*)ws;                          // 64MiB fp16 gemm out (overlays dead XFp)
  u16*   W2h    = (u16*)(ws + 134217728);            // 2MiB fp16 W^T pre-swizzled
  float* gainsw = (float*)(ws + 136314880);          // ~1MiB gain table [128][2064]
  float* qlrw   = (float*)(ws + 137400320);          // 32B composed quats
  float* partials = (float*)(ws + 138412032);        // 32KB
  float* sparts   = (float*)(ws + 138444800);        // 6KB
  float* alphaw   = (float*)(ws + 138450944);        // 32B
  float* geluw    = (float*)(ws + 138451008);        // 8.2KB

  kx_fr_pass1<<<dim3(256, 8), 512, 0, stream>>>(x, W_in, b_in, Zmid);
  kx_fr_pass2<<<dim3(512, 8), 128, 0, stream>>>(Zmid, partials, sparts);
  kx_finalize<<<1, 512, 0, stream>>>(partials, sparts, alphaw, geluw);
  kx_gains<<<128, 256, 0, stream>>>(alphaw, geluw, abase, pshift, thL, thR, gainsw, qlrw);
  kx_wt<<<dim3(16, 16), 256, 0, stream>>>(Wattn, W2h);
  kx_filter<<<dim3(16, 16, 8), 128, 0, stream>>>(x, W_in, b_in, gainsw, XFp);
  kx_a16<<<dim3(64, 8, 8), 256, 0, stream>>>(XFp, (uint32*)Aswz);
  kx_gemm<<<2048, 256, 0, stream>>>(Aswz, W2h, C16);
  kx_tail<<<8192, 256, 0, stream>>>(C16, x, W_in, b_in, battn, lng, lnb, Wout, bout,
                                    qlrw, Wf1, bff1, Wf2, bff2,
                                    n1g, n1b, n2g, n2b, n3g, n3b, (float*)d_out);
}

// Round 19
// 417.851 us; speedup vs baseline: 1.2967x; 1.0535x over previous
//
#include <hip/hip_runtime.h>
#include <hip/hip_bf16.h>
#include <math.h>

// PsiQRH block, MI355X. B=8 S=4096 QD=4 DM=1024 H=16 HD=64.
// Round 19: fp16-packed Zmid (halves pass1-write/pass2-read traffic),
// pass2 LDS ->32KB (stride 2048 + overlaid reduce buffer, 5 blocks/CU),
// finalize+gains+quats+wt merged into one dispatch (9 -> 7 launches).

#define DEV static __device__ __forceinline__
typedef unsigned int uint32;
typedef unsigned short u16;

typedef __attribute__((ext_vector_type(8))) _Float16 f16x8;
typedef __attribute__((ext_vector_type(4))) float f32x4;
typedef __attribute__((ext_vector_type(2))) unsigned int u32x2;

DEV float2 cmulf(float2 a, float2 b) {
  return make_float2(a.x * b.x - a.y * b.y, a.x * b.y + a.y * b.x);
}
DEV u16 f2h(float f) {
  union { _Float16 h; u16 u; } v;
  v.h = (_Float16)f;
  return v.u;
}
DEV float h2f(uint32 u) {
  union { u16 s; _Float16 h; } v;
  v.s = (u16)u;
  return (float)v.h;
}
DEV uint32 pack2h(float a, float b) {
  return (uint32)f2h(a) | ((uint32)f2h(b) << 16);
}
DEV float2 unp2h(uint32 u) {
  return make_float2(h2f(u & 0xFFFFu), h2f(u >> 16));
}
DEV void glds16(void* lds, const void* g) {
  __builtin_amdgcn_global_load_lds((const __attribute__((address_space(1))) unsigned int*)g,
                                   (__attribute__((address_space(3))) unsigned int*)lds, 16, 0, 0);
}
DEV void wave_sync() {
  asm volatile("s_waitcnt lgkmcnt(0)" ::: "memory");
  __builtin_amdgcn_sched_barrier(0);
}
DEV int dr10(int v) {   // base-4 digit reversal, 10-bit
  int r = (int)(__brev((unsigned)v) >> 22);
  return ((r & 0x155) << 1) | ((r & 0x2AA) >> 1);
}
constexpr int dr6c(int v) {   // base-4 digit reversal, 6-bit (involution)
  return ((v & 3) << 4) | (v & 12) | ((v >> 4) & 3);
}

// quarter-wave table: CQ[j] = cos(pi*j/32), j=0..16
constexpr float CQ[17] = {
  1.0f, 0.995184726672197f, 0.980785280403230f, 0.956940335732209f,
  0.923879532511287f, 0.881921264348355f, 0.831469612302545f, 0.773010453362737f,
  0.707106781186548f, 0.634393284163645f, 0.555570233019602f, 0.471396736825998f,
  0.382683432365090f, 0.290284677254462f, 0.195090322016128f, 0.098017140329561f, 0.0f };
constexpr float twc64(int j) {   // cos(2*pi*j/64)
  return (j & 63) <= 16 ? CQ[j & 63]
       : (j & 63) <= 32 ? -CQ[32 - (j & 63)]
       : (j & 63) <= 48 ? -CQ[(j & 63) - 32] : CQ[64 - (j & 63)];
}
constexpr float tws64(int j) {   // sin(2*pi*j/64)
  return (j & 63) <= 16 ? CQ[16 - (j & 63)]
       : (j & 63) <= 32 ? CQ[(j & 63) - 16]
       : (j & 63) <= 48 ? -CQ[48 - (j & 63)] : -CQ[(j & 63) - 48];
}

// cos/sin of pi*j/16, j = 0..15 (stage-offset twiddles for LDS FFTs)
constexpr float CR_C[16] = {
  1.0f, 0.980785280403230f, 0.923879532511287f, 0.831469612302545f,
  0.707106781186548f, 0.555570233019602f, 0.382683432365090f, 0.195090322016128f,
  0.0f, -0.195090322016128f, -0.382683432365090f, -0.555570233019602f,
  -0.707106781186548f, -0.831469612302545f, -0.923879532511287f, -0.980785280403230f };
constexpr float CR_S[16] = {
  0.0f, 0.195090322016128f, 0.382683432365090f, 0.555570233019602f,
  0.707106781186548f, 0.831469612302545f, 0.923879532511287f, 0.980785280403230f,
  1.0f, 0.980785280403230f, 0.923879532511287f, 0.831469612302545f,
  0.707106781186548f, 0.555570233019602f, 0.382683432365090f, 0.195090322016128f };

// ---------------- in-register 64-pt radix-4 FFTs (fully unrolled, const twiddles) -------------
template<int SGN>
DEV void rdif64(float2* z) {
  #pragma unroll
  for (int j = 0; j < 16; ++j) {
    float2 x0 = z[j], x1 = z[j + 16], x2 = z[j + 32], x3 = z[j + 48];
    float2 s0 = make_float2(x0.x + x2.x, x0.y + x2.y);
    float2 s1 = make_float2(x0.x - x2.x, x0.y - x2.y);
    float2 s2 = make_float2(x1.x + x3.x, x1.y + x3.y);
    float2 d  = make_float2(x1.x - x3.x, x1.y - x3.y);
    float2 s3 = (SGN < 0) ? make_float2(d.y, -d.x) : make_float2(-d.y, d.x);
    z[j] = make_float2(s0.x + s2.x, s0.y + s2.y);
    const float2 tf1 = make_float2(twc64(j),     (float)SGN * tws64(j));
    const float2 tf2 = make_float2(twc64(2 * j), (float)SGN * tws64(2 * j));
    const float2 tf3 = make_float2(twc64(3 * j), (float)SGN * tws64(3 * j));
    z[j + 16] = cmulf(make_float2(s1.x + s3.x, s1.y + s3.y), tf1);
    z[j + 32] = cmulf(make_float2(s0.x - s2.x, s0.y - s2.y), tf2);
    z[j + 48] = cmulf(make_float2(s1.x - s3.x, s1.y - s3.y), tf3);
  }
  #pragma unroll
  for (int b = 0; b < 64; b += 16)
    #pragma unroll
    for (int j = 0; j < 4; ++j) {
      const int i = b + j;
      float2 x0 = z[i], x1 = z[i + 4], x2 = z[i + 8], x3 = z[i + 12];
      float2 s0 = make_float2(x0.x + x2.x, x0.y + x2.y);
      float2 s1 = make_float2(x0.x - x2.x, x0.y - x2.y);
      float2 s2 = make_float2(x1.x + x3.x, x1.y + x3.y);
      float2 d  = make_float2(x1.x - x3.x, x1.y - x3.y);
      float2 s3 = (SGN < 0) ? make_float2(d.y, -d.x) : make_float2(-d.y, d.x);
      z[i] = make_float2(s0.x + s2.x, s0.y + s2.y);
      const float2 tf1 = make_float2(twc64(4 * j),  (float)SGN * tws64(4 * j));
      const float2 tf2 = make_float2(twc64(8 * j),  (float)SGN * tws64(8 * j));
      const float2 tf3 = make_float2(twc64(12 * j), (float)SGN * tws64(12 * j));
      z[i + 4]  = cmulf(make_float2(s1.x + s3.x, s1.y + s3.y), tf1);
      z[i + 8]  = cmulf(make_float2(s0.x - s2.x, s0.y - s2.y), tf2);
      z[i + 12] = cmulf(make_float2(s1.x - s3.x, s1.y - s3.y), tf3);
    }
  #pragma unroll
  for (int b = 0; b < 64; b += 4) {
    float2 x0 = z[b], x1 = z[b + 1], x2 = z[b + 2], x3 = z[b + 3];
    float2 s0 = make_float2(x0.x + x2.x, x0.y + x2.y);
    float2 s1 = make_float2(x0.x - x2.x, x0.y - x2.y);
    float2 s2 = make_float2(x1.x + x3.x, x1.y + x3.y);
    float2 d  = make_float2(x1.x - x3.x, x1.y - x3.y);
    float2 s3 = (SGN < 0) ? make_float2(d.y, -d.x) : make_float2(-d.y, d.x);
    z[b]     = make_float2(s0.x + s2.x, s0.y + s2.y);
    z[b + 1] = make_float2(s1.x + s3.x, s1.y + s3.y);
    z[b + 2] = make_float2(s0.x - s2.x, s0.y - s2.y);
    z[b + 3] = make_float2(s1.x - s3.x, s1.y - s3.y);
  }
}

template<int SGN>
DEV void rdit64(float2* z) {
  #pragma unroll
  for (int b = 0; b < 64; b += 4) {
    float2 b0 = z[b], b1 = z[b + 1], b2 = z[b + 2], b3 = z[b + 3];
    float2 t0 = make_float2(b0.x + b2.x, b0.y + b2.y);
    float2 t1 = make_float2(b0.x - b2.x, b0.y - b2.y);
    float2 t2 = make_float2(b1.x + b3.x, b1.y + b3.y);
    float2 d  = make_float2(b1.x - b3.x, b1.y - b3.y);
    float2 t3 = (SGN > 0) ? make_float2(-d.y, d.x) : make_float2(d.y, -d.x);
    z[b]     = make_float2(t0.x + t2.x, t0.y + t2.y);
    z[b + 1] = make_float2(t1.x + t3.x, t1.y + t3.y);
    z[b + 2] = make_float2(t0.x - t2.x, t0.y - t2.y);
    z[b + 3] = make_float2(t1.x - t3.x, t1.y - t3.y);
  }
  #pragma unroll
  for (int b = 0; b < 64; b += 16)
    #pragma unroll
    for (int j = 0; j < 4; ++j) {
      const int i = b + j;
      const float2 tf1 = make_float2(twc64(4 * j),  (float)SGN * tws64(4 * j));
      const float2 tf2 = make_float2(twc64(8 * j),  (float)SGN * tws64(8 * j));
      const float2 tf3 = make_float2(twc64(12 * j), (float)SGN * tws64(12 * j));
      float2 b0 = z[i];
      float2 b1 = cmulf(z[i + 4], tf1);
      float2 b2 = cmulf(z[i + 8], tf2);
      float2 b3 = cmulf(z[i + 12], tf3);
      float2 t0 = make_float2(b0.x + b2.x, b0.y + b2.y);
      float2 t1 = make_float2(b0.x - b2.x, b0.y - b2.y);
      float2 t2 = make_float2(b1.x + b3.x, b1.y + b3.y);
      float2 d  = make_float2(b1.x - b3.x, b1.y - b3.y);
      float2 t3 = (SGN > 0) ? make_float2(-d.y, d.x) : make_float2(d.y, -d.x);
      z[i]      = make_float2(t0.x + t2.x, t0.y + t2.y);
      z[i + 4]  = make_float2(t1.x + t3.x, t1.y + t3.y);
      z[i + 8]  = make_float2(t0.x - t2.x, t0.y - t2.y);
      z[i + 12] = make_float2(t1.x - t3.x, t1.y - t3.y);
    }
  #pragma unroll
  for (int j = 0; j < 16; ++j) {
    const float2 tf1 = make_float2(twc64(j),     (float)SGN * tws64(j));
    const float2 tf2 = make_float2(twc64(2 * j), (float)SGN * tws64(2 * j));
    const float2 tf3 = make_float2(twc64(3 * j), (float)SGN * tws64(3 * j));
    float2 b0 = z[j];
    float2 b1 = cmulf(z[j + 16], tf1);
    float2 b2 = cmulf(z[j + 32], tf2);
    float2 b3 = cmulf(z[j + 48], tf3);
    float2 t0 = make_float2(b0.x + b2.x, b0.y + b2.y);
    float2 t1 = make_float2(b0.x - b2.x, b0.y - b2.y);
    float2 t2 = make_float2(b1.x + b3.x, b1.y + b3.y);
    float2 d  = make_float2(b1.x - b3.x, b1.y - b3.y);
    float2 t3 = (SGN > 0) ? make_float2(-d.y, d.x) : make_float2(d.y, -d.x);
    z[j]      = make_float2(t0.x + t2.x, t0.y + t2.y);
    z[j + 16] = make_float2(t1.x + t3.x, t1.y + t3.y);
    z[j + 32] = make_float2(t0.x - t2.x, t0.y - t2.y);
    z[j + 48] = make_float2(t1.x - t3.x, t1.y - t3.y);
  }
}

// Radix-4 DIF over LDS, natural in -> digit-reversed out (negative exponent).
template<int L, int NLOG, int NSUB, bool WL>
DEV void dif4_stages(float2* F, int lg) {
  #pragma unroll
  for (int st = 0; st < NLOG / 2; ++st) {
    const int qlog = NLOG - 2 - 2 * st;
    const int q = 1 << qlog;
    float bs, bc;
    __sincosf((float)(lg & (q - 1)) * (-1.57079632679489661923f / (float)q), &bs, &bc);
    const float2 base = make_float2(bc, bs);
    #pragma unroll
    for (int u = 0; u < NSUB * (1 << (NLOG - 2)) / L; ++u) {
      const int sub = (u * L) >> (NLOG - 2);
      const int bf = ((u * L) & ((1 << (NLOG - 2)) - 1)) + lg;
      const int jj = ((u * L) % q) * 8 / q;
      const int i1 = (sub << NLOG) + ((bf >> qlog) << (qlog + 2)) + (bf & (q - 1));
      float2 x0 = F[i1], x1 = F[i1 + q], x2 = F[i1 + 2 * q], x3 = F[i1 + 3 * q];
      float2 s0 = make_float2(x0.x + x2.x, x0.y + x2.y);
      float2 s1 = make_float2(x0.x - x2.x, x0.y - x2.y);
      float2 s2 = make_float2(x1.x + x3.x, x1.y + x3.y);
      float2 dq = make_float2(x1.x - x3.x, x1.y - x3.y);
      float2 s3 = make_float2(dq.y, -dq.x);               // -i*(x1-x3)
      F[i1] = make_float2(s0.x + s2.x, s0.y + s2.y);
      if (qlog == 0) {
        F[i1 + 1] = make_float2(s1.x + s3.x, s1.y + s3.y);
        F[i1 + 2] = make_float2(s0.x - s2.x, s0.y - s2.y);
        F[i1 + 3] = make_float2(s1.x - s3.x, s1.y - s3.y);
      } else {
        const float2 tf1 = (jj == 0) ? base : cmulf(base, make_float2(CR_C[jj], -CR_S[jj]));
        const float2 tf2 = cmulf(tf1, tf1);
        const float2 tf3 = cmulf(tf2, tf1);
        F[i1 + q]     = cmulf(make_float2(s1.x + s3.x, s1.y + s3.y), tf1);
        F[i1 + 2 * q] = cmulf(make_float2(s0.x - s2.x, s0.y - s2.y), tf2);
        F[i1 + 3 * q] = cmulf(make_float2(s1.x - s3.x, s1.y - s3.y), tf3);
      }
    }
    if (WL) wave_sync(); else __syncthreads();
  }
}

// ---------------- quaternion helpers ----------------------------------------------------------
DEV float4 qmul4(float4 a, float4 b) {
  return make_float4(
    a.x * b.x - a.y * b.y - a.z * b.z - a.w * b.w,
    a.x * b.y + a.y * b.x + a.z * b.w - a.w * b.z,
    a.x * b.z - a.y * b.w + a.z * b.x + a.w * b.y,
    a.x * b.w + a.y * b.z - a.z * b.y + a.w * b.x);
}
DEV float4 qne(float4 q) {
  float n = sqrtf(q.x * q.x + q.y * q.y + q.z * q.z + q.w * q.w) + 1e-8f;
  float r = 1.0f / n;
  return make_float4(q.x * r, q.y * r, q.z * r, q.w * r);
}

// ---------------- fractal pass 1: 1024-pt radix-4 FFTs, wave-private; fp16-packed out --------
__global__ __launch_bounds__(512) void kx_fr_pass1(const float* __restrict__ x,
    const float* __restrict__ W_in, const float* __restrict__ b_in,
    uint32* __restrict__ zmid) {
  __shared__ float2 fb[8 * 1028];
  const int t = threadIdx.x, l = t & 63, w = t >> 6;
  const int btile = blockIdx.x, bz = blockIdx.y;
  const int bcol = btile * 8 + w;
  const int d = 2 * (bcol & 511);
  const int soff = bcol >> 9;
  const float w00 = W_in[d],     w10 = W_in[1024 + d], w20 = W_in[2048 + d], w30 = W_in[3072 + d];
  const float w01 = W_in[d + 1], w11 = W_in[1025 + d], w21 = W_in[2049 + d], w31 = W_in[3073 + d];
  const float bi0 = b_in[d], bi1 = b_in[d + 1];
  const float* xb = x + (size_t)bz * 4096 * 4;
  float2* fbw = fb + w * 1028;
  #pragma unroll
  for (int i = 0; i < 16; ++i) {
    int a = i * 64 + l;
    int s = 4 * a + soff;
    float4 xv = *(const float4*)(xb + (size_t)s * 4);
    float z0 = fmaf(xv.x, w00, fmaf(xv.y, w10, fmaf(xv.z, w20, fmaf(xv.w, w30, bi0))));
    float z1 = fmaf(xv.x, w01, fmaf(xv.y, w11, fmaf(xv.z, w21, fmaf(xv.w, w31, bi1))));
    fbw[a] = make_float2(z0, z1);
  }
  wave_sync();
  dif4_stages<64, 10, 1, true>(fbw, l);
  __syncthreads();
  uint32* dst = zmid + (size_t)bz * (1024 * 2048);
  #pragma unroll
  for (int i = 0; i < 16; ++i) {
    int idx = i * 512 + t;
    int w8 = idx & 7, cnat = idx >> 3;
    float2 v = fb[w8 * 1028 + dr10(cnat)];
    dst[(size_t)cnat * 2048 + btile * 8 + w8] = pack2h(v.x, v.y);
  }
}

DEV float block_reduce128(float* red, int t, float v) {
  red[t] = v; __syncthreads();
  for (int s = 64; s; s >>= 1) { if (t < s) red[t] += red[t + s]; __syncthreads(); }
  float r = red[0]; __syncthreads();
  return r;
}

// ---------------- fractal pass 2: fp16 Zmid in; LDS exactly 32KB (reduce buf overlaid) -------
__global__ __launch_bounds__(128) void kx_fr_pass2(const uint32* __restrict__ zmid,
    float* __restrict__ partials, float* __restrict__ sparts) {
  __shared__ float2 fb[2 * 2048];
  const int t = threadIdx.x, l = t & 63, w = t >> 6;   // w in {0,1}
  const int cg = blockIdx.x, bz = blockIdx.y;
  const int c = (cg == 0) ? (w ? 512 : 0) : (w ? (1024 - cg) : cg);
  const uint32* src = zmid + ((size_t)bz * 1024 + c) * 2048;
  float2* fbc = fb + w * 2048;
  float2 rot[4], stp4;
  {
    float sn, cs;
    __sincosf((float)(l * c) * (-6.28318530717958647692f / 2097152.0f), &sn, &cs);
    rot[0] = make_float2(cs, sn);
    float2 stp;
    __sincosf((float)c * (-6.28318530717958647692f / 32768.0f), &sn, &cs);
    stp = make_float2(cs, sn);
    rot[1] = cmulf(rot[0], stp);
    float2 stp2 = cmulf(stp, stp);
    rot[2] = cmulf(rot[0], stp2);
    rot[3] = cmulf(rot[1], stp2);
    stp4 = cmulf(stp2, stp2);
  }
  float2 zr[32];
  #pragma unroll
  for (int i = 0; i < 32; ++i) {
    int bb = i * 64 + l;
    zr[i] = cmulf(unp2h(src[bb]), rot[i & 3]);
    rot[i & 3] = cmulf(rot[i & 3], stp4);
  }
  {
    float bs, bc;
    __sincosf((float)l * (-3.14159265358979323846f / 1024.0f), &bs, &bc);
    const float2 b2 = make_float2(bc, bs);
    #pragma unroll
    for (int u = 0; u < 16; ++u) {
      const float2 tf = (u == 0) ? b2 : cmulf(b2, make_float2(CR_C[u], -CR_S[u]));
      int i1 = u * 64 + l;
      float2 a0 = zr[u], a1 = zr[u + 16];
      fbc[i1] = make_float2(a0.x + a1.x, a0.y + a1.y);
      fbc[i1 + 1024] = cmulf(make_float2(a0.x - a1.x, a0.y - a1.y), tf);
    }
    wave_sync();
  }
  dif4_stages<64, 10, 2, true>(fbc, l);
  __syncthreads();
  float t0 = 0.f, t1 = 0.f, s0 = 0.f, s1 = 0.f, s2 = 0.f;
  if (cg != 0) {
    const float2* fbm = fb + (1 - w) * 2048;
    float2 pw[32];
    pw[0] = make_float2(1.f, 0.f);
    {
      float sn, cs;
      __sincosf(-3.14159265358979323846f / 2048.0f, &sn, &cs);
      float2 w1 = make_float2(cs, sn);
      #pragma unroll
      for (int j = 1; j < 32; ++j) pw[j] = cmulf(pw[j - 1], w1);
    }
    const int drl = (l & 3) * 256 + ((l >> 2) & 3) * 64 + ((l >> 4) & 3) * 16;
    float2 base2;
    {
      float sn, cs;
      __sincosf((float)drl * (-3.14159265358979323846f / 1024.0f), &sn, &cs);
      float2 lf = make_float2(cs, sn);
      __sincosf((float)c * (-6.28318530717958647692f / 4194304.0f), &sn, &cs);
      base2 = cmulf(make_float2(cs, sn), lf);
    }
    #pragma unroll
    for (int i = 0; i < 32; ++i) {
      const int p = i * 64 + l;
      const int dri = (i & 3) * 4 + ((i >> 2) & 3);
      const int top = i >> 4;
      const int dd = 2 * (drl + dri) + top;
      float2 Zk = fbc[p];
      float2 Zm = fbm[2047 - p];
      float2 E = make_float2(0.5f * (Zk.x + Zm.x), 0.5f * (Zk.y - Zm.y));
      float2 A = make_float2(Zk.x - Zm.x, Zk.y + Zm.y);
      float2 O = make_float2(0.5f * A.y, -0.5f * A.x);
      float2 urot = cmulf(base2, pw[2 * dri + top]);
      float2 U = cmulf(urot, O);
      float Xr = E.x + U.x, Xi = E.y + U.y;
      float P = Xr * Xr + Xi * Xi;
      int k = c + (dd << 10);
      float fr = (float)k * (1.0f / 4194304.0f);
      if (fr > 0.01f && fr < 0.5f) {
        float lp = __logf(P + 1e-10f);
        float lk = __logf(fr + 1e-10f);
        t0 += lp; t1 += lk * lp;
        s0 += 1.0f; s1 += lk; s2 += lk * lk;
      }
    }
  } else {
    const float2* fbm = fbc;   // self-mirrored columns (c = 0, 512)
    float2 urot;
    {
      float sn, cs;
      __sincosf((float)(c + l * 1024) * (-6.28318530717958647692f / 4194304.0f), &sn, &cs);
      urot = make_float2(cs, sn);
    }
    const float2 ustp = make_float2(0.995184726672197f, -0.0980171403295606f); // e^{-i pi/32}
    #pragma unroll
    for (int i = 0; i < 32; ++i) {
      int dd = i * 64 + l;
      int md = (c == 0) ? ((2048 - dd) & 2047) : (2047 - dd);
      int pk = ((dd & 1) << 10) | dr10(dd >> 1);
      int pm = ((md & 1) << 10) | dr10(md >> 1);
      float2 Zk = fbc[pk];
      float2 Zm = fbm[pm];
      float2 E = make_float2(0.5f * (Zk.x + Zm.x), 0.5f * (Zk.y - Zm.y));
      float2 A = make_float2(Zk.x - Zm.x, Zk.y + Zm.y);
      float2 O = make_float2(0.5f * A.y, -0.5f * A.x);
      float2 U = cmulf(urot, O);
      float Xr = E.x + U.x, Xi = E.y + U.y;
      float P = Xr * Xr + Xi * Xi;
      int k = c + (dd << 10);
      float fr = (float)k * (1.0f / 4194304.0f);
      if (fr > 0.01f && fr < 0.5f) {
        float lp = __logf(P + 1e-10f);
        float lk = __logf(fr + 1e-10f);
        t0 += lp; t1 += lk * lp;
        s0 += 1.0f; s1 += lk; s2 += lk * lk;
      }
      urot = cmulf(urot, ustp);
    }
  }
  __syncthreads();                       // fb dead; reuse as reduction buffer
  float* red = (float*)fb;
  float T0 = block_reduce128(red, t, t0);
  float T1 = block_reduce128(red, t, t1);
  if (t == 0) {
    partials[((size_t)bz * 512 + cg) * 2 + 0] = T0;
    partials[((size_t)bz * 512 + cg) * 2 + 1] = T1;
  }
  if (bz == 0) {
    float S0 = block_reduce128(red, t, s0);
    float S1 = block_reduce128(red, t, s1);
    float S2 = block_reduce128(red, t, s2);
    if (t == 0) { sparts[cg * 3] = S0; sparts[cg * 3 + 1] = S1; sparts[cg * 3 + 2] = S2; }
  }
}

DEV float block_reduce256s(float* sh, int t, float v) {
  sh[t] = v; __syncthreads();
  for (int s = 128; s; s >>= 1) { if (t < s) sh[t] += sh[t + s]; __syncthreads(); }
  float r = sh[0]; __syncthreads();
  return r;
}

// ---------------- merged: gains (+alpha +gelu recompute +quats) and W transpose ---------------
// blocks 0..127: gains for bh; block 0 also writes composed quats.
// blocks 128..383: W_attn_out transpose (q = bid-128: nt = q&15, dt = q>>4).
__global__ __launch_bounds__(256) void kx_gainsall(const float* __restrict__ partials,
    const float* __restrict__ sparts, const float* __restrict__ abase,
    const float* __restrict__ pshift, const float* __restrict__ thL,
    const float* __restrict__ thR, const float* __restrict__ W,
    u16* __restrict__ Wt, float* __restrict__ gains, float* __restrict__ qlr) {
  const int bid = blockIdx.x;
  const int t = threadIdx.x;
  if (bid >= 128) {
    __shared__ float tile[64][65];
    const int q = bid - 128;
    const int nt = q & 15, dt = q >> 4;
    #pragma unroll
    for (int i = 0; i < 16; ++i) {
      int idx = i * 256 + t;
      int r = idx >> 6, cc = idx & 63;
      tile[r][cc] = W[(size_t)(dt * 64 + r) * 1024 + nt * 64 + cc];
    }
    __syncthreads();
    #pragma unroll
    for (int i = 0; i < 2; ++i) {
      int task = i * 256 + t;
      int nl = task >> 3, g = task & 7;
      union { u16 h[8]; uint4 v; } pk;
      #pragma unroll
      for (int k = 0; k < 8; ++k) pk.h[k] = f2h(tile[g * 8 + k][nl]);
      size_t idx = (size_t)(nt * 64 + nl) * 1024 + dt * 64 + ((g ^ (nl & 7)) << 3);
      *(uint4*)(Wt + idx) = pk.v;
    }
    return;
  }
  __shared__ float red[256];
  float s0 = 0.f, s1 = 0.f, s2 = 0.f;
  for (int i = t; i < 512; i += 256) {
    s0 += sparts[i * 3]; s1 += sparts[i * 3 + 1]; s2 += sparts[i * 3 + 2];
  }
  s0 = block_reduce256s(red, t, s0);
  s1 = block_reduce256s(red, t, s1);
  s2 = block_reduce256s(red, t, s2);
  const float mk = s1 / s0;
  const float var = s2 - mk * s1;
  const int b = bid >> 4, h = bid & 15;
  float t0 = 0.f, t1 = 0.f;
  for (int i = t; i < 512; i += 256) {
    t0 += partials[((size_t)b * 512 + i) * 2];
    t1 += partials[((size_t)b * 512 + i) * 2 + 1];
  }
  t0 = block_reduce256s(red, t, t0);
  t1 = block_reduce256s(red, t, t1);
  const float cov = t1 - mk * t0;
  const float beta = -cov / (var + 1e-10f);
  const float D = fminf(fmaxf((3.0f - beta) * 0.5f, 0.5f), 1.5f);
  const float alpha = fminf(fmaxf(1.0f + 0.8f * (D - 1.0f), 0.1f), 3.0f);
  const float aa = abase[h] * alpha;
  const float ps = pshift[h];
  // lk stats over 4096 (ddof=1); each thread holds 16 values
  float lkv[16];
  float ls = 0.f;
  #pragma unroll
  for (int i = 0; i < 16; ++i) {
    int s = i * 256 + t;
    int m = (s < 2048) ? s : (4096 - s);
    lkv[i] = logf((float)m * (1.0f / 4096.0f) + 1e-8f);
    ls += lkv[i];
  }
  const float mean = block_reduce256s(red, t, ls) * (1.0f / 4096.0f);
  float vs = 0.f;
  #pragma unroll
  for (int i = 0; i < 16; ++i) { float dv = lkv[i] - mean; vs += dv * dv; }
  const float sd = sqrtf(block_reduce256s(red, t, vs) * (1.0f / 4095.0f));
  for (int k = t; k < 2049; k += 256) {
    float lk_k = logf((float)k * (1.0f / 4096.0f) + 1e-8f);
    float xn = (lk_k - mean) / (sd + 1e-8f);
    float ge = 0.5f * xn * (1.0f + erff(xn * 0.70710678118654752440f));
    gains[(size_t)bid * 2064 + k] = cosf(fmaf(aa, ge, ps));
  }
  if (bid == 0 && t == 0) {
    float4 QL = make_float4(1.f, 0.f, 0.f, 0.f);
    float4 QRC = make_float4(1.f, 0.f, 0.f, 0.f);
    for (int it = 0; it < 4; ++it) {
      float ss0, cc0, ss1, cc1, ss2, cc2;
      sincosf(0.5f * thL[it * 3 + 0], &ss0, &cc0);
      sincosf(0.5f * thL[it * 3 + 1], &ss1, &cc1);
      sincosf(0.5f * thL[it * 3 + 2], &ss2, &cc2);
      float4 qL = qne(make_float4(cc0 * cc1 * cc2, ss0 * cc1 * cc2, cc0 * ss1 * cc2, cc0 * cc1 * ss2));
      QL = qmul4(qL, QL);
      sincosf(0.5f * thR[it * 3 + 0], &ss0, &cc0);
      sincosf(0.5f * thR[it * 3 + 1], &ss1, &cc1);
      sincosf(0.5f * thR[it * 3 + 2], &ss2, &cc2);
      float4 qR = qne(make_float4(cc0 * cc1 * cc2, ss0 * cc1 * cc2, cc0 * ss1 * cc2, cc0 * cc1 * ss2));
      QRC = qmul4(QRC, make_float4(qR.x, -qR.y, -qR.z, -qR.w));
    }
    *(float4*)qlr = QL;
    *(float4*)(qlr + 4) = QRC;
  }
}

// ---------------- spectral filter: four-step register FFT (64x64), sequential store ----------
__global__ __launch_bounds__(128, 1) void kx_filter(const float* __restrict__ x,
    const float* __restrict__ W_in, const float* __restrict__ b_in,
    const float* __restrict__ gains, uint32* __restrict__ XFp) {
  __shared__ uint32 tr[2][4096];   // fp16x2 transpose buffer, 16KB per wave
  const int t = threadIdx.x, l = t & 63, wv = t >> 6;
  const int g = blockIdx.x, h = blockIdx.y, bz = blockIdx.z;
  const int d0 = h * 64 + g * 4 + wv * 2;
  const float* gn = gains + ((size_t)bz * 16 + h) * 2064;
  const float wa0 = W_in[d0],     wa1 = W_in[1024 + d0], wa2 = W_in[2048 + d0], wa3 = W_in[3072 + d0];
  const float wb0 = W_in[d0 + 1], wb1 = W_in[1025 + d0], wb2 = W_in[2049 + d0], wb3 = W_in[3073 + d0];
  const float bia = b_in[d0], bib = b_in[d0 + 1];
  const float* xb = x + (size_t)bz * 4096 * 4;
  uint32* trw = tr[wv];
  float2 z[64];
  #pragma unroll
  for (int r = 0; r < 64; ++r) {
    int s = r * 64 + l;
    float4 xv = *(const float4*)(xb + (size_t)s * 4);
    float za = fmaf(xv.x, wa0, fmaf(xv.y, wa1, fmaf(xv.z, wa2, fmaf(xv.w, wa3, bia))));
    float zb = fmaf(xv.x, wb0, fmaf(xv.y, wb1, fmaf(xv.z, wb2, fmaf(xv.w, wb3, bib))));
    z[r] = make_float2(za, zb);
  }
  rdif64<-1>(z);
  {
    float sn, cs;
    __sincosf((float)l * (-6.28318530717958647692f / 4096.0f), &sn, &cs);
    float2 w1 = make_float2(cs, sn);
    float2 w2 = cmulf(w1, w1);
    float2 w4 = cmulf(w2, w2);
    float2 tch[4] = { make_float2(1.f, 0.f), w1, w2, cmulf(w2, w1) };
    #pragma unroll
    for (int i = 0; i < 16; ++i) {
      #pragma unroll
      for (int j = 0; j < 4; ++j) {
        const int rr = dr6c(4 * i + j);
        z[rr] = cmulf(z[rr], tch[j]);
      }
      #pragma unroll
      for (int j = 0; j < 4; ++j) tch[j] = cmulf(tch[j], w4);
    }
  }
  #pragma unroll
  for (int r = 0; r < 64; ++r) {
    const int k1 = dr6c(r);
    trw[k1 * 64 + ((l + k1) & 63)] = pack2h(z[r].x, z[r].y);
  }
  wave_sync();
  #pragma unroll
  for (int c = 0; c < 64; ++c) {
    uint32 u = trw[l * 64 + ((c + l) & 63)];
    z[c] = unp2h(u);
  }
  wave_sync();
  rdif64<-1>(z);
  #pragma unroll
  for (int r = 0; r < 64; ++r) {
    const int k = l + (dr6c(r) << 6);
    const int km = (k < 2048) ? k : (4096 - k);
    const float gk = gn[km];
    z[r] = make_float2(z[r].x * gk, z[r].y * gk);
  }
  rdit64<1>(z);
  {
    float sn, cs;
    __sincosf((float)l * (6.28318530717958647692f / 4096.0f), &sn, &cs);
    float2 v1 = make_float2(cs, sn);
    float2 v2 = cmulf(v1, v1);
    float2 v4 = cmulf(v2, v2);
    float2 tch[4] = { make_float2(1.f, 0.f), v1, v2, cmulf(v2, v1) };
    #pragma unroll
    for (int i = 0; i < 16; ++i) {
      #pragma unroll
      for (int j = 0; j < 4; ++j)
        z[4 * i + j] = cmulf(z[4 * i + j], tch[j]);
      #pragma unroll
      for (int j = 0; j < 4; ++j) tch[j] = cmulf(tch[j], v4);
    }
  }
  #pragma unroll
  for (int r = 0; r < 64; ++r)
    trw[r * 64 + ((l + r) & 63)] = pack2h(z[r].x, z[r].y);
  wave_sync();
  #pragma unroll
  for (int c = 0; c < 64; ++c) {
    uint32 u = trw[l * 64 + ((c + l) & 63)];
    z[c] = unp2h(u);
  }
  wave_sync();
  #pragma unroll
  for (int j = 0; j < 64; ++j) {
    const int dj = dr6c(j);
    if (dj > j) { float2 tmp = z[j]; z[j] = z[dj]; z[dj] = tmp; }
  }
  rdit64<1>(z);
  uint32* rowp = XFp + ((size_t)bz * 512 + (d0 >> 1)) * 4096;
  const float sc = 1.0f / 4096.0f;
  #pragma unroll
  for (int r = 0; r < 64; ++r)
    rowp[r * 64 + l] = pack2h(z[r].x * sc, z[r].y * sc);
}

// ---------------- A transpose: u32 [b][512 p][4096 s] -> [b][4096 s][512 p] + slot swizzle ----
__global__ __launch_bounds__(256) void kx_a16(const uint32* __restrict__ XFp, uint32* __restrict__ Aswz) {
  __shared__ uint32 tl[64][65];
  const int t = threadIdx.x;
  const int st = blockIdx.x, pt = blockIdx.y, bz = blockIdx.z;
  const uint32* src = XFp + ((size_t)bz * 512 + pt * 64) * 4096 + st * 64;
  #pragma unroll
  for (int i = 0; i < 16; ++i) {
    int p = i * 4 + (t >> 6);
    int s = t & 63;
    tl[p][s] = src[(size_t)p * 4096 + s];
  }
  __syncthreads();
  uint32* dst = Aswz + ((size_t)bz * 4096 + st * 64) * 512 + pt * 64;
  #pragma unroll
  for (int i = 0; i < 16; ++i) {
    int s = i * 4 + (t >> 6);
    int c = t & 63;
    int gsl = ((c & 31) >> 2) ^ (s & 7);
    int u32idx = (c >> 5) * 32 + gsl * 4 + (c & 3);
    dst[(size_t)s * 512 + u32idx] = tl[c][s];
  }
}

// ---------------- fp16 MFMA GEMM: C16[32768x1024] = A*W (fp16 out) ----------------------------
__global__ __launch_bounds__(256) void kx_gemm(const u16* __restrict__ A,
    const u16* __restrict__ Bw, u16* __restrict__ C) {
  __shared__ u16 sm[32768];
  const int t = threadIdx.x, l = t & 63, w = t >> 6;
  const int wm = w >> 1, wn = w & 1;
  const int id = blockIdx.x;
  const int wg = (id & 7) * 256 + (id >> 3);        // XCD-contiguous chunks (2048 blocks)
  const int bm = wg >> 3, bn = wg & 7;
  const int bh = bm >> 5;
  const u16* Ab = A + ((size_t)(bh * 4096 + (bm & 31) * 128)) * 1024;
  const u16* Bb = Bw + (size_t)(bn * 128) * 1024;
  const int fr = l & 15;
  const int lr = l >> 3, lg = l & 7;
  f32x4 acc[4][4];
  #pragma unroll
  for (int m = 0; m < 4; ++m)
    #pragma unroll
    for (int n = 0; n < 4; ++n) acc[m][n] = (f32x4){0.f, 0.f, 0.f, 0.f};

  #define STAGE(KT, BUF) { \
    u16* Ad = sm + (BUF) * 8192; \
    u16* Bd = sm + 16384 + (BUF) * 8192; \
    _Pragma("unroll") \
    for (int j = 0; j < 4; ++j) { \
      int qq = j * 4 + w; \
      glds16((void*)(Ad + qq * 512), Ab + (size_t)(qq * 8 + lr) * 1024 + (KT) * 64 + lg * 8); \
      glds16((void*)(Bd + qq * 512), Bb + (size_t)(qq * 8 + lr) * 1024 + (KT) * 64 + lg * 8); \
    } }

  STAGE(0, 0);
  __syncthreads();
  for (int kt = 0; kt < 16; ++kt) {
    const int cur = kt & 1;
    if (kt < 15) STAGE(kt + 1, cur ^ 1);
    const u16* Ac = sm + cur * 8192;
    const u16* Bc = sm + 16384 + cur * 8192;
    #pragma unroll
    for (int kk = 0; kk < 2; ++kk) {
      const int g8r = kk * 4 + (l >> 4);
      f16x8 af[4], bf[4];
      #pragma unroll
      for (int m = 0; m < 4; ++m) {
        int s = wm * 64 + m * 16 + fr;
        af[m] = *(const f16x8*)&Ac[s * 64 + ((g8r ^ (s & 7)) << 3)];
      }
      #pragma unroll
      for (int n = 0; n < 4; ++n) {
        int nn = wn * 64 + n * 16 + fr;
        bf[n] = *(const f16x8*)&Bc[nn * 64 + ((g8r ^ (nn & 7)) << 3)];
      }
      #pragma unroll
      for (int m = 0; m < 4; ++m)
        #pragma unroll
        for (int n = 0; n < 4; ++n)
          acc[m][n] = __builtin_amdgcn_mfma_f32_16x16x32_f16(af[m], bf[n], acc[m][n], 0, 0, 0);
    }
    __syncthreads();
  }
  float* Cs = (float*)sm;
  const int rl4 = (l >> 4) * 4;
  #pragma unroll
  for (int m = 0; m < 4; ++m) {
    int rbase = wm * 64 + m * 16 + rl4;
    #pragma unroll
    for (int n = 0; n < 4; ++n) {
      int cc = wn * 64 + n * 16 + fr;
      #pragma unroll
      for (int e = 0; e < 4; ++e) {
        int r = rbase + e;
        Cs[r * 128 + (cc ^ (((r >> 2) & 3) << 3))] = acc[m][n][e];
      }
    }
  }
  __syncthreads();
  u16* cgp = C + (size_t)(bm * 128) * 1024 + bn * 128;
  #pragma unroll
  for (int it = 0; it < 16; ++it) {
    int idx = it * 256 + t;
    int r = idx >> 5, c4 = (idx & 31) * 4;
    f32x4 v = *(const f32x4*)&Cs[r * 128 + (c4 ^ (((r >> 2) & 3) << 3))];
    u32x2 pv;
    pv.x = (uint32)f2h(v.x) | ((uint32)f2h(v.y) << 16);
    pv.y = (uint32)f2h(v.z) | ((uint32)f2h(v.w) << 16);
    __builtin_nontemporal_store(pv, (u32x2*)(cgp + (size_t)r * 1024 + c4));
  }
}

// ---------------- tail: LN(xp+out) -> @W_out -> composed quat -> FF ----------------------------
DEV float wred64(float v) {
  #pragma unroll
  for (int m = 32; m; m >>= 1) v += __shfl_xor(v, m);
  return v;
}
DEV float4 ln4q(float4 v, const float* g, const float* b) {
  float m = 0.25f * (v.x + v.y + v.z + v.w);
  float a0 = v.x - m, a1 = v.y - m, a2 = v.z - m, a3 = v.w - m;
  float var = 0.25f * (a0 * a0 + a1 * a1 + a2 * a2 + a3 * a3);
  float rs = 1.0f / sqrtf(var + 1e-5f);
  return make_float4(a0 * rs * g[0] + b[0], a1 * rs * g[1] + b[1],
                     a2 * rs * g[2] + b[2], a3 * rs * g[3] + b[3]);
}
DEV float gelu1(float v) { return 0.5f * v * (1.0f + erff(v * 0.70710678118654752440f)); }

__global__ __launch_bounds__(256) void kx_tail(const u16* __restrict__ G,
    const float* __restrict__ x, const float* __restrict__ W_in, const float* __restrict__ b_in,
    const float* __restrict__ b_attn, const float* __restrict__ lng, const float* __restrict__ lnb,
    const float* __restrict__ W_out, const float* __restrict__ b_out,
    const float* __restrict__ qlr,
    const float* __restrict__ Wf1, const float* __restrict__ bff1,
    const float* __restrict__ Wf2, const float* __restrict__ bff2,
    const float* __restrict__ n1g, const float* __restrict__ n1b,
    const float* __restrict__ n2g, const float* __restrict__ n2b,
    const float* __restrict__ n3g, const float* __restrict__ n3b,
    float* __restrict__ out) {
  const int l = threadIdx.x & 63, w = threadIdx.x >> 6;
  const size_t rg = (size_t)blockIdx.x * 4 + w;
  const float4 x4 = *(const float4*)(x + rg * 4);
  float4 tv[4];
  float lsum = 0.f;
  #pragma unroll
  for (int j = 0; j < 4; ++j) {
    int dd = j * 256 + l * 4;
    uint2 gv = *(const uint2*)(G + rg * 1024 + dd);
    float4 g4 = make_float4(h2f(gv.x & 0xFFFFu), h2f(gv.x >> 16),
                            h2f(gv.y & 0xFFFFu), h2f(gv.y >> 16));
    float4 w0 = *(const float4*)(W_in + dd);
    float4 w1 = *(const float4*)(W_in + 1024 + dd);
    float4 w2 = *(const float4*)(W_in + 2048 + dd);
    float4 w3 = *(const float4*)(W_in + 3072 + dd);
    float4 bi = *(const float4*)(b_in + dd);
    float4 ba = *(const float4*)(b_attn + dd);
    float4 o;
    o.x = g4.x + bi.x + ba.x + x4.x * w0.x + x4.y * w1.x + x4.z * w2.x + x4.w * w3.x;
    o.y = g4.y + bi.y + ba.y + x4.x * w0.y + x4.y * w1.y + x4.z * w2.y + x4.w * w3.y;
    o.z = g4.z + bi.z + ba.z + x4.x * w0.z + x4.y * w1.z + x4.z * w2.z + x4.w * w3.z;
    o.w = g4.w + bi.w + ba.w + x4.x * w0.w + x4.y * w1.w + x4.z * w2.w + x4.w * w3.w;
    tv[j] = o;
    lsum += o.x + o.y + o.z + o.w;
  }
  const float mean = wred64(lsum) * (1.0f / 1024.0f);
  float vsum = 0.f;
  #pragma unroll
  for (int j = 0; j < 4; ++j) {
    float a0 = tv[j].x - mean, a1 = tv[j].y - mean, a2 = tv[j].z - mean, a3 = tv[j].w - mean;
    vsum += a0 * a0 + a1 * a1 + a2 * a2 + a3 * a3;
  }
  const float rstd = 1.0f / sqrtf(wred64(vsum) * (1.0f / 1024.0f) + 1e-5f);
  float4 aq = make_float4(0.f, 0.f, 0.f, 0.f);
  #pragma unroll
  for (int j = 0; j < 4; ++j) {
    int dd = j * 256 + l * 4;
    float4 gg = *(const float4*)(lng + dd);
    float4 bb = *(const float4*)(lnb + dd);
    float av[4];
    av[0] = (tv[j].x - mean) * rstd * gg.x + bb.x;
    av[1] = (tv[j].y - mean) * rstd * gg.y + bb.y;
    av[2] = (tv[j].z - mean) * rstd * gg.z + bb.z;
    av[3] = (tv[j].w - mean) * rstd * gg.w + bb.w;
    #pragma unroll
    for (int e = 0; e < 4; ++e) {
      float4 wr = *(const float4*)(W_out + (size_t)(dd + e) * 4);
      aq.x = fmaf(av[e], wr.x, aq.x);
      aq.y = fmaf(av[e], wr.y, aq.y);
      aq.z = fmaf(av[e], wr.z, aq.z);
      aq.w = fmaf(av[e], wr.w, aq.w);
    }
  }
  aq.x = wred64(aq.x) + b_out[0];
  aq.y = wred64(aq.y) + b_out[1];
  aq.z = wred64(aq.z) + b_out[2];
  aq.w = wred64(aq.w) + b_out[3];
  float4 q1 = make_float4(x4.x + aq.x, x4.y + aq.y, x4.z + aq.z, x4.w + aq.w);
  float4 hq = qne(ln4q(q1, n1g, n1b));
  const float4 QL = *(const float4*)qlr;
  const float4 QRC = *(const float4*)(qlr + 4);
  float4 o = qne(qmul4(qmul4(QL, hq), QRC));
  float4 h2 = qne(ln4q(make_float4(hq.x + o.x, hq.y + o.y, hq.z + o.z, hq.w + o.w), n2g, n2b));
  float ffx = 0.f, ffy = 0.f, ffz = 0.f, ffw = 0.f;
  if (l < 16) {
    float uv = bff1[l] + h2.x * Wf1[l] + h2.y * Wf1[16 + l] + h2.z * Wf1[32 + l] + h2.w * Wf1[48 + l];
    uv = gelu1(uv);
    float4 w2r = *(const float4*)(Wf2 + l * 4);
    ffx = uv * w2r.x; ffy = uv * w2r.y; ffz = uv * w2r.z; ffw = uv * w2r.w;
  }
  ffx = wred64(ffx) + bff2[0];
  ffy = wred64(ffy) + bff2[1];
  ffz = wred64(ffz) + bff2[2];
  ffw = wred64(ffw) + bff2[3];
  float4 h3 = qne(ln4q(make_float4(h2.x + ffx, h2.y + ffy, h2.z + ffz, h2.w + ffw), n3g, n3b));
  if (l == 0) *(float4*)(out + rg * 4) = h3;
}

extern "C" void kernel_launch(void* const* d_in, const int* in_sizes, int n_in,
                              void* d_out, int out_size, void* d_ws, size_t ws_size,
                              hipStream_t stream) {
  (void)in_sizes; (void)n_in; (void)out_size;
  const float* x      = (const float*)d_in[0];
  const float* W_in   = (const float*)d_in[1];
  const float* b_in   = (const float*)d_in[2];
  const float* abase  = (const float*)d_in[3];
  const float* pshift = (const float*)d_in[4];
  const float* Wattn  = (const float*)d_in[5];
  const float* battn  = (const float*)d_in[6];
  const float* lng    = (const float*)d_in[7];
  const float* lnb    = (const float*)d_in[8];
  const float* Wout   = (const float*)d_in[9];
  const float* bout   = (const float*)d_in[10];
  const float* thL    = (const float*)d_in[11];
  const float* thR    = (const float*)d_in[12];
  const float* Wf1    = (const float*)d_in[13];
  const float* bff1   = (const float*)d_in[14];
  const float* Wf2    = (const float*)d_in[15];
  const float* bff2   = (const float*)d_in[16];
  const float* n1g    = (const float*)d_in[17];
  const float* n1b    = (const float*)d_in[18];
  const float* n2g    = (const float*)d_in[19];
  const float* n2b    = (const float*)d_in[20];
  const float* n3g    = (const float*)d_in[21];
  const float* n3b    = (const float*)d_in[22];

  if (ws_size < (size_t)138459204) return;  // ~132 MiB
  char* ws = (char*)d_ws;
  uint32* Zmid  = (uint32*)ws;                       // 64MiB fp16-packed (fractal only)
  uint32* XFp   = (uint32*)ws;                       // 64MiB (filter out, u32 pair [b][p][s])
  u16*   Aswz   = (u16*)(ws + 67108864);             // 64MiB (A fp16 [b][s][d] pre-swizzled)
  u16*   C16    = (u16*)ws;                          // 64MiB fp16 gemm out (overlays dead XFp)
  u16*   W2h    = (u16*)(ws + 134217728);            // 2MiB fp16 W^T pre-swizzled
  float* gainsw = (float*)(ws + 136314880);          // ~1MiB gain table [128][2064]
  float* qlrw   = (float*)(ws + 137400320);          // 32B composed quats
  float* partials = (float*)(ws + 138412032);        // 32KB
  float* sparts   = (float*)(ws + 138444800);        // 6KB

  kx_fr_pass1<<<dim3(256, 8), 512, 0, stream>>>(x, W_in, b_in, Zmid);
  kx_fr_pass2<<<dim3(512, 8), 128, 0, stream>>>(Zmid, partials, sparts);
  kx_gainsall<<<384, 256, 0, stream>>>(partials, sparts, abase, pshift, thL, thR,
                                       Wattn, W2h, gainsw, qlrw);
  kx_filter<<<dim3(16, 16, 8), 128, 0, stream>>>(x, W_in, b_in, gainsw, XFp);
  kx_a16<<<dim3(64, 8, 8), 256, 0, stream>>>(XFp, (uint32*)Aswz);
  kx_gemm<<<2048, 256, 0, stream>>>(Aswz, W2h, C16);
  kx_tail<<<8192, 256, 0, stream>>>(C16, x, W_in, b_in, battn, lng, lnb, Wout, bout,
                                    qlrw, Wf1, bff1, Wf2, bff2,
                                    n1g, n1b, n2g, n2b, n3g, n3b, (float*)d_out);
}

// Round 20
// 395.248 us; speedup vs baseline: 1.3708x; 1.0572x over previous
//
#include <hip/hip_runtime.h>
#include <hip/hip_bf16.h>
#include <math.h>

// PsiQRH block, MI355X. B=8 S=4096 QD=4 DM=1024 H=16 HD=64.
// Round 20: kx_a16 eliminated — GEMM reads A directly from XFp [b][pair][s]
// (4 consecutive pair-u32 rows == one 8-d MFMA fragment), glds16 staging with
// pre-swizzled global source (g^=p&7), 2-way-free LDS reads. C16 moved to the
// old Aswz region (gemm now reads XFp, must not overlay).

#define DEV static __device__ __forceinline__
typedef unsigned int uint32;
typedef unsigned short u16;

typedef __attribute__((ext_vector_type(8))) _Float16 f16x8;
typedef __attribute__((ext_vector_type(4))) float f32x4;
typedef __attribute__((ext_vector_type(2))) unsigned int u32x2;

DEV float2 cmulf(float2 a, float2 b) {
  return make_float2(a.x * b.x - a.y * b.y, a.x * b.y + a.y * b.x);
}
DEV u16 f2h(float f) {
  union { _Float16 h; u16 u; } v;
  v.h = (_Float16)f;
  return v.u;
}
DEV float h2f(uint32 u) {
  union { u16 s; _Float16 h; } v;
  v.s = (u16)u;
  return (float)v.h;
}
DEV uint32 pack2h(float a, float b) {
  return (uint32)f2h(a) | ((uint32)f2h(b) << 16);
}
DEV float2 unp2h(uint32 u) {
  return make_float2(h2f(u & 0xFFFFu), h2f(u >> 16));
}
DEV f16x8 mkfrag4(uint32 a, uint32 b, uint32 c, uint32 d) {
  union { uint4 u; f16x8 v; } x;
  x.u = make_uint4(a, b, c, d);
  return x.v;
}
DEV void glds16(void* lds, const void* g) {
  __builtin_amdgcn_global_load_lds((const __attribute__((address_space(1))) unsigned int*)g,
                                   (__attribute__((address_space(3))) unsigned int*)lds, 16, 0, 0);
}
DEV void wave_sync() {
  asm volatile("s_waitcnt lgkmcnt(0)" ::: "memory");
  __builtin_amdgcn_sched_barrier(0);
}
DEV int dr10(int v) {   // base-4 digit reversal, 10-bit
  int r = (int)(__brev((unsigned)v) >> 22);
  return ((r & 0x155) << 1) | ((r & 0x2AA) >> 1);
}
constexpr int dr6c(int v) {   // base-4 digit reversal, 6-bit (involution)
  return ((v & 3) << 4) | (v & 12) | ((v >> 4) & 3);
}

// quarter-wave table: CQ[j] = cos(pi*j/32), j=0..16
constexpr float CQ[17] = {
  1.0f, 0.995184726672197f, 0.980785280403230f, 0.956940335732209f,
  0.923879532511287f, 0.881921264348355f, 0.831469612302545f, 0.773010453362737f,
  0.707106781186548f, 0.634393284163645f, 0.555570233019602f, 0.471396736825998f,
  0.382683432365090f, 0.290284677254462f, 0.195090322016128f, 0.098017140329561f, 0.0f };
constexpr float twc64(int j) {   // cos(2*pi*j/64)
  return (j & 63) <= 16 ? CQ[j & 63]
       : (j & 63) <= 32 ? -CQ[32 - (j & 63)]
       : (j & 63) <= 48 ? -CQ[(j & 63) - 32] : CQ[64 - (j & 63)];
}
constexpr float tws64(int j) {   // sin(2*pi*j/64)
  return (j & 63) <= 16 ? CQ[16 - (j & 63)]
       : (j & 63) <= 32 ? CQ[(j & 63) - 16]
       : (j & 63) <= 48 ? -CQ[48 - (j & 63)] : -CQ[(j & 63) - 48];
}

// cos/sin of pi*j/16, j = 0..15 (stage-offset twiddles for LDS FFTs)
constexpr float CR_C[16] = {
  1.0f, 0.980785280403230f, 0.923879532511287f, 0.831469612302545f,
  0.707106781186548f, 0.555570233019602f, 0.382683432365090f, 0.195090322016128f,
  0.0f, -0.195090322016128f, -0.382683432365090f, -0.555570233019602f,
  -0.707106781186548f, -0.831469612302545f, -0.923879532511287f, -0.980785280403230f };
constexpr float CR_S[16] = {
  0.0f, 0.195090322016128f, 0.382683432365090f, 0.555570233019602f,
  0.707106781186548f, 0.831469612302545f, 0.923879532511287f, 0.980785280403230f,
  1.0f, 0.980785280403230f, 0.923879532511287f, 0.831469612302545f,
  0.707106781186548f, 0.555570233019602f, 0.382683432365090f, 0.195090322016128f };

// ---------------- in-register 64-pt radix-4 FFTs (fully unrolled, const twiddles) -------------
template<int SGN>
DEV void rdif64(float2* z) {
  #pragma unroll
  for (int j = 0; j < 16; ++j) {
    float2 x0 = z[j], x1 = z[j + 16], x2 = z[j + 32], x3 = z[j + 48];
    float2 s0 = make_float2(x0.x + x2.x, x0.y + x2.y);
    float2 s1 = make_float2(x0.x - x2.x, x0.y - x2.y);
    float2 s2 = make_float2(x1.x + x3.x, x1.y + x3.y);
    float2 d  = make_float2(x1.x - x3.x, x1.y - x3.y);
    float2 s3 = (SGN < 0) ? make_float2(d.y, -d.x) : make_float2(-d.y, d.x);
    z[j] = make_float2(s0.x + s2.x, s0.y + s2.y);
    const float2 tf1 = make_float2(twc64(j),     (float)SGN * tws64(j));
    const float2 tf2 = make_float2(twc64(2 * j), (float)SGN * tws64(2 * j));
    const float2 tf3 = make_float2(twc64(3 * j), (float)SGN * tws64(3 * j));
    z[j + 16] = cmulf(make_float2(s1.x + s3.x, s1.y + s3.y), tf1);
    z[j + 32] = cmulf(make_float2(s0.x - s2.x, s0.y - s2.y), tf2);
    z[j + 48] = cmulf(make_float2(s1.x - s3.x, s1.y - s3.y), tf3);
  }
  #pragma unroll
  for (int b = 0; b < 64; b += 16)
    #pragma unroll
    for (int j = 0; j < 4; ++j) {
      const int i = b + j;
      float2 x0 = z[i], x1 = z[i + 4], x2 = z[i + 8], x3 = z[i + 12];
      float2 s0 = make_float2(x0.x + x2.x, x0.y + x2.y);
      float2 s1 = make_float2(x0.x - x2.x, x0.y - x2.y);
      float2 s2 = make_float2(x1.x + x3.x, x1.y + x3.y);
      float2 d  = make_float2(x1.x - x3.x, x1.y - x3.y);
      float2 s3 = (SGN < 0) ? make_float2(d.y, -d.x) : make_float2(-d.y, d.x);
      z[i] = make_float2(s0.x + s2.x, s0.y + s2.y);
      const float2 tf1 = make_float2(twc64(4 * j),  (float)SGN * tws64(4 * j));
      const float2 tf2 = make_float2(twc64(8 * j),  (float)SGN * tws64(8 * j));
      const float2 tf3 = make_float2(twc64(12 * j), (float)SGN * tws64(12 * j));
      z[i + 4]  = cmulf(make_float2(s1.x + s3.x, s1.y + s3.y), tf1);
      z[i + 8]  = cmulf(make_float2(s0.x - s2.x, s0.y - s2.y), tf2);
      z[i + 12] = cmulf(make_float2(s1.x - s3.x, s1.y - s3.y), tf3);
    }
  #pragma unroll
  for (int b = 0; b < 64; b += 4) {
    float2 x0 = z[b], x1 = z[b + 1], x2 = z[b + 2], x3 = z[b + 3];
    float2 s0 = make_float2(x0.x + x2.x, x0.y + x2.y);
    float2 s1 = make_float2(x0.x - x2.x, x0.y - x2.y);
    float2 s2 = make_float2(x1.x + x3.x, x1.y + x3.y);
    float2 d  = make_float2(x1.x - x3.x, x1.y - x3.y);
    float2 s3 = (SGN < 0) ? make_float2(d.y, -d.x) : make_float2(-d.y, d.x);
    z[b]     = make_float2(s0.x + s2.x, s0.y + s2.y);
    z[b + 1] = make_float2(s1.x + s3.x, s1.y + s3.y);
    z[b + 2] = make_float2(s0.x - s2.x, s0.y - s2.y);
    z[b + 3] = make_float2(s1.x - s3.x, s1.y - s3.y);
  }
}

template<int SGN>
DEV void rdit64(float2* z) {
  #pragma unroll
  for (int b = 0; b < 64; b += 4) {
    float2 b0 = z[b], b1 = z[b + 1], b2 = z[b + 2], b3 = z[b + 3];
    float2 t0 = make_float2(b0.x + b2.x, b0.y + b2.y);
    float2 t1 = make_float2(b0.x - b2.x, b0.y - b2.y);
    float2 t2 = make_float2(b1.x + b3.x, b1.y + b3.y);
    float2 d  = make_float2(b1.x - b3.x, b1.y - b3.y);
    float2 t3 = (SGN > 0) ? make_float2(-d.y, d.x) : make_float2(d.y, -d.x);
    z[b]     = make_float2(t0.x + t2.x, t0.y + t2.y);
    z[b + 1] = make_float2(t1.x + t3.x, t1.y + t3.y);
    z[b + 2] = make_float2(t0.x - t2.x, t0.y - t2.y);
    z[b + 3] = make_float2(t1.x - t3.x, t1.y - t3.y);
  }
  #pragma unroll
  for (int b = 0; b < 64; b += 16)
    #pragma unroll
    for (int j = 0; j < 4; ++j) {
      const int i = b + j;
      const float2 tf1 = make_float2(twc64(4 * j),  (float)SGN * tws64(4 * j));
      const float2 tf2 = make_float2(twc64(8 * j),  (float)SGN * tws64(8 * j));
      const float2 tf3 = make_float2(twc64(12 * j), (float)SGN * tws64(12 * j));
      float2 b0 = z[i];
      float2 b1 = cmulf(z[i + 4], tf1);
      float2 b2 = cmulf(z[i + 8], tf2);
      float2 b3 = cmulf(z[i + 12], tf3);
      float2 t0 = make_float2(b0.x + b2.x, b0.y + b2.y);
      float2 t1 = make_float2(b0.x - b2.x, b0.y - b2.y);
      float2 t2 = make_float2(b1.x + b3.x, b1.y + b3.y);
      float2 d  = make_float2(b1.x - b3.x, b1.y - b3.y);
      float2 t3 = (SGN > 0) ? make_float2(-d.y, d.x) : make_float2(d.y, -d.x);
      z[i]      = make_float2(t0.x + t2.x, t0.y + t2.y);
      z[i + 4]  = make_float2(t1.x + t3.x, t1.y + t3.y);
      z[i + 8]  = make_float2(t0.x - t2.x, t0.y - t2.y);
      z[i + 12] = make_float2(t1.x - t3.x, t1.y - t3.y);
    }
  #pragma unroll
  for (int j = 0; j < 16; ++j) {
    const float2 tf1 = make_float2(twc64(j),     (float)SGN * tws64(j));
    const float2 tf2 = make_float2(twc64(2 * j), (float)SGN * tws64(2 * j));
    const float2 tf3 = make_float2(twc64(3 * j), (float)SGN * tws64(3 * j));
    float2 b0 = z[j];
    float2 b1 = cmulf(z[j + 16], tf1);
    float2 b2 = cmulf(z[j + 32], tf2);
    float2 b3 = cmulf(z[j + 48], tf3);
    float2 t0 = make_float2(b0.x + b2.x, b0.y + b2.y);
    float2 t1 = make_float2(b0.x - b2.x, b0.y - b2.y);
    float2 t2 = make_float2(b1.x + b3.x, b1.y + b3.y);
    float2 d  = make_float2(b1.x - b3.x, b1.y - b3.y);
    float2 t3 = (SGN > 0) ? make_float2(-d.y, d.x) : make_float2(d.y, -d.x);
    z[j]      = make_float2(t0.x + t2.x, t0.y + t2.y);
    z[j + 16] = make_float2(t1.x + t3.x, t1.y + t3.y);
    z[j + 32] = make_float2(t0.x - t2.x, t0.y - t2.y);
    z[j + 48] = make_float2(t1.x - t3.x, t1.y - t3.y);
  }
}

// Radix-4 DIF over LDS, natural in -> digit-reversed out (negative exponent).
template<int L, int NLOG, int NSUB, bool WL>
DEV void dif4_stages(float2* F, int lg) {
  #pragma unroll
  for (int st = 0; st < NLOG / 2; ++st) {
    const int qlog = NLOG - 2 - 2 * st;
    const int q = 1 << qlog;
    float bs, bc;
    __sincosf((float)(lg & (q - 1)) * (-1.57079632679489661923f / (float)q), &bs, &bc);
    const float2 base = make_float2(bc, bs);
    #pragma unroll
    for (int u = 0; u < NSUB * (1 << (NLOG - 2)) / L; ++u) {
      const int sub = (u * L) >> (NLOG - 2);
      const int bf = ((u * L) & ((1 << (NLOG - 2)) - 1)) + lg;
      const int jj = ((u * L) % q) * 8 / q;
      const int i1 = (sub << NLOG) + ((bf >> qlog) << (qlog + 2)) + (bf & (q - 1));
      float2 x0 = F[i1], x1 = F[i1 + q], x2 = F[i1 + 2 * q], x3 = F[i1 + 3 * q];
      float2 s0 = make_float2(x0.x + x2.x, x0.y + x2.y);
      float2 s1 = make_float2(x0.x - x2.x, x0.y - x2.y);
      float2 s2 = make_float2(x1.x + x3.x, x1.y + x3.y);
      float2 dq = make_float2(x1.x - x3.x, x1.y - x3.y);
      float2 s3 = make_float2(dq.y, -dq.x);               // -i*(x1-x3)
      F[i1] = make_float2(s0.x + s2.x, s0.y + s2.y);
      if (qlog == 0) {
        F[i1 + 1] = make_float2(s1.x + s3.x, s1.y + s3.y);
        F[i1 + 2] = make_float2(s0.x - s2.x, s0.y - s2.y);
        F[i1 + 3] = make_float2(s1.x - s3.x, s1.y - s3.y);
      } else {
        const float2 tf1 = (jj == 0) ? base : cmulf(base, make_float2(CR_C[jj], -CR_S[jj]));
        const float2 tf2 = cmulf(tf1, tf1);
        const float2 tf3 = cmulf(tf2, tf1);
        F[i1 + q]     = cmulf(make_float2(s1.x + s3.x, s1.y + s3.y), tf1);
        F[i1 + 2 * q] = cmulf(make_float2(s0.x - s2.x, s0.y - s2.y), tf2);
        F[i1 + 3 * q] = cmulf(make_float2(s1.x - s3.x, s1.y - s3.y), tf3);
      }
    }
    if (WL) wave_sync(); else __syncthreads();
  }
}

// ---------------- quaternion helpers ----------------------------------------------------------
DEV float4 qmul4(float4 a, float4 b) {
  return make_float4(
    a.x * b.x - a.y * b.y - a.z * b.z - a.w * b.w,
    a.x * b.y + a.y * b.x + a.z * b.w - a.w * b.z,
    a.x * b.z - a.y * b.w + a.z * b.x + a.w * b.y,
    a.x * b.w + a.y * b.z - a.z * b.y + a.w * b.x);
}
DEV float4 qne(float4 q) {
  float n = sqrtf(q.x * q.x + q.y * q.y + q.z * q.z + q.w * q.w) + 1e-8f;
  float r = 1.0f / n;
  return make_float4(q.x * r, q.y * r, q.z * r, q.w * r);
}

// ---------------- fractal pass 1: 1024-pt radix-4 FFTs, wave-private; fp16-packed out --------
__global__ __launch_bounds__(512) void kx_fr_pass1(const float* __restrict__ x,
    const float* __restrict__ W_in, const float* __restrict__ b_in,
    uint32* __restrict__ zmid) {
  __shared__ float2 fb[8 * 1028];
  const int t = threadIdx.x, l = t & 63, w = t >> 6;
  const int btile = blockIdx.x, bz = blockIdx.y;
  const int bcol = btile * 8 + w;
  const int d = 2 * (bcol & 511);
  const int soff = bcol >> 9;
  const float w00 = W_in[d],     w10 = W_in[1024 + d], w20 = W_in[2048 + d], w30 = W_in[3072 + d];
  const float w01 = W_in[d + 1], w11 = W_in[1025 + d], w21 = W_in[2049 + d], w31 = W_in[3073 + d];
  const float bi0 = b_in[d], bi1 = b_in[d + 1];
  const float* xb = x + (size_t)bz * 4096 * 4;
  float2* fbw = fb + w * 1028;
  #pragma unroll
  for (int i = 0; i < 16; ++i) {
    int a = i * 64 + l;
    int s = 4 * a + soff;
    float4 xv = *(const float4*)(xb + (size_t)s * 4);
    float z0 = fmaf(xv.x, w00, fmaf(xv.y, w10, fmaf(xv.z, w20, fmaf(xv.w, w30, bi0))));
    float z1 = fmaf(xv.x, w01, fmaf(xv.y, w11, fmaf(xv.z, w21, fmaf(xv.w, w31, bi1))));
    fbw[a] = make_float2(z0, z1);
  }
  wave_sync();
  dif4_stages<64, 10, 1, true>(fbw, l);
  __syncthreads();
  uint32* dst = zmid + (size_t)bz * (1024 * 2048);
  #pragma unroll
  for (int i = 0; i < 16; ++i) {
    int idx = i * 512 + t;
    int w8 = idx & 7, cnat = idx >> 3;
    float2 v = fb[w8 * 1028 + dr10(cnat)];
    dst[(size_t)cnat * 2048 + btile * 8 + w8] = pack2h(v.x, v.y);
  }
}

DEV float block_reduce128(float* red, int t, float v) {
  red[t] = v; __syncthreads();
  for (int s = 64; s; s >>= 1) { if (t < s) red[t] += red[t + s]; __syncthreads(); }
  float r = red[0]; __syncthreads();
  return r;
}

// ---------------- fractal pass 2: fp16 Zmid in; LDS exactly 32KB (reduce buf overlaid) -------
__global__ __launch_bounds__(128) void kx_fr_pass2(const uint32* __restrict__ zmid,
    float* __restrict__ partials, float* __restrict__ sparts) {
  __shared__ float2 fb[2 * 2048];
  const int t = threadIdx.x, l = t & 63, w = t >> 6;   // w in {0,1}
  const int cg = blockIdx.x, bz = blockIdx.y;
  const int c = (cg == 0) ? (w ? 512 : 0) : (w ? (1024 - cg) : cg);
  const uint32* src = zmid + ((size_t)bz * 1024 + c) * 2048;
  float2* fbc = fb + w * 2048;
  float2 rot[4], stp4;
  {
    float sn, cs;
    __sincosf((float)(l * c) * (-6.28318530717958647692f / 2097152.0f), &sn, &cs);
    rot[0] = make_float2(cs, sn);
    float2 stp;
    __sincosf((float)c * (-6.28318530717958647692f / 32768.0f), &sn, &cs);
    stp = make_float2(cs, sn);
    rot[1] = cmulf(rot[0], stp);
    float2 stp2 = cmulf(stp, stp);
    rot[2] = cmulf(rot[0], stp2);
    rot[3] = cmulf(rot[1], stp2);
    stp4 = cmulf(stp2, stp2);
  }
  float2 zr[32];
  #pragma unroll
  for (int i = 0; i < 32; ++i) {
    int bb = i * 64 + l;
    zr[i] = cmulf(unp2h(src[bb]), rot[i & 3]);
    rot[i & 3] = cmulf(rot[i & 3], stp4);
  }
  {
    float bs, bc;
    __sincosf((float)l * (-3.14159265358979323846f / 1024.0f), &bs, &bc);
    const float2 b2 = make_float2(bc, bs);
    #pragma unroll
    for (int u = 0; u < 16; ++u) {
      const float2 tf = (u == 0) ? b2 : cmulf(b2, make_float2(CR_C[u], -CR_S[u]));
      int i1 = u * 64 + l;
      float2 a0 = zr[u], a1 = zr[u + 16];
      fbc[i1] = make_float2(a0.x + a1.x, a0.y + a1.y);
      fbc[i1 + 1024] = cmulf(make_float2(a0.x - a1.x, a0.y - a1.y), tf);
    }
    wave_sync();
  }
  dif4_stages<64, 10, 2, true>(fbc, l);
  __syncthreads();
  float t0 = 0.f, t1 = 0.f, s0 = 0.f, s1 = 0.f, s2 = 0.f;
  if (cg != 0) {
    const float2* fbm = fb + (1 - w) * 2048;
    float2 pw[32];
    pw[0] = make_float2(1.f, 0.f);
    {
      float sn, cs;
      __sincosf(-3.14159265358979323846f / 2048.0f, &sn, &cs);
      float2 w1 = make_float2(cs, sn);
      #pragma unroll
      for (int j = 1; j < 32; ++j) pw[j] = cmulf(pw[j - 1], w1);
    }
    const int drl = (l & 3) * 256 + ((l >> 2) & 3) * 64 + ((l >> 4) & 3) * 16;
    float2 base2;
    {
      float sn, cs;
      __sincosf((float)drl * (-3.14159265358979323846f / 1024.0f), &sn, &cs);
      float2 lf = make_float2(cs, sn);
      __sincosf((float)c * (-6.28318530717958647692f / 4194304.0f), &sn, &cs);
      base2 = cmulf(make_float2(cs, sn), lf);
    }
    #pragma unroll
    for (int i = 0; i < 32; ++i) {
      const int p = i * 64 + l;
      const int dri = (i & 3) * 4 + ((i >> 2) & 3);
      const int top = i >> 4;
      const int dd = 2 * (drl + dri) + top;
      float2 Zk = fbc[p];
      float2 Zm = fbm[2047 - p];
      float2 E = make_float2(0.5f * (Zk.x + Zm.x), 0.5f * (Zk.y - Zm.y));
      float2 A = make_float2(Zk.x - Zm.x, Zk.y + Zm.y);
      float2 O = make_float2(0.5f * A.y, -0.5f * A.x);
      float2 urot = cmulf(base2, pw[2 * dri + top]);
      float2 U = cmulf(urot, O);
      float Xr = E.x + U.x, Xi = E.y + U.y;
      float P = Xr * Xr + Xi * Xi;
      int k = c + (dd << 10);
      float fr = (float)k * (1.0f / 4194304.0f);
      if (fr > 0.01f && fr < 0.5f) {
        float lp = __logf(P + 1e-10f);
        float lk = __logf(fr + 1e-10f);
        t0 += lp; t1 += lk * lp;
        s0 += 1.0f; s1 += lk; s2 += lk * lk;
      }
    }
  } else {
    const float2* fbm = fbc;   // self-mirrored columns (c = 0, 512)
    float2 urot;
    {
      float sn, cs;
      __sincosf((float)(c + l * 1024) * (-6.28318530717958647692f / 4194304.0f), &sn, &cs);
      urot = make_float2(cs, sn);
    }
    const float2 ustp = make_float2(0.995184726672197f, -0.0980171403295606f); // e^{-i pi/32}
    #pragma unroll
    for (int i = 0; i < 32; ++i) {
      int dd = i * 64 + l;
      int md = (c == 0) ? ((2048 - dd) & 2047) : (2047 - dd);
      int pk = ((dd & 1) << 10) | dr10(dd >> 1);
      int pm = ((md & 1) << 10) | dr10(md >> 1);
      float2 Zk = fbc[pk];
      float2 Zm = fbm[pm];
      float2 E = make_float2(0.5f * (Zk.x + Zm.x), 0.5f * (Zk.y - Zm.y));
      float2 A = make_float2(Zk.x - Zm.x, Zk.y + Zm.y);
      float2 O = make_float2(0.5f * A.y, -0.5f * A.x);
      float2 U = cmulf(urot, O);
      float Xr = E.x + U.x, Xi = E.y + U.y;
      float P = Xr * Xr + Xi * Xi;
      int k = c + (dd << 10);
      float fr = (float)k * (1.0f / 4194304.0f);
      if (fr > 0.01f && fr < 0.5f) {
        float lp = __logf(P + 1e-10f);
        float lk = __logf(fr + 1e-10f);
        t0 += lp; t1 += lk * lp;
        s0 += 1.0f; s1 += lk; s2 += lk * lk;
      }
      urot = cmulf(urot, ustp);
    }
  }
  __syncthreads();                       // fb dead; reuse as reduction buffer
  float* red = (float*)fb;
  float T0 = block_reduce128(red, t, t0);
  float T1 = block_reduce128(red, t, t1);
  if (t == 0) {
    partials[((size_t)bz * 512 + cg) * 2 + 0] = T0;
    partials[((size_t)bz * 512 + cg) * 2 + 1] = T1;
  }
  if (bz == 0) {
    float S0 = block_reduce128(red, t, s0);
    float S1 = block_reduce128(red, t, s1);
    float S2 = block_reduce128(red, t, s2);
    if (t == 0) { sparts[cg * 3] = S0; sparts[cg * 3 + 1] = S1; sparts[cg * 3 + 2] = S2; }
  }
}

DEV float block_reduce256s(float* sh, int t, float v) {
  sh[t] = v; __syncthreads();
  for (int s = 128; s; s >>= 1) { if (t < s) sh[t] += sh[t + s]; __syncthreads(); }
  float r = sh[0]; __syncthreads();
  return r;
}

// ---------------- merged: gains (+alpha +gelu recompute +quats) and W transpose ---------------
__global__ __launch_bounds__(256) void kx_gainsall(const float* __restrict__ partials,
    const float* __restrict__ sparts, const float* __restrict__ abase,
    const float* __restrict__ pshift, const float* __restrict__ thL,
    const float* __restrict__ thR, const float* __restrict__ W,
    u16* __restrict__ Wt, float* __restrict__ gains, float* __restrict__ qlr) {
  const int bid = blockIdx.x;
  const int t = threadIdx.x;
  if (bid >= 128) {
    __shared__ float tile[64][65];
    const int q = bid - 128;
    const int nt = q & 15, dt = q >> 4;
    #pragma unroll
    for (int i = 0; i < 16; ++i) {
      int idx = i * 256 + t;
      int r = idx >> 6, cc = idx & 63;
      tile[r][cc] = W[(size_t)(dt * 64 + r) * 1024 + nt * 64 + cc];
    }
    __syncthreads();
    #pragma unroll
    for (int i = 0; i < 2; ++i) {
      int task = i * 256 + t;
      int nl = task >> 3, g = task & 7;
      union { u16 h[8]; uint4 v; } pk;
      #pragma unroll
      for (int k = 0; k < 8; ++k) pk.h[k] = f2h(tile[g * 8 + k][nl]);
      size_t idx = (size_t)(nt * 64 + nl) * 1024 + dt * 64 + ((g ^ (nl & 7)) << 3);
      *(uint4*)(Wt + idx) = pk.v;
    }
    return;
  }
  __shared__ float red[256];
  float s0 = 0.f, s1 = 0.f, s2 = 0.f;
  for (int i = t; i < 512; i += 256) {
    s0 += sparts[i * 3]; s1 += sparts[i * 3 + 1]; s2 += sparts[i * 3 + 2];
  }
  s0 = block_reduce256s(red, t, s0);
  s1 = block_reduce256s(red, t, s1);
  s2 = block_reduce256s(red, t, s2);
  const float mk = s1 / s0;
  const float var = s2 - mk * s1;
  const int b = bid >> 4, h = bid & 15;
  float t0 = 0.f, t1 = 0.f;
  for (int i = t; i < 512; i += 256) {
    t0 += partials[((size_t)b * 512 + i) * 2];
    t1 += partials[((size_t)b * 512 + i) * 2 + 1];
  }
  t0 = block_reduce256s(red, t, t0);
  t1 = block_reduce256s(red, t, t1);
  const float cov = t1 - mk * t0;
  const float beta = -cov / (var + 1e-10f);
  const float D = fminf(fmaxf((3.0f - beta) * 0.5f, 0.5f), 1.5f);
  const float alpha = fminf(fmaxf(1.0f + 0.8f * (D - 1.0f), 0.1f), 3.0f);
  const float aa = abase[h] * alpha;
  const float ps = pshift[h];
  float lkv[16];
  float ls = 0.f;
  #pragma unroll
  for (int i = 0; i < 16; ++i) {
    int s = i * 256 + t;
    int m = (s < 2048) ? s : (4096 - s);
    lkv[i] = logf((float)m * (1.0f / 4096.0f) + 1e-8f);
    ls += lkv[i];
  }
  const float mean = block_reduce256s(red, t, ls) * (1.0f / 4096.0f);
  float vs = 0.f;
  #pragma unroll
  for (int i = 0; i < 16; ++i) { float dv = lkv[i] - mean; vs += dv * dv; }
  const float sd = sqrtf(block_reduce256s(red, t, vs) * (1.0f / 4095.0f));
  for (int k = t; k < 2049; k += 256) {
    float lk_k = logf((float)k * (1.0f / 4096.0f) + 1e-8f);
    float xn = (lk_k - mean) / (sd + 1e-8f);
    float ge = 0.5f * xn * (1.0f + erff(xn * 0.70710678118654752440f));
    gains[(size_t)bid * 2064 + k] = cosf(fmaf(aa, ge, ps));
  }
  if (bid == 0 && t == 0) {
    float4 QL = make_float4(1.f, 0.f, 0.f, 0.f);
    float4 QRC = make_float4(1.f, 0.f, 0.f, 0.f);
    for (int it = 0; it < 4; ++it) {
      float ss0, cc0, ss1, cc1, ss2, cc2;
      sincosf(0.5f * thL[it * 3 + 0], &ss0, &cc0);
      sincosf(0.5f * thL[it * 3 + 1], &ss1, &cc1);
      sincosf(0.5f * thL[it * 3 + 2], &ss2, &cc2);
      float4 qL = qne(make_float4(cc0 * cc1 * cc2, ss0 * cc1 * cc2, cc0 * ss1 * cc2, cc0 * cc1 * ss2));
      QL = qmul4(qL, QL);
      sincosf(0.5f * thR[it * 3 + 0], &ss0, &cc0);
      sincosf(0.5f * thR[it * 3 + 1], &ss1, &cc1);
      sincosf(0.5f * thR[it * 3 + 2], &ss2, &cc2);
      float4 qR = qne(make_float4(cc0 * cc1 * cc2, ss0 * cc1 * cc2, cc0 * ss1 * cc2, cc0 * cc1 * ss2));
      QRC = qmul4(QRC, make_float4(qR.x, -qR.y, -qR.z, -qR.w));
    }
    *(float4*)qlr = QL;
    *(float4*)(qlr + 4) = QRC;
  }
}

// ---------------- spectral filter: four-step register FFT (64x64), sequential store ----------
__global__ __launch_bounds__(128, 1) void kx_filter(const float* __restrict__ x,
    const float* __restrict__ W_in, const float* __restrict__ b_in,
    const float* __restrict__ gains, uint32* __restrict__ XFp) {
  __shared__ uint32 tr[2][4096];   // fp16x2 transpose buffer, 16KB per wave
  const int t = threadIdx.x, l = t & 63, wv = t >> 6;
  const int g = blockIdx.x, h = blockIdx.y, bz = blockIdx.z;
  const int d0 = h * 64 + g * 4 + wv * 2;
  const float* gn = gains + ((size_t)bz * 16 + h) * 2064;
  const float wa0 = W_in[d0],     wa1 = W_in[1024 + d0], wa2 = W_in[2048 + d0], wa3 = W_in[3072 + d0];
  const float wb0 = W_in[d0 + 1], wb1 = W_in[1025 + d0], wb2 = W_in[2049 + d0], wb3 = W_in[3073 + d0];
  const float bia = b_in[d0], bib = b_in[d0 + 1];
  const float* xb = x + (size_t)bz * 4096 * 4;
  uint32* trw = tr[wv];
  float2 z[64];
  #pragma unroll
  for (int r = 0; r < 64; ++r) {
    int s = r * 64 + l;
    float4 xv = *(const float4*)(xb + (size_t)s * 4);
    float za = fmaf(xv.x, wa0, fmaf(xv.y, wa1, fmaf(xv.z, wa2, fmaf(xv.w, wa3, bia))));
    float zb = fmaf(xv.x, wb0, fmaf(xv.y, wb1, fmaf(xv.z, wb2, fmaf(xv.w, wb3, bib))));
    z[r] = make_float2(za, zb);
  }
  rdif64<-1>(z);
  {
    float sn, cs;
    __sincosf((float)l * (-6.28318530717958647692f / 4096.0f), &sn, &cs);
    float2 w1 = make_float2(cs, sn);
    float2 w2 = cmulf(w1, w1);
    float2 w4 = cmulf(w2, w2);
    float2 tch[4] = { make_float2(1.f, 0.f), w1, w2, cmulf(w2, w1) };
    #pragma unroll
    for (int i = 0; i < 16; ++i) {
      #pragma unroll
      for (int j = 0; j < 4; ++j) {
        const int rr = dr6c(4 * i + j);
        z[rr] = cmulf(z[rr], tch[j]);
      }
      #pragma unroll
      for (int j = 0; j < 4; ++j) tch[j] = cmulf(tch[j], w4);
    }
  }
  #pragma unroll
  for (int r = 0; r < 64; ++r) {
    const int k1 = dr6c(r);
    trw[k1 * 64 + ((l + k1) & 63)] = pack2h(z[r].x, z[r].y);
  }
  wave_sync();
  #pragma unroll
  for (int c = 0; c < 64; ++c) {
    uint32 u = trw[l * 64 + ((c + l) & 63)];
    z[c] = unp2h(u);
  }
  wave_sync();
  rdif64<-1>(z);
  #pragma unroll
  for (int r = 0; r < 64; ++r) {
    const int k = l + (dr6c(r) << 6);
    const int km = (k < 2048) ? k : (4096 - k);
    const float gk = gn[km];
    z[r] = make_float2(z[r].x * gk, z[r].y * gk);
  }
  rdit64<1>(z);
  {
    float sn, cs;
    __sincosf((float)l * (6.28318530717958647692f / 4096.0f), &sn, &cs);
    float2 v1 = make_float2(cs, sn);
    float2 v2 = cmulf(v1, v1);
    float2 v4 = cmulf(v2, v2);
    float2 tch[4] = { make_float2(1.f, 0.f), v1, v2, cmulf(v2, v1) };
    #pragma unroll
    for (int i = 0; i < 16; ++i) {
      #pragma unroll
      for (int j = 0; j < 4; ++j)
        z[4 * i + j] = cmulf(z[4 * i + j], tch[j]);
      #pragma unroll
      for (int j = 0; j < 4; ++j) tch[j] = cmulf(tch[j], v4);
    }
  }
  #pragma unroll
  for (int r = 0; r < 64; ++r)
    trw[r * 64 + ((l + r) & 63)] = pack2h(z[r].x, z[r].y);
  wave_sync();
  #pragma unroll
  for (int c = 0; c < 64; ++c) {
    uint32 u = trw[l * 64 + ((c + l) & 63)];
    z[c] = unp2h(u);
  }
  wave_sync();
  #pragma unroll
  for (int j = 0; j < 64; ++j) {
    const int dj = dr6c(j);
    if (dj > j) { float2 tmp = z[j]; z[j] = z[dj]; z[dj] = tmp; }
  }
  rdit64<1>(z);
  uint32* rowp = XFp + ((size_t)bz * 512 + (d0 >> 1)) * 4096;
  const float sc = 1.0f / 4096.0f;
  #pragma unroll
  for (int r = 0; r < 64; ++r)
    rowp[r * 64 + l] = pack2h(z[r].x * sc, z[r].y * sc);
}

// ---------------- fp16 MFMA GEMM: C16 = A*W, A read DIRECTLY from XFp [b][pair][s] ------------
__global__ __launch_bounds__(256) void kx_gemm(const uint32* __restrict__ XFp,
    const u16* __restrict__ Bw, u16* __restrict__ C) {
  __shared__ uint32 sm[16384];          // 64KB: A u32[2][4096] | B u16[2][8192] (as u32[2][4096])
  uint32* Asm = sm;                     // A buffers: [buf][p*128 + col]
  u16* Bsm = (u16*)(sm + 8192);         // B buffers: [buf][8192]
  const int t = threadIdx.x, l = t & 63, w = t >> 6;
  const int wm = w >> 1, wn = w & 1;
  const int id = blockIdx.x;
  const int wg = (id & 7) * 256 + (id >> 3);        // XCD-contiguous chunks (2048 blocks)
  const int bm = wg >> 3, bn = wg & 7;
  const int bh = bm >> 5;
  const int s0 = (bm & 31) * 128;
  const uint32* Ab = XFp + ((size_t)(bh * 512)) * 4096 + s0;
  const u16* Bb = Bw + (size_t)(bn * 128) * 1024;
  const int fr = l & 15;
  const int lr = l >> 3, lg = l & 7;                // B staging
  const int ap = (l >> 5);                          // A staging: row parity within chunk
  const int ag = l & 31;                            // A staging: local 16B granule
  f32x4 acc[4][4];
  #pragma unroll
  for (int m = 0; m < 4; ++m)
    #pragma unroll
    for (int n = 0; n < 4; ++n) acc[m][n] = (f32x4){0.f, 0.f, 0.f, 0.f};

  // per kt: A tile = pairs kt*32..+32 x 128 s (u32, swizzled granules); B as before.
  #define STAGE(KT, BUF) { \
    uint32* Ad = Asm + (BUF) * 4096; \
    u16* Bd = Bsm + (BUF) * 8192; \
    _Pragma("unroll") \
    for (int j = 0; j < 4; ++j) { \
      int cch = j * 4 + w; \
      int pp = 2 * cch + ap; \
      int gs = ag ^ (pp & 7); \
      glds16((void*)(Ad + cch * 256), Ab + (size_t)((KT) * 32 + pp) * 4096 + gs * 4); \
      int q = j * 4 + w; \
      glds16((void*)(Bd + q * 512), Bb + (size_t)(q * 8 + lr) * 1024 + (KT) * 64 + lg * 8); \
    } }

  STAGE(0, 0);
  __syncthreads();
  for (int kt = 0; kt < 16; ++kt) {
    const int cur = kt & 1;
    if (kt < 15) STAGE(kt + 1, cur ^ 1);
    const uint32* Ac = Asm + cur * 4096;
    const u16* Bc = Bsm + cur * 8192;
    #pragma unroll
    for (int kk = 0; kk < 2; ++kk) {
      const int g8r = kk * 4 + (l >> 4);
      const int p0 = kk * 16 + (l >> 4) * 4;
      f16x8 af[4], bf[4];
      #pragma unroll
      for (int m = 0; m < 4; ++m) {
        const int s = wm * 64 + m * 16 + fr;
        const int sg = s >> 2, sr = s & 3;
        uint32 q0 = Ac[(p0 + 0) * 128 + (((sg) ^ ((p0 + 0) & 7)) << 2) + sr];
        uint32 q1 = Ac[(p0 + 1) * 128 + (((sg) ^ ((p0 + 1) & 7)) << 2) + sr];
        uint32 q2 = Ac[(p0 + 2) * 128 + (((sg) ^ ((p0 + 2) & 7)) << 2) + sr];
        uint32 q3 = Ac[(p0 + 3) * 128 + (((sg) ^ ((p0 + 3) & 7)) << 2) + sr];
        af[m] = mkfrag4(q0, q1, q2, q3);
      }
      #pragma unroll
      for (int n = 0; n < 4; ++n) {
        int nn = wn * 64 + n * 16 + fr;
        bf[n] = *(const f16x8*)&Bc[nn * 64 + ((g8r ^ (nn & 7)) << 3)];
      }
      #pragma unroll
      for (int m = 0; m < 4; ++m)
        #pragma unroll
        for (int n = 0; n < 4; ++n)
          acc[m][n] = __builtin_amdgcn_mfma_f32_16x16x32_f16(af[m], bf[n], acc[m][n], 0, 0, 0);
    }
    __syncthreads();
  }
  float* Cs = (float*)sm;
  const int rl4 = (l >> 4) * 4;
  #pragma unroll
  for (int m = 0; m < 4; ++m) {
    int rbase = wm * 64 + m * 16 + rl4;
    #pragma unroll
    for (int n = 0; n < 4; ++n) {
      int cc = wn * 64 + n * 16 + fr;
      #pragma unroll
      for (int e = 0; e < 4; ++e) {
        int r = rbase + e;
        Cs[r * 128 + (cc ^ (((r >> 2) & 3) << 3))] = acc[m][n][e];
      }
    }
  }
  __syncthreads();
  u16* cgp = C + (size_t)(bm * 128) * 1024 + bn * 128;
  #pragma unroll
  for (int it = 0; it < 16; ++it) {
    int idx = it * 256 + t;
    int r = idx >> 5, c4 = (idx & 31) * 4;
    f32x4 v = *(const f32x4*)&Cs[r * 128 + (c4 ^ (((r >> 2) & 3) << 3))];
    u32x2 pv;
    pv.x = (uint32)f2h(v.x) | ((uint32)f2h(v.y) << 16);
    pv.y = (uint32)f2h(v.z) | ((uint32)f2h(v.w) << 16);
    __builtin_nontemporal_store(pv, (u32x2*)(cgp + (size_t)r * 1024 + c4));
  }
}

// ---------------- tail: LN(xp+out) -> @W_out -> composed quat -> FF ----------------------------
DEV float wred64(float v) {
  #pragma unroll
  for (int m = 32; m; m >>= 1) v += __shfl_xor(v, m);
  return v;
}
DEV float4 ln4q(float4 v, const float* g, const float* b) {
  float m = 0.25f * (v.x + v.y + v.z + v.w);
  float a0 = v.x - m, a1 = v.y - m, a2 = v.z - m, a3 = v.w - m;
  float var = 0.25f * (a0 * a0 + a1 * a1 + a2 * a2 + a3 * a3);
  float rs = 1.0f / sqrtf(var + 1e-5f);
  return make_float4(a0 * rs * g[0] + b[0], a1 * rs * g[1] + b[1],
                     a2 * rs * g[2] + b[2], a3 * rs * g[3] + b[3]);
}
DEV float gelu1(float v) { return 0.5f * v * (1.0f + erff(v * 0.70710678118654752440f)); }

__global__ __launch_bounds__(256) void kx_tail(const u16* __restrict__ G,
    const float* __restrict__ x, const float* __restrict__ W_in, const float* __restrict__ b_in,
    const float* __restrict__ b_attn, const float* __restrict__ lng, const float* __restrict__ lnb,
    const float* __restrict__ W_out, const float* __restrict__ b_out,
    const float* __restrict__ qlr,
    const float* __restrict__ Wf1, const float* __restrict__ bff1,
    const float* __restrict__ Wf2, const float* __restrict__ bff2,
    const float* __restrict__ n1g, const float* __restrict__ n1b,
    const float* __restrict__ n2g, const float* __restrict__ n2b,
    const float* __restrict__ n3g, const float* __restrict__ n3b,
    float* __restrict__ out) {
  const int l = threadIdx.x & 63, w = threadIdx.x >> 6;
  const size_t rg = (size_t)blockIdx.x * 4 + w;
  const float4 x4 = *(const float4*)(x + rg * 4);
  float4 tv[4];
  float lsum = 0.f;
  #pragma unroll
  for (int j = 0; j < 4; ++j) {
    int dd = j * 256 + l * 4;
    uint2 gv = *(const uint2*)(G + rg * 1024 + dd);
    float4 g4 = make_float4(h2f(gv.x & 0xFFFFu), h2f(gv.x >> 16),
                            h2f(gv.y & 0xFFFFu), h2f(gv.y >> 16));
    float4 w0 = *(const float4*)(W_in + dd);
    float4 w1 = *(const float4*)(W_in + 1024 + dd);
    float4 w2 = *(const float4*)(W_in + 2048 + dd);
    float4 w3 = *(const float4*)(W_in + 3072 + dd);
    float4 bi = *(const float4*)(b_in + dd);
    float4 ba = *(const float4*)(b_attn + dd);
    float4 o;
    o.x = g4.x + bi.x + ba.x + x4.x * w0.x + x4.y * w1.x + x4.z * w2.x + x4.w * w3.x;
    o.y = g4.y + bi.y + ba.y + x4.x * w0.y + x4.y * w1.y + x4.z * w2.y + x4.w * w3.y;
    o.z = g4.z + bi.z + ba.z + x4.x * w0.z + x4.y * w1.z + x4.z * w2.z + x4.w * w3.z;
    o.w = g4.w + bi.w + ba.w + x4.x * w0.w + x4.y * w1.w + x4.z * w2.w + x4.w * w3.w;
    tv[j] = o;
    lsum += o.x + o.y + o.z + o.w;
  }
  const float mean = wred64(lsum) * (1.0f / 1024.0f);
  float vsum = 0.f;
  #pragma unroll
  for (int j = 0; j < 4; ++j) {
    float a0 = tv[j].x - mean, a1 = tv[j].y - mean, a2 = tv[j].z - mean, a3 = tv[j].w - mean;
    vsum += a0 * a0 + a1 * a1 + a2 * a2 + a3 * a3;
  }
  const float rstd = 1.0f / sqrtf(wred64(vsum) * (1.0f / 1024.0f) + 1e-5f);
  float4 aq = make_float4(0.f, 0.f, 0.f, 0.f);
  #pragma unroll
  for (int j = 0; j < 4; ++j) {
    int dd = j * 256 + l * 4;
    float4 gg = *(const float4*)(lng + dd);
    float4 bb = *(const float4*)(lnb + dd);
    float av[4];
    av[0] = (tv[j].x - mean) * rstd * gg.x + bb.x;
    av[1] = (tv[j].y - mean) * rstd * gg.y + bb.y;
    av[2] = (tv[j].z - mean) * rstd * gg.z + bb.z;
    av[3] = (tv[j].w - mean) * rstd * gg.w + bb.w;
    #pragma unroll
    for (int e = 0; e < 4; ++e) {
      float4 wr = *(const float4*)(W_out + (size_t)(dd + e) * 4);
      aq.x = fmaf(av[e], wr.x, aq.x);
      aq.y = fmaf(av[e], wr.y, aq.y);
      aq.z = fmaf(av[e], wr.z, aq.z);
      aq.w = fmaf(av[e], wr.w, aq.w);
    }
  }
  aq.x = wred64(aq.x) + b_out[0];
  aq.y = wred64(aq.y) + b_out[1];
  aq.z = wred64(aq.z) + b_out[2];
  aq.w = wred64(aq.w) + b_out[3];
  float4 q1 = make_float4(x4.x + aq.x, x4.y + aq.y, x4.z + aq.z, x4.w + aq.w);
  float4 hq = qne(ln4q(q1, n1g, n1b));
  const float4 QL = *(const float4*)qlr;
  const float4 QRC = *(const float4*)(qlr + 4);
  float4 o = qne(qmul4(qmul4(QL, hq), QRC));
  float4 h2 = qne(ln4q(make_float4(hq.x + o.x, hq.y + o.y, hq.z + o.z, hq.w + o.w), n2g, n2b));
  float ffx = 0.f, ffy = 0.f, ffz = 0.f, ffw = 0.f;
  if (l < 16) {
    float uv = bff1[l] + h2.x * Wf1[l] + h2.y * Wf1[16 + l] + h2.z * Wf1[32 + l] + h2.w * Wf1[48 + l];
    uv = gelu1(uv);
    float4 w2r = *(const float4*)(Wf2 + l * 4);
    ffx = uv * w2r.x; ffy = uv * w2r.y; ffz = uv * w2r.z; ffw = uv * w2r.w;
  }
  ffx = wred64(ffx) + bff2[0];
  ffy = wred64(ffy) + bff2[1];
  ffz = wred64(ffz) + bff2[2];
  ffw = wred64(ffw) + bff2[3];
  float4 h3 = qne(ln4q(make_float4(h2.x + ffx, h2.y + ffy, h2.z + ffz, h2.w + ffw), n3g, n3b));
  if (l == 0) *(float4*)(out + rg * 4) = h3;
}

extern "C" void kernel_launch(void* const* d_in, const int* in_sizes, int n_in,
                              void* d_out, int out_size, void* d_ws, size_t ws_size,
                              hipStream_t stream) {
  (void)in_sizes; (void)n_in; (void)out_size;
  const float* x      = (const float*)d_in[0];
  const float* W_in   = (const float*)d_in[1];
  const float* b_in   = (const float*)d_in[2];
  const float* abase  = (const float*)d_in[3];
  const float* pshift = (const float*)d_in[4];
  const float* Wattn  = (const float*)d_in[5];
  const float* battn  = (const float*)d_in[6];
  const float* lng    = (const float*)d_in[7];
  const float* lnb    = (const float*)d_in[8];
  const float* Wout   = (const float*)d_in[9];
  const float* bout   = (const float*)d_in[10];
  const float* thL    = (const float*)d_in[11];
  const float* thR    = (const float*)d_in[12];
  const float* Wf1    = (const float*)d_in[13];
  const float* bff1   = (const float*)d_in[14];
  const float* Wf2    = (const float*)d_in[15];
  const float* bff2   = (const float*)d_in[16];
  const float* n1g    = (const float*)d_in[17];
  const float* n1b    = (const float*)d_in[18];
  const float* n2g    = (const float*)d_in[19];
  const float* n2b    = (const float*)d_in[20];
  const float* n3g    = (const float*)d_in[21];
  const float* n3b    = (const float*)d_in[22];

  if (ws_size < (size_t)138459204) return;  // ~132 MiB
  char* ws = (char*)d_ws;
  uint32* Zmid  = (uint32*)ws;                       // 64MiB fp16-packed (fractal only)
  uint32* XFp   = (uint32*)ws;                       // 64MiB (filter out, u32 pair [b][p][s]; overlays dead Zmid)
  u16*   C16    = (u16*)(ws + 67108864);             // 64MiB fp16 gemm out (separate: gemm reads XFp!)
  u16*   W2h    = (u16*)(ws + 134217728);            // 2MiB fp16 W^T pre-swizzled
  float* gainsw = (float*)(ws + 136314880);          // ~1MiB gain table [128][2064]
  float* qlrw   = (float*)(ws + 137400320);          // 32B composed quats
  float* partials = (float*)(ws + 138412032);        // 32KB
  float* sparts   = (float*)(ws + 138444800);        // 6KB

  kx_fr_pass1<<<dim3(256, 8), 512, 0, stream>>>(x, W_in, b_in, Zmid);
  kx_fr_pass2<<<dim3(512, 8), 128, 0, stream>>>(Zmid, partials, sparts);
  kx_gainsall<<<384, 256, 0, stream>>>(partials, sparts, abase, pshift, thL, thR,
                                       Wattn, W2h, gainsw, qlrw);
  kx_filter<<<dim3(16, 16, 8), 128, 0, stream>>>(x, W_in, b_in, gainsw, XFp);
  kx_gemm<<<2048, 256, 0, stream>>>(XFp, W2h, C16);
  kx_tail<<<8192, 256, 0, stream>>>(C16, x, W_in, b_in, battn, lng, lnb, Wout, bout,
                                    qlrw, Wf1, bff1, Wf2, bff2,
                                    n1g, n1b, n2g, n2b, n3g, n3b, (float*)d_out);
}